// Round 2
// baseline (3370.856 us; speedup 1.0000x reference)
//
#include <hip/hip_runtime.h>
#include <hip/hip_bf16.h>

#define NT 2048
#define Dm 768
#define Fm 3072
#define Bm 16
#define Sm 128
#define Hm 12
#define DHm 64

__device__ __forceinline__ float gelu_f(float x){
  return 0.5f*x*(1.0f + erff(x*0.70710678118654752f));
}

// ---- batch-level routing: mean over S, @sw_w, softmax top-1 ----
__global__ __launch_bounds__(256) void k_route_batch(const float* __restrict__ xf,
    const float* __restrict__ sw_w, const float* __restrict__ sw_b,
    float* __restrict__ pmax_b, int* __restrict__ route_b){
  int b = blockIdx.x, tid = threadIdx.x;
  __shared__ float xm[Dm];
  for(int d=tid; d<Dm; d+=256){
    float s=0.f;
    const float* xp = xf + ((size_t)b*Sm)*Dm + d;
    for(int ss=0; ss<Sm; ss++) s += xp[(size_t)ss*Dm];
    xm[d] = s*(1.0f/Sm);
  }
  __syncthreads();
  float a0=0,a1=0,a2=0,a3=0;
  for(int d=tid; d<Dm; d+=256){
    float xv = xm[d];
    a0 += xv*sw_w[d*4+0];
    a1 += xv*sw_w[d*4+1];
    a2 += xv*sw_w[d*4+2];
    a3 += xv*sw_w[d*4+3];
  }
  __shared__ float red[4][256];
  red[0][tid]=a0; red[1][tid]=a1; red[2][tid]=a2; red[3][tid]=a3;
  for(int off=128; off>0; off>>=1){
    __syncthreads();
    if(tid<off){ for(int u=0;u<4;u++) red[u][tid]+=red[u][tid+off]; }
  }
  __syncthreads();
  if(tid==0){
    float l[4]; for(int u=0;u<4;u++) l[u]=red[u][0]+sw_b[u];
    float m=l[0]; int arg=0;
    for(int u=1;u<4;u++) if(l[u]>m){ m=l[u]; arg=u; }
    float s=0; for(int u=0;u<4;u++) s+=expf(l[u]-m);
    pmax_b[b]=1.0f/s;     // max prob = exp(0)/sum
    route_b[b]=arg;
  }
}

// ---- plain GEMM: C[M,N] = A[M,K] @ W[K,N] + bias, per-batch expert weight select ----
__global__ __launch_bounds__(256) void k_gemm(
    const float* __restrict__ A, const float* __restrict__ W, const float* __restrict__ bias,
    float* __restrict__ C, int N, int K,
    const int* __restrict__ route_b, long long wstride, long long bstride,
    int accum, int dogelu, const float* __restrict__ bias_scale_b)
{
  int m0 = blockIdx.y*64, n0 = blockIdx.x*64;
  int tid = threadIdx.x, tx = tid&15, ty = tid>>4;
  int bidx = m0 >> 7;  // 128 tokens per batch row
  const float* Wp = W; const float* bp = bias;
  if(route_b){ int e = route_b[bidx]; Wp += (long long)e*wstride; bp += (long long)e*bstride; }
  __shared__ float As[16][64];
  __shared__ float Ws[16][64];
  float acc[4][4] = {};
  for(int k0=0; k0<K; k0+=16){
    for(int l=tid; l<1024; l+=256){
      int m=l>>4, k=l&15;
      As[k][m] = A[(size_t)(m0+m)*K + k0+k];
    }
    for(int l=tid; l<1024; l+=256){
      int k=l>>6, n=l&63;
      Ws[k][n] = Wp[(size_t)(k0+k)*N + n0+n];
    }
    __syncthreads();
    #pragma unroll
    for(int kk=0; kk<16; kk++){
      float va0=As[kk][ty*4+0], va1=As[kk][ty*4+1], va2=As[kk][ty*4+2], va3=As[kk][ty*4+3];
      float vb0=Ws[kk][tx*4+0], vb1=Ws[kk][tx*4+1], vb2=Ws[kk][tx*4+2], vb3=Ws[kk][tx*4+3];
      acc[0][0]+=va0*vb0; acc[0][1]+=va0*vb1; acc[0][2]+=va0*vb2; acc[0][3]+=va0*vb3;
      acc[1][0]+=va1*vb0; acc[1][1]+=va1*vb1; acc[1][2]+=va1*vb2; acc[1][3]+=va1*vb3;
      acc[2][0]+=va2*vb0; acc[2][1]+=va2*vb1; acc[2][2]+=va2*vb2; acc[2][3]+=va2*vb3;
      acc[3][0]+=va3*vb0; acc[3][1]+=va3*vb1; acc[3][2]+=va3*vb2; acc[3][3]+=va3*vb3;
    }
    __syncthreads();
  }
  float bscale = bias_scale_b ? bias_scale_b[bidx] : 1.0f;
  for(int i=0;i<4;i++){
    int m = m0 + ty*4 + i;
    for(int j=0;j<4;j++){
      int n = n0 + tx*4 + j;
      float v = acc[i][j] + bscale*bp[n];
      if(dogelu) v = gelu_f(v);
      size_t idx = (size_t)m*N + n;
      if(accum) C[idx] += v; else C[idx] = v;
    }
  }
}

// ---- grouped (gathered-row) GEMM for the token-routed Switch FFN ----
__global__ __launch_bounds__(256) void k_gemm_grp(
    const float* __restrict__ A, const float* __restrict__ Wb, const float* __restrict__ biasb,
    float* __restrict__ C, int N, int K,
    const int* __restrict__ idxlist, const int* __restrict__ grp_base, const int* __restrict__ grp_count,
    int dogelu, const float* __restrict__ rowscale)
{
  int g = blockIdx.y >> 5, t = blockIdx.y & 31;
  int cnt = grp_count[g];
  int r0 = t*64;
  if(r0 >= cnt) return;
  int n0 = blockIdx.x*64;
  const float* W = Wb + (size_t)g*K*N;
  const float* bias = biasb + (size_t)g*N;
  int tid = threadIdx.x, tx = tid&15, ty = tid>>4;
  __shared__ int rows[64];
  if(tid < 64){
    int gi = r0 + tid;
    rows[tid] = (gi < cnt) ? idxlist[grp_base[g]+gi] : -1;
  }
  __syncthreads();
  __shared__ float As[16][64];
  __shared__ float Ws[16][64];
  float acc[4][4] = {};
  for(int k0=0; k0<K; k0+=16){
    for(int l=tid; l<1024; l+=256){
      int m=l>>4, k=l&15;
      int rm = rows[m];
      As[k][m] = (rm>=0) ? A[(size_t)rm*K + k0+k] : 0.f;
    }
    for(int l=tid; l<1024; l+=256){
      int k=l>>6, n=l&63;
      Ws[k][n] = W[(size_t)(k0+k)*N + n0+n];
    }
    __syncthreads();
    #pragma unroll
    for(int kk=0; kk<16; kk++){
      float va0=As[kk][ty*4+0], va1=As[kk][ty*4+1], va2=As[kk][ty*4+2], va3=As[kk][ty*4+3];
      float vb0=Ws[kk][tx*4+0], vb1=Ws[kk][tx*4+1], vb2=Ws[kk][tx*4+2], vb3=Ws[kk][tx*4+3];
      acc[0][0]+=va0*vb0; acc[0][1]+=va0*vb1; acc[0][2]+=va0*vb2; acc[0][3]+=va0*vb3;
      acc[1][0]+=va1*vb0; acc[1][1]+=va1*vb1; acc[1][2]+=va1*vb2; acc[1][3]+=va1*vb3;
      acc[2][0]+=va2*vb0; acc[2][1]+=va2*vb1; acc[2][2]+=va2*vb2; acc[2][3]+=va2*vb3;
      acc[3][0]+=va3*vb0; acc[3][1]+=va3*vb1; acc[3][2]+=va3*vb2; acc[3][3]+=va3*vb3;
    }
    __syncthreads();
  }
  for(int i=0;i<4;i++){
    int rm = rows[ty*4+i];
    if(rm < 0) continue;
    float sc = rowscale ? rowscale[rm] : 1.0f;
    for(int j=0;j<4;j++){
      int n = n0 + tx*4 + j;
      float v = acc[i][j] + bias[n];
      if(dogelu) v = gelu_f(v);
      v *= sc;
      C[(size_t)rm*N + n] = v;
    }
  }
}

// ---- attention core: one block per (h, b, query-half); scores+softmax+PV ----
__global__ __launch_bounds__(256) void k_attn(
    const float* __restrict__ Q, const float* __restrict__ Kt, const float* __restrict__ V,
    const float* __restrict__ mask, float* __restrict__ ctx, const float* __restrict__ scale_b)
{
  int h = blockIdx.x, b = blockIdx.y, qh = blockIdx.z;
  int tid = threadIdx.x;
  __shared__ float kv[128][64];   // K tile, later reused for V
  __shared__ float sS[64][128];   // scores for 64 queries
  size_t base = ((size_t)b*Sm)*Dm + h*DHm;
  for(int l=tid; l<128*64; l+=256){
    int s=l>>6, d=l&63;
    kv[s][d] = Kt[base + (size_t)s*Dm + d];
  }
  __syncthreads();
  int ql = tid>>2;          // 0..63 local query
  int quarter = tid&3;
  int qi = qh*64 + ql;
  float qreg[64];
  const float* qp = Q + base + (size_t)qi*Dm;
  #pragma unroll
  for(int d=0; d<64; d++) qreg[d] = qp[d];
  int kb = quarter*32;
  for(int ki=kb; ki<kb+32; ki++){
    float s=0.f;
    #pragma unroll
    for(int d=0; d<64; d++) s += qreg[d]*kv[ki][d];
    sS[ql][ki] = s*0.125f + mask[b*Sm+ki];
  }
  __syncthreads();
  if(tid < 64){
    float m = -3.4e38f;
    for(int ki=0; ki<128; ki++) m = fmaxf(m, sS[tid][ki]);
    float sum = 0.f;
    for(int ki=0; ki<128; ki++){ float e = expf(sS[tid][ki]-m); sS[tid][ki]=e; sum+=e; }
    float inv = 1.0f/sum;
    for(int ki=0; ki<128; ki++) sS[tid][ki] *= inv;
  }
  __syncthreads();
  for(int l=tid; l<128*64; l+=256){   // reuse kv for V
    int s=l>>6, d=l&63;
    kv[s][d] = V[base + (size_t)s*Dm + d];
  }
  __syncthreads();
  float sc = scale_b ? scale_b[b] : 1.0f;
  int d0 = quarter*16;
  for(int d=d0; d<d0+16; d++){
    float s=0.f;
    for(int ki=0; ki<128; ki++) s += sS[ql][ki]*kv[ki][d];
    ctx[base + (size_t)qi*Dm + d] = s*sc;
  }
}

// ---- token-level Switch routing ----
__global__ __launch_bounds__(256) void k_tok_route(const float* __restrict__ att,
    const float* __restrict__ ur_w, const float* __restrict__ ur_b,
    const int* __restrict__ route_b, float* __restrict__ tok_pmax,
    int* __restrict__ tok_e, int* __restrict__ grp_count)
{
  int n = blockIdx.x, tid = threadIdx.x;
  int i = route_b[n>>7];
  const float* w = ur_w + (size_t)i*Dm*4;
  const float* ap = att + (size_t)n*Dm;
  float a0=0,a1=0,a2=0,a3=0;
  for(int d=tid; d<Dm; d+=256){
    float a = ap[d];
    a0 += a*w[d*4+0];
    a1 += a*w[d*4+1];
    a2 += a*w[d*4+2];
    a3 += a*w[d*4+3];
  }
  __shared__ float red[4][256];
  red[0][tid]=a0; red[1][tid]=a1; red[2][tid]=a2; red[3][tid]=a3;
  for(int off=128; off>0; off>>=1){
    __syncthreads();
    if(tid<off){ for(int u=0;u<4;u++) red[u][tid]+=red[u][tid+off]; }
  }
  __syncthreads();
  if(tid==0){
    float l[4]; for(int u=0;u<4;u++) l[u]=red[u][0]+ur_b[i*4+u];
    float m=l[0]; int arg=0;
    for(int u=1;u<4;u++) if(l[u]>m){ m=l[u]; arg=u; }
    float s=0; for(int u=0;u<4;u++) s+=expf(l[u]-m);
    tok_pmax[n] = 1.0f/s;
    tok_e[n] = arg;
    atomicAdd(&grp_count[i*4+arg], 1);
  }
}

__global__ void k_prefix(const int* __restrict__ cnt, int* __restrict__ base, int* __restrict__ cur){
  if(threadIdx.x==0 && blockIdx.x==0){
    int s=0;
    for(int g=0; g<16; g++){ base[g]=s; cur[g]=s; s+=cnt[g]; }
  }
}

__global__ void k_scatter(const int* __restrict__ route_b, const int* __restrict__ tok_e,
                          int* __restrict__ cur, int* __restrict__ idxl){
  int n = blockIdx.x*256 + threadIdx.x;
  if(n < NT){
    int g = route_b[n>>7]*4 + tok_e[n];
    int pos = atomicAdd(&cur[g], 1);
    idxl[pos] = n;
  }
}

// ---- final residual add + LayerNorm -> f32 out ----
__global__ __launch_bounds__(256) void k_final_ln(const float* __restrict__ att,
    const float* __restrict__ ycf, const float* __restrict__ yu,
    const float* __restrict__ ln_g, const float* __restrict__ ln_b, float* __restrict__ out)
{
  int n = blockIdx.x, tid = threadIdx.x;
  __shared__ float yb[Dm];
  __shared__ float red[256];
  size_t base = (size_t)n*Dm;
  float ps = 0.f;
  for(int d=tid; d<Dm; d+=256){
    float v = att[base+d] + ycf[base+d] + yu[base+d];
    yb[d]=v; ps+=v;
  }
  red[tid]=ps;
  for(int off=128; off>0; off>>=1){ __syncthreads(); if(tid<off) red[tid]+=red[tid+off]; }
  __syncthreads();
  float mu = red[0]*(1.0f/Dm);
  __syncthreads();
  float pv = 0.f;
  for(int d=tid; d<Dm; d+=256){ float t = yb[d]-mu; pv += t*t; }
  red[tid]=pv;
  for(int off=128; off>0; off>>=1){ __syncthreads(); if(tid<off) red[tid]+=red[tid+off]; }
  __syncthreads();
  float var = red[0]*(1.0f/Dm);
  float rstd = rsqrtf(var + 1e-12f);
  for(int d=tid; d<Dm; d+=256){
    out[base+d] = (yb[d]-mu)*rstd*ln_g[d] + ln_b[d];
  }
}

extern "C" void kernel_launch(void* const* d_in, const int* in_sizes, int n_in,
                              void* d_out, int out_size, void* d_ws, size_t ws_size,
                              hipStream_t stream)
{
  const float* x     =(const float*)d_in[0];
  const float* mask  =(const float*)d_in[1];
  const float* sw_w  =(const float*)d_in[2];
  const float* sw_b  =(const float*)d_in[3];
  const float* ca_wq =(const float*)d_in[4];
  const float* ca_bq =(const float*)d_in[5];
  const float* ca_wk =(const float*)d_in[6];
  const float* ca_bk =(const float*)d_in[7];
  const float* ca_wv =(const float*)d_in[8];
  const float* ca_bv =(const float*)d_in[9];
  const float* ca_wo =(const float*)d_in[10];
  const float* ca_bo =(const float*)d_in[11];
  const float* ua_wq =(const float*)d_in[12];
  const float* ua_bq =(const float*)d_in[13];
  const float* ua_wk =(const float*)d_in[14];
  const float* ua_bk =(const float*)d_in[15];
  const float* ua_wv =(const float*)d_in[16];
  const float* ua_bv =(const float*)d_in[17];
  const float* ua_wo =(const float*)d_in[18];
  const float* ua_bo =(const float*)d_in[19];
  const float* cf_w1 =(const float*)d_in[20];
  const float* cf_b1 =(const float*)d_in[21];
  const float* cf_w2 =(const float*)d_in[22];
  const float* cf_b2 =(const float*)d_in[23];
  const float* ur_w  =(const float*)d_in[24];
  const float* ur_b  =(const float*)d_in[25];
  const float* uf_w1 =(const float*)d_in[26];
  const float* uf_b1 =(const float*)d_in[27];
  const float* uf_w2 =(const float*)d_in[28];
  const float* uf_b2 =(const float*)d_in[29];
  const float* ln_g  =(const float*)d_in[30];
  const float* ln_b  =(const float*)d_in[31];

  float* p = (float*)d_ws;
  float* qc   = p; p += (size_t)NT*Dm;
  float* kc   = p; p += (size_t)NT*Dm;
  float* vc   = p; p += (size_t)NT*Dm;
  float* qu   = p; p += (size_t)NT*Dm;
  float* ku   = p; p += (size_t)NT*Dm;
  float* vu   = p; p += (size_t)NT*Dm;
  float* cc   = p; p += (size_t)NT*Dm;    // ctx common; later reused as ycf
  float* cu   = p; p += (size_t)NT*Dm;    // ctx unique (pre-scaled); later reused as yuo
  float* att  = p; p += (size_t)NT*Dm;
  float* pmaxb= p; p += 16;
  float* tokp = p; p += NT;
  int* ip = (int*)p;
  int* routeb = ip; ip += 16;
  int* toke   = ip; ip += NT;
  int* gcnt   = ip; ip += 16;
  int* gbase  = ip; ip += 16;
  int* gcur   = ip; ip += 16;
  int* idxl   = ip; ip += NT;
  // hbuf (NT*Fm floats) aliases qc..qu region, free during FFN phase
  float* hbuf = qc;
  float* ycf  = cc;
  float* yuo  = cu;
  size_t need = (size_t)((char*)ip - (char*)d_ws);
  if(need > ws_size) return;   // workspace too small: bail visibly (output stays 0)

  hipMemsetAsync(gcnt, 0, 48*sizeof(int), stream);   // gcnt, gbase, gcur

  k_route_batch<<<16, 256, 0, stream>>>(x, sw_w, sw_b, pmaxb, routeb);

  dim3 g768(12, 32);
  // common + unique QKV projections
  k_gemm<<<g768,256,0,stream>>>(x, ca_wq, ca_bq, qc, Dm, Dm, nullptr,0,0, 0,0,nullptr);
  k_gemm<<<g768,256,0,stream>>>(x, ca_wk, ca_bk, kc, Dm, Dm, nullptr,0,0, 0,0,nullptr);
  k_gemm<<<g768,256,0,stream>>>(x, ca_wv, ca_bv, vc, Dm, Dm, nullptr,0,0, 0,0,nullptr);
  k_gemm<<<g768,256,0,stream>>>(x, ua_wq, ua_bq, qu, Dm, Dm, routeb,(long long)Dm*Dm,Dm, 0,0,nullptr);
  k_gemm<<<g768,256,0,stream>>>(x, ua_wk, ua_bk, ku, Dm, Dm, routeb,(long long)Dm*Dm,Dm, 0,0,nullptr);
  k_gemm<<<g768,256,0,stream>>>(x, ua_wv, ua_bv, vu, Dm, Dm, routeb,(long long)Dm*Dm,Dm, 0,0,nullptr);

  dim3 ga(Hm, Bm, 2);
  k_attn<<<ga,256,0,stream>>>(qc, kc, vc, mask, cc, nullptr);
  k_attn<<<ga,256,0,stream>>>(qu, ku, vu, mask, cu, pmaxb);   // ctx_u *= pmax[b]

  // output projections: att = cc@ca_wo + ca_bo + (cu_scaled)@ua_wo[route] + pmax*ua_bo[route]
  k_gemm<<<g768,256,0,stream>>>(cc, ca_wo, ca_bo, att, Dm, Dm, nullptr,0,0, 0,0,nullptr);
  k_gemm<<<g768,256,0,stream>>>(cu, ua_wo, ua_bo, att, Dm, Dm, routeb,(long long)Dm*Dm,Dm, 1,0, pmaxb);

  // token routing + grouping
  k_tok_route<<<NT,256,0,stream>>>(att, ur_w, ur_b, routeb, tokp, toke, gcnt);
  k_prefix<<<1,64,0,stream>>>(gcnt, gbase, gcur);
  k_scatter<<<NT/256,256,0,stream>>>(routeb, toke, gcur, idxl);

  // common FFN (hbuf reuses qc..qu region — q/k/v no longer needed)
  dim3 gf1(48, 32), gf2(12, 32);
  k_gemm<<<gf1,256,0,stream>>>(att, cf_w1, cf_b1, hbuf, Fm, Dm, nullptr,0,0, 0,1,nullptr);
  k_gemm<<<gf2,256,0,stream>>>(hbuf, cf_w2, cf_b2, ycf, Dm, Fm, nullptr,0,0, 0,0,nullptr);

  // unique Switch FFN (grouped, token gather); hbuf reused again
  dim3 gg1(48, 512), gg2(12, 512);
  k_gemm_grp<<<gg1,256,0,stream>>>(att, uf_w1, uf_b1, hbuf, Fm, Dm, idxl, gbase, gcnt, 1, nullptr);
  k_gemm_grp<<<gg2,256,0,stream>>>(hbuf, uf_w2, uf_b2, yuo, Dm, Fm, idxl, gbase, gcnt, 0, tokp);

  k_final_ln<<<NT,256,0,stream>>>(att, ycf, yuo, ln_g, ln_b, (float*)d_out);
}

// Round 5
// 1035.543 us; speedup vs baseline: 3.2552x; 3.2552x over previous
//
#include <hip/hip_runtime.h>

#define NT 2048
#define Dm 768
#define Fm 3072
#define Bm 16
#define Sm 128
#define Hm 12
#define DHm 64

#define BM 64
#define BN 128
#define BK 32

typedef __attribute__((ext_vector_type(8))) short bf16x8;
typedef __attribute__((ext_vector_type(4))) float f32x4;

__device__ __forceinline__ unsigned short f2bf(float f){
  unsigned u = __float_as_uint(f);
  unsigned r = (u + 0x7fffu + ((u>>16)&1u)) >> 16;   // round-nearest-even
  return (unsigned short)r;
}
__device__ __forceinline__ float bf2f(unsigned short h){ return __uint_as_float(((unsigned)h)<<16); }
// split f32 into hi/lo bf16 pair, packed: hi = bits[15:0], lo = bits[31:16]
__device__ __forceinline__ unsigned fsplit2(float x){
  unsigned short h = f2bf(x);
  unsigned short l = f2bf(x - bf2f(h));
  return (unsigned)h | ((unsigned)l << 16);
}
__device__ __forceinline__ float gelu_f(float x){
  return 0.5f*x*(1.0f + erff(x*0.70710678118654752f));
}
// byte offset of 8-elem k-group (row,kg) in a [rows][32]-bf16 LDS tile (64B/row);
// XOR swizzle spreads same-kg column reads across banks (2-way residual = free).
__device__ __forceinline__ int lswz(int row, int kg){
  return (row<<6) | (((kg ^ ((row>>1)&3))&3)<<4);
}

// ================= plain bf16 MFMA tile loop (post-routing GEMMs) =================
__device__ __forceinline__ void mm_tile(
    const short* __restrict__ Abf, int lda, const int* rowsLds, int m0,
    const float* __restrict__ W0, int N, int K, int n0,
    short* As, short* Bs, f32x4 acc[2][4])
{
  int tid = threadIdx.x;
  int lane = tid & 63, wv = tid >> 6;
  int wm = wv & 1, wn = wv >> 1;
  int ar = tid >> 2, aseg = tid & 3;
  int bkq = tid & 3, bn2 = tid >> 2;
  int grow = rowsLds ? rowsLds[ar] : (m0 + ar);
  int aoff[2], boff[4];
  #pragma unroll
  for(int fi=0; fi<2; fi++) aoff[fi] = lswz(wm*32 + fi*16 + (lane&15), lane>>4);
  #pragma unroll
  for(int fj=0; fj<4; fj++) boff[fj] = lswz(wn*64 + fj*16 + (lane&15), lane>>4);

  for(int k0=0; k0<K; k0+=BK){
    {
      bf16x8 av = {0,0,0,0,0,0,0,0};
      if(grow >= 0) av = *(const bf16x8*)(Abf + (size_t)grow*lda + k0 + aseg*8);
      *(bf16x8*)((char*)As + lswz(ar, aseg)) = av;
    }
    {
      int kk = k0 + bkq*8;
      const float* wp = W0 + (size_t)kk*N + n0 + bn2*2;
      bf16x8 v0, v1;
      #pragma unroll
      for(int i=0;i<8;i++){
        float2 w = *(const float2*)(wp + (size_t)i*N);
        v0[i] = (short)f2bf(w.x);
        v1[i] = (short)f2bf(w.y);
      }
      *(bf16x8*)((char*)Bs + lswz(bn2*2,   bkq)) = v0;
      *(bf16x8*)((char*)Bs + lswz(bn2*2+1, bkq)) = v1;
    }
    __syncthreads();
    bf16x8 af[2], bfr[4];
    #pragma unroll
    for(int fi=0; fi<2; fi++) af[fi] = *(const bf16x8*)((const char*)As + aoff[fi]);
    #pragma unroll
    for(int fj=0; fj<4; fj++) bfr[fj] = *(const bf16x8*)((const char*)Bs + boff[fj]);
    #pragma unroll
    for(int fi=0; fi<2; fi++)
      #pragma unroll
      for(int fj=0; fj<4; fj++)
        acc[fi][fj] = __builtin_amdgcn_mfma_f32_16x16x32_bf16(af[fi], bfr[fj], acc[fi][fj], 0, 0, 0);
    __syncthreads();
  }
}

// ================= split-bf16 ("bf16x3") MFMA tile loop: ~f32 precision =================
// A f32 [rows][lda], W f32 (two sources split at ksplit). 3 MFMAs per frag pair.
__device__ __forceinline__ void mm_tile3(
    const float* __restrict__ A, int lda, int m0,
    const float* __restrict__ W0, const float* __restrict__ W1, int ksplit,
    int N, int K, int n0,
    short* AsH, short* AsL, short* BsH, short* BsL, f32x4 acc[2][4])
{
  int tid = threadIdx.x;
  int lane = tid & 63, wv = tid >> 6;
  int wm = wv & 1, wn = wv >> 1;
  int ar = tid >> 2, aseg = tid & 3;
  int bkq = tid & 3, bn2 = tid >> 2;
  int aoff[2], boff[4];
  #pragma unroll
  for(int fi=0; fi<2; fi++) aoff[fi] = lswz(wm*32 + fi*16 + (lane&15), lane>>4);
  #pragma unroll
  for(int fj=0; fj<4; fj++) boff[fj] = lswz(wn*64 + fj*16 + (lane&15), lane>>4);
  const float* arow = A + (size_t)(m0+ar)*lda + aseg*8;

  for(int k0=0; k0<K; k0+=BK){
    {
      float4 v0 = *(const float4*)(arow + k0);
      float4 v1 = *(const float4*)(arow + k0 + 4);
      bf16x8 h, l;
      unsigned p;
      p = fsplit2(v0.x); h[0]=(short)(p&0xffff); l[0]=(short)(p>>16);
      p = fsplit2(v0.y); h[1]=(short)(p&0xffff); l[1]=(short)(p>>16);
      p = fsplit2(v0.z); h[2]=(short)(p&0xffff); l[2]=(short)(p>>16);
      p = fsplit2(v0.w); h[3]=(short)(p&0xffff); l[3]=(short)(p>>16);
      p = fsplit2(v1.x); h[4]=(short)(p&0xffff); l[4]=(short)(p>>16);
      p = fsplit2(v1.y); h[5]=(short)(p&0xffff); l[5]=(short)(p>>16);
      p = fsplit2(v1.z); h[6]=(short)(p&0xffff); l[6]=(short)(p>>16);
      p = fsplit2(v1.w); h[7]=(short)(p&0xffff); l[7]=(short)(p>>16);
      *(bf16x8*)((char*)AsH + lswz(ar, aseg)) = h;
      *(bf16x8*)((char*)AsL + lswz(ar, aseg)) = l;
    }
    {
      int kk = k0 + bkq*8;
      const float* wp = (kk < ksplit) ? (W0 + (size_t)kk*N) : (W1 + (size_t)(kk-ksplit)*N);
      wp += n0 + bn2*2;
      bf16x8 h0,l0,h1,l1;
      #pragma unroll
      for(int i=0;i<8;i++){
        float2 w = *(const float2*)(wp + (size_t)i*N);
        unsigned p0 = fsplit2(w.x);
        unsigned p1 = fsplit2(w.y);
        h0[i]=(short)(p0&0xffff); l0[i]=(short)(p0>>16);
        h1[i]=(short)(p1&0xffff); l1[i]=(short)(p1>>16);
      }
      *(bf16x8*)((char*)BsH + lswz(bn2*2,   bkq)) = h0;
      *(bf16x8*)((char*)BsL + lswz(bn2*2,   bkq)) = l0;
      *(bf16x8*)((char*)BsH + lswz(bn2*2+1, bkq)) = h1;
      *(bf16x8*)((char*)BsL + lswz(bn2*2+1, bkq)) = l1;
    }
    __syncthreads();
    bf16x8 ah[2], al[2], bh[4], bl[4];
    #pragma unroll
    for(int fi=0; fi<2; fi++){
      ah[fi] = *(const bf16x8*)((const char*)AsH + aoff[fi]);
      al[fi] = *(const bf16x8*)((const char*)AsL + aoff[fi]);
    }
    #pragma unroll
    for(int fj=0; fj<4; fj++){
      bh[fj] = *(const bf16x8*)((const char*)BsH + boff[fj]);
      bl[fj] = *(const bf16x8*)((const char*)BsL + boff[fj]);
    }
    #pragma unroll
    for(int fi=0; fi<2; fi++)
      #pragma unroll
      for(int fj=0; fj<4; fj++){
        acc[fi][fj] = __builtin_amdgcn_mfma_f32_16x16x32_bf16(ah[fi], bh[fj], acc[fi][fj], 0, 0, 0);
        acc[fi][fj] = __builtin_amdgcn_mfma_f32_16x16x32_bf16(ah[fi], bl[fj], acc[fi][fj], 0, 0, 0);
        acc[fi][fj] = __builtin_amdgcn_mfma_f32_16x16x32_bf16(al[fi], bh[fj], acc[fi][fj], 0, 0, 0);
      }
    __syncthreads();
  }
}

// ================= fused QKV (common + unique), split precision, f32 out =================
struct PtrArr6 { const float* w[6]; const float* b[6]; };

__global__ __launch_bounds__(256) void mm3_qkv(const float* __restrict__ x, PtrArr6 pa,
    const int* __restrict__ routeb, float* __restrict__ qkvout)
{
  int n0 = blockIdx.x*BN, m0 = blockIdx.y*BM, z = blockIdx.z;
  int bidx = m0 >> 7;
  const float* W = pa.w[z]; const float* bias = pa.b[z];
  if(z >= 3){ int e = routeb[bidx]; W += (size_t)e*Dm*Dm; bias += (size_t)e*Dm; }
  __shared__ short AsH[BM*BK], AsL[BM*BK];
  __shared__ short BsH[BN*BK], BsL[BN*BK];
  f32x4 acc[2][4] = {};
  mm_tile3(x, Dm, m0, W, nullptr, 1<<30, Dm, Dm, n0, AsH, AsL, BsH, BsL, acc);
  float* outp = qkvout + (size_t)z*NT*Dm;
  int lane = threadIdx.x&63, wv = threadIdx.x>>6, wm = wv&1, wn = wv>>1;
  #pragma unroll
  for(int fi=0; fi<2; fi++)
    #pragma unroll
    for(int fj=0; fj<4; fj++)
      #pragma unroll
      for(int r=0; r<4; r++){
        int row = m0 + wm*32 + fi*16 + ((lane>>4)<<2) + r;
        int col = n0 + wn*64 + fj*16 + (lane&15);
        outp[(size_t)row*Dm + col] = acc[fi][fj][r] + bias[col];
      }
}

// ================= fused output projection (split, K=1536) =================
__global__ __launch_bounds__(256) void mm3_outproj(const float* __restrict__ ctx,
    const float* __restrict__ ca_wo, const float* __restrict__ ua_wo,
    const float* __restrict__ ca_bo, const float* __restrict__ ua_bo,
    const int* __restrict__ routeb, const float* __restrict__ pmaxb,
    float* __restrict__ att, short* __restrict__ attbf)
{
  int n0 = blockIdx.x*BN, m0 = blockIdx.y*BM;
  int bidx = m0 >> 7;
  int e = routeb[bidx];
  float pm = pmaxb[bidx];
  __shared__ short AsH[BM*BK], AsL[BM*BK];
  __shared__ short BsH[BN*BK], BsL[BN*BK];
  f32x4 acc[2][4] = {};
  mm_tile3(ctx, 1536, m0, ca_wo, ua_wo + (size_t)e*Dm*Dm, Dm, Dm, 1536, n0, AsH, AsL, BsH, BsL, acc);
  int lane = threadIdx.x&63, wv = threadIdx.x>>6, wm = wv&1, wn = wv>>1;
  #pragma unroll
  for(int fi=0; fi<2; fi++)
    #pragma unroll
    for(int fj=0; fj<4; fj++)
      #pragma unroll
      for(int r=0; r<4; r++){
        int row = m0 + wm*32 + fi*16 + ((lane>>4)<<2) + r;
        int col = n0 + wn*64 + fj*16 + (lane&15);
        float v = acc[fi][fj][r] + ca_bo[col] + pm*ua_bo[(size_t)e*Dm + col];
        att[(size_t)row*Dm + col] = v;
        attbf[(size_t)row*Dm + col] = (short)f2bf(v);
      }
}

// ================= plain FFN GEMM =================
__global__ __launch_bounds__(256) void mm_ffn(const short* __restrict__ Abf, int lda,
    const float* __restrict__ W, const float* __restrict__ bias, int N, int K,
    float* __restrict__ outf, short* __restrict__ outb, int dogelu)
{
  int n0 = blockIdx.x*BN, m0 = blockIdx.y*BM;
  __shared__ short As[BM*BK];
  __shared__ short Bs[BN*BK];
  f32x4 acc[2][4] = {};
  mm_tile(Abf, lda, nullptr, m0, W, N, K, n0, As, Bs, acc);
  int lane = threadIdx.x&63, wv = threadIdx.x>>6, wm = wv&1, wn = wv>>1;
  #pragma unroll
  for(int fi=0; fi<2; fi++)
    #pragma unroll
    for(int fj=0; fj<4; fj++)
      #pragma unroll
      for(int r=0; r<4; r++){
        int row = m0 + wm*32 + fi*16 + ((lane>>4)<<2) + r;
        int col = n0 + wn*64 + fj*16 + (lane&15);
        float v = acc[fi][fj][r] + bias[col];
        if(dogelu) v = gelu_f(v);
        if(outf) outf[(size_t)row*N + col] = v;
        if(outb) outb[(size_t)row*N + col] = (short)f2bf(v);
      }
}

// ================= grouped Switch-FFN GEMM1: gather att rows -> compact h =================
__global__ __launch_bounds__(256) void mm_grp1(const short* __restrict__ attbf,
    const float* __restrict__ uf_w1, const float* __restrict__ uf_b1,
    const int* __restrict__ idxl, const int* __restrict__ gbase, const int* __restrict__ gcnt,
    short* __restrict__ hg)
{
  int g = blockIdx.y & 15, t = blockIdx.y >> 4;
  int cnt = gcnt[g];
  int r0 = t*BM;
  if(r0 >= cnt) return;
  int n0 = blockIdx.x*BN;
  int tid = threadIdx.x;
  __shared__ int rows[BM];
  if(tid < BM) rows[tid] = (r0 + tid < cnt) ? idxl[gbase[g] + r0 + tid] : -1;
  __syncthreads();
  const float* W = uf_w1 + (size_t)g*Dm*Fm;
  const float* bias = uf_b1 + (size_t)g*Fm;
  __shared__ short As[BM*BK];
  __shared__ short Bs[BN*BK];
  f32x4 acc[2][4] = {};
  mm_tile(attbf, Dm, rows, 0, W, Fm, Dm, n0, As, Bs, acc);
  int lane = tid&63, wv = tid>>6, wm = wv&1, wn = wv>>1;
  int pos0 = gbase[g] + r0;
  #pragma unroll
  for(int fi=0; fi<2; fi++)
    #pragma unroll
    for(int fj=0; fj<4; fj++)
      #pragma unroll
      for(int r=0; r<4; r++){
        int lr = wm*32 + fi*16 + ((lane>>4)<<2) + r;
        if(r0 + lr >= cnt) continue;
        int col = n0 + wn*64 + fj*16 + (lane&15);
        hg[(size_t)(pos0+lr)*Fm + col] = (short)f2bf(gelu_f(acc[fi][fj][r] + bias[col]));
      }
}

// ================= grouped Switch-FFN GEMM2: compact h -> scatter y (scaled) =================
__global__ __launch_bounds__(256) void mm_grp2(const short* __restrict__ hg,
    const float* __restrict__ uf_w2, const float* __restrict__ uf_b2,
    const int* __restrict__ idxl, const int* __restrict__ gbase, const int* __restrict__ gcnt,
    const float* __restrict__ tokp, float* __restrict__ yuo)
{
  int g = blockIdx.y & 15, t = blockIdx.y >> 4;
  int cnt = gcnt[g];
  int r0 = t*BM;
  if(r0 >= cnt) return;
  int n0 = blockIdx.x*BN;
  int tid = threadIdx.x;
  int pos0 = gbase[g] + r0;
  __shared__ int rows[BM];
  __shared__ int orows[BM];
  if(tid < BM){
    int ok = (r0 + tid < cnt);
    rows[tid]  = ok ? (pos0 + tid) : -1;
    orows[tid] = ok ? idxl[pos0 + tid] : -1;
  }
  __syncthreads();
  const float* W = uf_w2 + (size_t)g*Fm*Dm;
  const float* bias = uf_b2 + (size_t)g*Dm;
  __shared__ short As[BM*BK];
  __shared__ short Bs[BN*BK];
  f32x4 acc[2][4] = {};
  mm_tile(hg, Fm, rows, 0, W, Dm, Fm, n0, As, Bs, acc);
  int lane = tid&63, wv = tid>>6, wm = wv&1, wn = wv>>1;
  #pragma unroll
  for(int fi=0; fi<2; fi++)
    #pragma unroll
    for(int fj=0; fj<4; fj++)
      #pragma unroll
      for(int r=0; r<4; r++){
        int lr = wm*32 + fi*16 + ((lane>>4)<<2) + r;
        int rm = orows[lr];
        if(rm < 0) continue;
        int col = n0 + wn*64 + fj*16 + (lane&15);
        yuo[(size_t)rm*Dm + col] = (acc[fi][fj][r] + bias[col]) * tokp[rm];
      }
}

// ================= batch-level routing =================
__global__ __launch_bounds__(256) void k_route_batch(const float* __restrict__ xf,
    const float* __restrict__ sw_w, const float* __restrict__ sw_b,
    float* __restrict__ pmax_b, int* __restrict__ route_b){
  int b = blockIdx.x, tid = threadIdx.x;
  __shared__ float xm[Dm];
  for(int d=tid; d<Dm; d+=256){
    float s=0.f;
    const float* xp = xf + ((size_t)b*Sm)*Dm + d;
    for(int ss=0; ss<Sm; ss++) s += xp[(size_t)ss*Dm];
    xm[d] = s*(1.0f/Sm);
  }
  __syncthreads();
  float a0=0,a1=0,a2=0,a3=0;
  for(int d=tid; d<Dm; d+=256){
    float xv = xm[d];
    a0 += xv*sw_w[d*4+0]; a1 += xv*sw_w[d*4+1];
    a2 += xv*sw_w[d*4+2]; a3 += xv*sw_w[d*4+3];
  }
  __shared__ float red[4][256];
  red[0][tid]=a0; red[1][tid]=a1; red[2][tid]=a2; red[3][tid]=a3;
  for(int off=128; off>0; off>>=1){
    __syncthreads();
    if(tid<off){ for(int u=0;u<4;u++) red[u][tid]+=red[u][tid+off]; }
  }
  __syncthreads();
  if(tid==0){
    float l[4]; for(int u=0;u<4;u++) l[u]=red[u][0]+sw_b[u];
    float m=l[0]; int arg=0;
    for(int u=1;u<4;u++) if(l[u]>m){ m=l[u]; arg=u; }
    float s=0; for(int u=0;u<4;u++) s+=expf(l[u]-m);
    pmax_b[b]=1.0f/s;
    route_b[b]=arg;
  }
}

// ================= attention (f32 in/out; ctx -> [2048][1536], unique pre-scaled) =================
__global__ __launch_bounds__(256) void k_attn_f(const float* __restrict__ qkv,
    const float* __restrict__ mask, const float* __restrict__ pmaxb, float* __restrict__ ctx)
{
  int h = blockIdx.x, b = blockIdx.y, z = blockIdx.z;
  int qh = z & 1, kind = z >> 1;
  const float* Q  = qkv + (size_t)(kind*3+0)*NT*Dm;
  const float* Kp = qkv + (size_t)(kind*3+1)*NT*Dm;
  const float* Vp = qkv + (size_t)(kind*3+2)*NT*Dm;
  int tid = threadIdx.x;
  __shared__ float kv[128][64];
  __shared__ float sS[64][128];
  size_t base = ((size_t)b*Sm)*Dm + h*DHm;
  for(int l=tid; l<2048; l+=256){
    int s=l>>4, d0=(l&15)*4;
    float4 v = *(const float4*)(Kp + base + (size_t)s*Dm + d0);
    kv[s][d0]=v.x; kv[s][d0+1]=v.y; kv[s][d0+2]=v.z; kv[s][d0+3]=v.w;
  }
  __syncthreads();
  int ql = tid>>2, quarter = tid&3;
  int qi = qh*64 + ql;
  float qreg[64];
  const float* qp = Q + base + (size_t)qi*Dm;
  #pragma unroll
  for(int d=0; d<64; d++) qreg[d] = qp[d];
  int kb = quarter*32;
  for(int ki=kb; ki<kb+32; ki++){
    float s=0.f;
    #pragma unroll
    for(int d=0; d<64; d++) s += qreg[d]*kv[ki][d];
    sS[ql][ki] = s*0.125f + mask[b*Sm+ki];
  }
  __syncthreads();
  if(tid < 64){
    float m = -3.4e38f;
    for(int ki=0; ki<128; ki++) m = fmaxf(m, sS[tid][ki]);
    float sum = 0.f;
    for(int ki=0; ki<128; ki++){ float e = expf(sS[tid][ki]-m); sS[tid][ki]=e; sum+=e; }
    float inv = 1.0f/sum;
    for(int ki=0; ki<128; ki++) sS[tid][ki] *= inv;
  }
  __syncthreads();
  for(int l=tid; l<2048; l+=256){
    int s=l>>4, d0=(l&15)*4;
    float4 v = *(const float4*)(Vp + base + (size_t)s*Dm + d0);
    kv[s][d0]=v.x; kv[s][d0+1]=v.y; kv[s][d0+2]=v.z; kv[s][d0+3]=v.w;
  }
  __syncthreads();
  float sc = kind ? pmaxb[b] : 1.0f;
  int d0 = quarter*16;
  for(int d=d0; d<d0+16; d++){
    float s=0.f;
    for(int ki=0; ki<128; ki++) s += sS[ql][ki]*kv[ki][d];
    ctx[((size_t)b*Sm + qi)*1536 + kind*Dm + h*DHm + d] = s*sc;
  }
}

// ================= token-level Switch routing =================
__global__ __launch_bounds__(256) void k_tok_route(const float* __restrict__ att,
    const float* __restrict__ ur_w, const float* __restrict__ ur_b,
    const int* __restrict__ route_b, float* __restrict__ tok_pmax,
    int* __restrict__ tok_e, int* __restrict__ grp_count)
{
  int n = blockIdx.x, tid = threadIdx.x;
  int i = route_b[n>>7];
  const float* w = ur_w + (size_t)i*Dm*4;
  const float* ap = att + (size_t)n*Dm;
  float a0=0,a1=0,a2=0,a3=0;
  for(int d=tid; d<Dm; d+=256){
    float a = ap[d];
    a0 += a*w[d*4+0]; a1 += a*w[d*4+1];
    a2 += a*w[d*4+2]; a3 += a*w[d*4+3];
  }
  __shared__ float red[4][256];
  red[0][tid]=a0; red[1][tid]=a1; red[2][tid]=a2; red[3][tid]=a3;
  for(int off=128; off>0; off>>=1){
    __syncthreads();
    if(tid<off){ for(int u=0;u<4;u++) red[u][tid]+=red[u][tid+off]; }
  }
  __syncthreads();
  if(tid==0){
    float l[4]; for(int u=0;u<4;u++) l[u]=red[u][0]+ur_b[i*4+u];
    float m=l[0]; int arg=0;
    for(int u=1;u<4;u++) if(l[u]>m){ m=l[u]; arg=u; }
    float s=0; for(int u=0;u<4;u++) s+=expf(l[u]-m);
    tok_pmax[n] = 1.0f/s;
    tok_e[n] = arg;
    atomicAdd(&grp_count[i*4+arg], 1);
  }
}

__global__ void k_prefix(const int* __restrict__ cnt, int* __restrict__ base, int* __restrict__ cur){
  if(threadIdx.x==0 && blockIdx.x==0){
    int s=0;
    for(int g=0; g<16; g++){ base[g]=s; cur[g]=s; s+=cnt[g]; }
  }
}

__global__ void k_scatter(const int* __restrict__ route_b, const int* __restrict__ tok_e,
                          int* __restrict__ cur, int* __restrict__ idxl){
  int n = blockIdx.x*256 + threadIdx.x;
  if(n < NT){
    int g = route_b[n>>7]*4 + tok_e[n];
    int pos = atomicAdd(&cur[g], 1);
    idxl[pos] = n;
  }
}

// ================= final residual add + LayerNorm =================
__global__ __launch_bounds__(256) void k_final_ln(const float* __restrict__ att,
    const float* __restrict__ ycf, const float* __restrict__ yu,
    const float* __restrict__ ln_g, const float* __restrict__ ln_b, float* __restrict__ out)
{
  int n = blockIdx.x, tid = threadIdx.x;
  __shared__ float yb[Dm];
  __shared__ float red[256];
  size_t base = (size_t)n*Dm;
  float ps = 0.f;
  for(int d=tid; d<Dm; d+=256){
    float v = att[base+d] + ycf[base+d] + yu[base+d];
    yb[d]=v; ps+=v;
  }
  red[tid]=ps;
  for(int off=128; off>0; off>>=1){ __syncthreads(); if(tid<off) red[tid]+=red[tid+off]; }
  __syncthreads();
  float mu = red[0]*(1.0f/Dm);
  __syncthreads();
  float pv = 0.f;
  for(int d=tid; d<Dm; d+=256){ float t = yb[d]-mu; pv += t*t; }
  red[tid]=pv;
  for(int off=128; off>0; off>>=1){ __syncthreads(); if(tid<off) red[tid]+=red[tid+off]; }
  __syncthreads();
  float var = red[0]*(1.0f/Dm);
  float rstd = rsqrtf(var + 1e-12f);
  for(int d=tid; d<Dm; d+=256){
    out[base+d] = (yb[d]-mu)*rstd*ln_g[d] + ln_b[d];
  }
}

extern "C" void kernel_launch(void* const* d_in, const int* in_sizes, int n_in,
                              void* d_out, int out_size, void* d_ws, size_t ws_size,
                              hipStream_t stream)
{
  const float* x     =(const float*)d_in[0];
  const float* mask  =(const float*)d_in[1];
  const float* sw_w  =(const float*)d_in[2];
  const float* sw_b  =(const float*)d_in[3];
  const float* ca_wq =(const float*)d_in[4];
  const float* ca_bq =(const float*)d_in[5];
  const float* ca_wk =(const float*)d_in[6];
  const float* ca_bk =(const float*)d_in[7];
  const float* ca_wv =(const float*)d_in[8];
  const float* ca_bv =(const float*)d_in[9];
  const float* ca_wo =(const float*)d_in[10];
  const float* ca_bo =(const float*)d_in[11];
  const float* ua_wq =(const float*)d_in[12];
  const float* ua_bq =(const float*)d_in[13];
  const float* ua_wk =(const float*)d_in[14];
  const float* ua_bk =(const float*)d_in[15];
  const float* ua_wv =(const float*)d_in[16];
  const float* ua_bv =(const float*)d_in[17];
  const float* ua_wo =(const float*)d_in[18];
  const float* ua_bo =(const float*)d_in[19];
  const float* cf_w1 =(const float*)d_in[20];
  const float* cf_b1 =(const float*)d_in[21];
  const float* cf_w2 =(const float*)d_in[22];
  const float* cf_b2 =(const float*)d_in[23];
  const float* ur_w  =(const float*)d_in[24];
  const float* ur_b  =(const float*)d_in[25];
  const float* uf_w1 =(const float*)d_in[26];
  const float* uf_b1 =(const float*)d_in[27];
  const float* uf_w2 =(const float*)d_in[28];
  const float* uf_b2 =(const float*)d_in[29];
  const float* ln_g  =(const float*)d_in[30];
  const float* ln_b  =(const float*)d_in[31];

  // ---- workspace (phase-aliased region of 8*NT*Dm floats = 50.3MB) ----
  // phase A: qkv f32 [6][NT][Dm] | ctx f32 [NT][1536]
  // phase B: h_bf [NT][Fm] bf16 | hg_bf [NT][Fm] bf16 | ycf f32 | yuo f32
  float* region = (float*)d_ws;
  float* qkv = region;                                 // 6*NT*Dm f32
  float* ctx = region + (size_t)6*NT*Dm;               // NT*1536 f32
  short* h_bf  = (short*)region;                       // NT*Fm bf16
  short* hg_bf = (short*)region + (size_t)NT*Fm;       // NT*Fm bf16
  float* ycf   = (float*)((short*)region + (size_t)2*NT*Fm);   // NT*Dm f32
  float* yuo   = ycf + (size_t)NT*Dm;                  // NT*Dm f32
  float* fp    = region + (size_t)8*NT*Dm;             // end of region
  float* att   = fp; fp += (size_t)NT*Dm;
  float* tokp  = fp; fp += NT;
  float* pmaxb = fp; fp += 16;
  short* att_bf = (short*)fp;
  int*   ip     = (int*)(att_bf + (size_t)NT*Dm);
  int* routeb = ip; ip += 16;
  int* toke   = ip; ip += NT;
  int* gcnt   = ip; ip += 16;
  int* gbase  = ip; ip += 16;
  int* gcur   = ip; ip += 16;
  int* idxl   = ip; ip += NT;
  size_t need = (size_t)((char*)ip - (char*)d_ws);
  if(need > ws_size) return;   // bail visibly (output stays 0)

  (void)hipMemsetAsync(gcnt, 0, 48*sizeof(int), stream);   // gcnt, gbase, gcur

  k_route_batch<<<16, 256, 0, stream>>>(x, sw_w, sw_b, pmaxb, routeb);

  // fused QKV (split precision): z = {cq,ck,cv,uq,uk,uv}
  PtrArr6 pa;
  pa.w[0]=ca_wq; pa.w[1]=ca_wk; pa.w[2]=ca_wv; pa.w[3]=ua_wq; pa.w[4]=ua_wk; pa.w[5]=ua_wv;
  pa.b[0]=ca_bq; pa.b[1]=ca_bk; pa.b[2]=ca_bv; pa.b[3]=ua_bq; pa.b[4]=ua_bk; pa.b[5]=ua_bv;
  mm3_qkv<<<dim3(Dm/BN, NT/BM, 6), 256, 0, stream>>>(x, pa, routeb, qkv);

  // attention (f32): z = qh + 2*kind
  k_attn_f<<<dim3(Hm, Bm, 4), 256, 0, stream>>>(qkv, mask, pmaxb, ctx);

  // fused output projection (split precision, K=1536)
  mm3_outproj<<<dim3(Dm/BN, NT/BM), 256, 0, stream>>>(ctx, ca_wo, ua_wo, ca_bo, ua_bo,
                                                      routeb, pmaxb, att, att_bf);

  // token routing + grouping (from f32 att -> flip-safe)
  k_tok_route<<<NT, 256, 0, stream>>>(att, ur_w, ur_b, routeb, tokp, toke, gcnt);
  k_prefix<<<1, 64, 0, stream>>>(gcnt, gbase, gcur);
  k_scatter<<<NT/256, 256, 0, stream>>>(routeb, toke, gcur, idxl);

  // common FFN (plain bf16 MFMA)
  mm_ffn<<<dim3(Fm/BN, NT/BM), 256, 0, stream>>>(att_bf, Dm, cf_w1, cf_b1, Fm, Dm,
                                                 nullptr, h_bf, 1);
  mm_ffn<<<dim3(Dm/BN, NT/BM), 256, 0, stream>>>(h_bf, Fm, cf_w2, cf_b2, Dm, Fm,
                                                 ycf, nullptr, 0);

  // unique Switch FFN (grouped, plain bf16 MFMA)
  mm_grp1<<<dim3(Fm/BN, 512), 256, 0, stream>>>(att_bf, uf_w1, uf_b1, idxl, gbase, gcnt, hg_bf);
  mm_grp2<<<dim3(Dm/BN, 512), 256, 0, stream>>>(hg_bf, uf_w2, uf_b2, idxl, gbase, gcnt, tokp, yuo);

  k_final_ln<<<NT, 256, 0, stream>>>(att, ycf, yuo, ln_g, ln_b, (float*)d_out);
}

// Round 6
// 871.516 us; speedup vs baseline: 3.8678x; 1.1882x over previous
//
#include <hip/hip_runtime.h>

#define NT 2048
#define Dm 768
#define Fm 3072
#define Bm 16
#define Sm 128
#define Hm 12
#define DHm 64

#define BM 64
#define BN 128
#define BK 32

typedef __attribute__((ext_vector_type(8))) short bf16x8;
typedef __attribute__((ext_vector_type(4))) float f32x4;

__device__ __forceinline__ unsigned short f2bf(float f){
  unsigned u = __float_as_uint(f);
  unsigned r = (u + 0x7fffu + ((u>>16)&1u)) >> 16;   // round-nearest-even
  return (unsigned short)r;
}
__device__ __forceinline__ float bf2f(unsigned short h){ return __uint_as_float(((unsigned)h)<<16); }
// split f32 into hi/lo bf16 pair, packed: hi = bits[15:0], lo = bits[31:16]
__device__ __forceinline__ unsigned fsplit2(float x){
  unsigned short h = f2bf(x);
  unsigned short l = f2bf(x - bf2f(h));
  return (unsigned)h | ((unsigned)l << 16);
}
__device__ __forceinline__ float gelu_f(float x){
  return 0.5f*x*(1.0f + erff(x*0.70710678118654752f));
}
// byte offset of 8-elem k-group (row,kg) in a [rows][32]-bf16 LDS tile (64B/row);
// XOR swizzle spreads same-kg column reads across banks (2-way residual = free).
__device__ __forceinline__ int lswz(int row, int kg){
  return (row<<6) | (((kg ^ ((row>>1)&3))&3)<<4);
}

// ================= plain bf16 MFMA tile loop (post-routing GEMMs) =================
__device__ __forceinline__ void mm_tile(
    const short* __restrict__ Abf, int lda, const int* rowsLds, int m0,
    const float* __restrict__ W0, int N, int K, int n0,
    short* As, short* Bs, f32x4 acc[2][4])
{
  int tid = threadIdx.x;
  int lane = tid & 63, wv = tid >> 6;
  int wm = wv & 1, wn = wv >> 1;
  int ar = tid >> 2, aseg = tid & 3;
  int bkq = tid & 3, bn2 = tid >> 2;
  int grow = rowsLds ? rowsLds[ar] : (m0 + ar);
  int aoff[2], boff[4];
  #pragma unroll
  for(int fi=0; fi<2; fi++) aoff[fi] = lswz(wm*32 + fi*16 + (lane&15), lane>>4);
  #pragma unroll
  for(int fj=0; fj<4; fj++) boff[fj] = lswz(wn*64 + fj*16 + (lane&15), lane>>4);

  for(int k0=0; k0<K; k0+=BK){
    {
      bf16x8 av = {0,0,0,0,0,0,0,0};
      if(grow >= 0) av = *(const bf16x8*)(Abf + (size_t)grow*lda + k0 + aseg*8);
      *(bf16x8*)((char*)As + lswz(ar, aseg)) = av;
    }
    {
      int kk = k0 + bkq*8;
      const float* wp = W0 + (size_t)kk*N + n0 + bn2*2;
      bf16x8 v0, v1;
      #pragma unroll
      for(int i=0;i<8;i++){
        float2 w = *(const float2*)(wp + (size_t)i*N);
        v0[i] = (short)f2bf(w.x);
        v1[i] = (short)f2bf(w.y);
      }
      *(bf16x8*)((char*)Bs + lswz(bn2*2,   bkq)) = v0;
      *(bf16x8*)((char*)Bs + lswz(bn2*2+1, bkq)) = v1;
    }
    __syncthreads();
    bf16x8 af[2], bfr[4];
    #pragma unroll
    for(int fi=0; fi<2; fi++) af[fi] = *(const bf16x8*)((const char*)As + aoff[fi]);
    #pragma unroll
    for(int fj=0; fj<4; fj++) bfr[fj] = *(const bf16x8*)((const char*)Bs + boff[fj]);
    #pragma unroll
    for(int fi=0; fi<2; fi++)
      #pragma unroll
      for(int fj=0; fj<4; fj++)
        acc[fi][fj] = __builtin_amdgcn_mfma_f32_16x16x32_bf16(af[fi], bfr[fj], acc[fi][fj], 0, 0, 0);
    __syncthreads();
  }
}

// ================= split-bf16 ("bf16x3") MFMA tile loop: ~f32 precision =================
__device__ __forceinline__ void mm_tile3(
    const float* __restrict__ A, int lda, int m0,
    const float* __restrict__ W0, const float* __restrict__ W1, int ksplit,
    int N, int K, int n0,
    short* AsH, short* AsL, short* BsH, short* BsL, f32x4 acc[2][4])
{
  int tid = threadIdx.x;
  int lane = tid & 63, wv = tid >> 6;
  int wm = wv & 1, wn = wv >> 1;
  int ar = tid >> 2, aseg = tid & 3;
  int bkq = tid & 3, bn2 = tid >> 2;
  int aoff[2], boff[4];
  #pragma unroll
  for(int fi=0; fi<2; fi++) aoff[fi] = lswz(wm*32 + fi*16 + (lane&15), lane>>4);
  #pragma unroll
  for(int fj=0; fj<4; fj++) boff[fj] = lswz(wn*64 + fj*16 + (lane&15), lane>>4);
  const float* arow = A + (size_t)(m0+ar)*lda + aseg*8;

  for(int k0=0; k0<K; k0+=BK){
    {
      float4 v0 = *(const float4*)(arow + k0);
      float4 v1 = *(const float4*)(arow + k0 + 4);
      bf16x8 h, l;
      unsigned p;
      p = fsplit2(v0.x); h[0]=(short)(p&0xffff); l[0]=(short)(p>>16);
      p = fsplit2(v0.y); h[1]=(short)(p&0xffff); l[1]=(short)(p>>16);
      p = fsplit2(v0.z); h[2]=(short)(p&0xffff); l[2]=(short)(p>>16);
      p = fsplit2(v0.w); h[3]=(short)(p&0xffff); l[3]=(short)(p>>16);
      p = fsplit2(v1.x); h[4]=(short)(p&0xffff); l[4]=(short)(p>>16);
      p = fsplit2(v1.y); h[5]=(short)(p&0xffff); l[5]=(short)(p>>16);
      p = fsplit2(v1.z); h[6]=(short)(p&0xffff); l[6]=(short)(p>>16);
      p = fsplit2(v1.w); h[7]=(short)(p&0xffff); l[7]=(short)(p>>16);
      *(bf16x8*)((char*)AsH + lswz(ar, aseg)) = h;
      *(bf16x8*)((char*)AsL + lswz(ar, aseg)) = l;
    }
    {
      int kk = k0 + bkq*8;
      const float* wp = (kk < ksplit) ? (W0 + (size_t)kk*N) : (W1 + (size_t)(kk-ksplit)*N);
      wp += n0 + bn2*2;
      bf16x8 h0,l0,h1,l1;
      #pragma unroll
      for(int i=0;i<8;i++){
        float2 w = *(const float2*)(wp + (size_t)i*N);
        unsigned p0 = fsplit2(w.x);
        unsigned p1 = fsplit2(w.y);
        h0[i]=(short)(p0&0xffff); l0[i]=(short)(p0>>16);
        h1[i]=(short)(p1&0xffff); l1[i]=(short)(p1>>16);
      }
      *(bf16x8*)((char*)BsH + lswz(bn2*2,   bkq)) = h0;
      *(bf16x8*)((char*)BsL + lswz(bn2*2,   bkq)) = l0;
      *(bf16x8*)((char*)BsH + lswz(bn2*2+1, bkq)) = h1;
      *(bf16x8*)((char*)BsL + lswz(bn2*2+1, bkq)) = l1;
    }
    __syncthreads();
    bf16x8 ah[2], al[2], bh[4], bl[4];
    #pragma unroll
    for(int fi=0; fi<2; fi++){
      ah[fi] = *(const bf16x8*)((const char*)AsH + aoff[fi]);
      al[fi] = *(const bf16x8*)((const char*)AsL + aoff[fi]);
    }
    #pragma unroll
    for(int fj=0; fj<4; fj++){
      bh[fj] = *(const bf16x8*)((const char*)BsH + boff[fj]);
      bl[fj] = *(const bf16x8*)((const char*)BsL + boff[fj]);
    }
    #pragma unroll
    for(int fi=0; fi<2; fi++)
      #pragma unroll
      for(int fj=0; fj<4; fj++){
        acc[fi][fj] = __builtin_amdgcn_mfma_f32_16x16x32_bf16(ah[fi], bh[fj], acc[fi][fj], 0, 0, 0);
        acc[fi][fj] = __builtin_amdgcn_mfma_f32_16x16x32_bf16(ah[fi], bl[fj], acc[fi][fj], 0, 0, 0);
        acc[fi][fj] = __builtin_amdgcn_mfma_f32_16x16x32_bf16(al[fi], bh[fj], acc[fi][fj], 0, 0, 0);
      }
    __syncthreads();
  }
}

// ================= fused QKV (common + unique), split precision, f32 out =================
struct PtrArr6 { const float* w[6]; const float* b[6]; };

__global__ __launch_bounds__(256) void mm3_qkv(const float* __restrict__ x, PtrArr6 pa,
    const int* __restrict__ routeb, float* __restrict__ qkvout)
{
  int n0 = blockIdx.x*BN, m0 = blockIdx.y*BM, z = blockIdx.z;
  int bidx = m0 >> 7;
  const float* W = pa.w[z]; const float* bias = pa.b[z];
  if(z >= 3){ int e = routeb[bidx]; W += (size_t)e*Dm*Dm; bias += (size_t)e*Dm; }
  __shared__ short AsH[BM*BK], AsL[BM*BK];
  __shared__ short BsH[BN*BK], BsL[BN*BK];
  f32x4 acc[2][4] = {};
  mm_tile3(x, Dm, m0, W, nullptr, 1<<30, Dm, Dm, n0, AsH, AsL, BsH, BsL, acc);
  float* outp = qkvout + (size_t)z*NT*Dm;
  int lane = threadIdx.x&63, wv = threadIdx.x>>6, wm = wv&1, wn = wv>>1;
  #pragma unroll
  for(int fi=0; fi<2; fi++)
    #pragma unroll
    for(int fj=0; fj<4; fj++)
      #pragma unroll
      for(int r=0; r<4; r++){
        int row = m0 + wm*32 + fi*16 + ((lane>>4)<<2) + r;
        int col = n0 + wn*64 + fj*16 + (lane&15);
        outp[(size_t)row*Dm + col] = acc[fi][fj][r] + bias[col];
      }
}

// ================= fused output projection (split, K=1536) =================
__global__ __launch_bounds__(256) void mm3_outproj(const float* __restrict__ ctx,
    const float* __restrict__ ca_wo, const float* __restrict__ ua_wo,
    const float* __restrict__ ca_bo, const float* __restrict__ ua_bo,
    const int* __restrict__ routeb, const float* __restrict__ pmaxb,
    float* __restrict__ att, short* __restrict__ attbf)
{
  int n0 = blockIdx.x*BN, m0 = blockIdx.y*BM;
  int bidx = m0 >> 7;
  int e = routeb[bidx];
  float pm = pmaxb[bidx];
  __shared__ short AsH[BM*BK], AsL[BM*BK];
  __shared__ short BsH[BN*BK], BsL[BN*BK];
  f32x4 acc[2][4] = {};
  mm_tile3(ctx, 1536, m0, ca_wo, ua_wo + (size_t)e*Dm*Dm, Dm, Dm, 1536, n0, AsH, AsL, BsH, BsL, acc);
  int lane = threadIdx.x&63, wv = threadIdx.x>>6, wm = wv&1, wn = wv>>1;
  #pragma unroll
  for(int fi=0; fi<2; fi++)
    #pragma unroll
    for(int fj=0; fj<4; fj++)
      #pragma unroll
      for(int r=0; r<4; r++){
        int row = m0 + wm*32 + fi*16 + ((lane>>4)<<2) + r;
        int col = n0 + wn*64 + fj*16 + (lane&15);
        float v = acc[fi][fj][r] + ca_bo[col] + pm*ua_bo[(size_t)e*Dm + col];
        att[(size_t)row*Dm + col] = v;
        attbf[(size_t)row*Dm + col] = (short)f2bf(v);
      }
}

// ================= F-stage: common FFN1 (y<32) + grouped Switch-FFN1 (tile list) =================
__global__ __launch_bounds__(256) void mm_fstage(const short* __restrict__ attbf,
    const float* __restrict__ cf_w1, const float* __restrict__ cf_b1,
    const float* __restrict__ uf_w1, const float* __restrict__ uf_b1,
    const int* __restrict__ idxl, const int* __restrict__ gbase, const int* __restrict__ gcnt,
    const int* __restrict__ tlist, const int* __restrict__ ntl,
    short* __restrict__ h, short* __restrict__ hg)
{
  int n0 = blockIdx.x*BN, y = blockIdx.y;
  int tid = threadIdx.x;
  __shared__ short As[BM*BK];
  __shared__ short Bs[BN*BK];
  int lane = tid&63, wv = tid>>6, wm = wv&1, wn = wv>>1;
  f32x4 acc[2][4] = {};
  if(y < 32){
    int m0 = y*BM;
    mm_tile(attbf, Dm, nullptr, m0, cf_w1, Fm, Dm, n0, As, Bs, acc);
    #pragma unroll
    for(int fi=0; fi<2; fi++)
      #pragma unroll
      for(int fj=0; fj<4; fj++)
        #pragma unroll
        for(int r=0; r<4; r++){
          int row = m0 + wm*32 + fi*16 + ((lane>>4)<<2) + r;
          int col = n0 + wn*64 + fj*16 + (lane&15);
          h[(size_t)row*Fm + col] = (short)f2bf(gelu_f(acc[fi][fj][r] + cf_b1[col]));
        }
  } else {
    int i = y - 32;
    if(i >= ntl[0]) return;
    int v = tlist[i], g = v>>8, t = v&255;
    int cnt = gcnt[g], r0 = t*BM, pos0 = gbase[g] + r0;
    __shared__ int rows[BM];
    if(tid < BM) rows[tid] = (r0 + tid < cnt) ? idxl[pos0 + tid] : -1;
    __syncthreads();
    mm_tile(attbf, Dm, rows, 0, uf_w1 + (size_t)g*Dm*Fm, Fm, Dm, n0, As, Bs, acc);
    const float* bias = uf_b1 + (size_t)g*Fm;
    #pragma unroll
    for(int fi=0; fi<2; fi++)
      #pragma unroll
      for(int fj=0; fj<4; fj++)
        #pragma unroll
        for(int r=0; r<4; r++){
          int lr = wm*32 + fi*16 + ((lane>>4)<<2) + r;
          if(r0 + lr >= cnt) continue;
          int col = n0 + wn*64 + fj*16 + (lane&15);
          hg[(size_t)(pos0+lr)*Fm + col] = (short)f2bf(gelu_f(acc[fi][fj][r] + bias[col]));
        }
  }
}

// ================= D-stage: split-K (z=kc of 2) common FFN2 + grouped FFN2 =================
// chunk kc writes its own partial buffer (deterministic); kc==0 adds bias.
__global__ __launch_bounds__(256) void mm_dstage(const short* __restrict__ h,
    const short* __restrict__ hg,
    const float* __restrict__ cf_w2, const float* __restrict__ cf_b2,
    const float* __restrict__ uf_w2, const float* __restrict__ uf_b2,
    const int* __restrict__ idxl, const int* __restrict__ gbase, const int* __restrict__ gcnt,
    const int* __restrict__ tlist, const int* __restrict__ ntl,
    const float* __restrict__ tokp, float* __restrict__ ycf2, float* __restrict__ yuo2)
{
  const int KC2 = Fm/2;   // 1536
  int n0 = blockIdx.x*BN, y = blockIdx.y, kc = blockIdx.z;
  int tid = threadIdx.x;
  __shared__ short As[BM*BK];
  __shared__ short Bs[BN*BK];
  int lane = tid&63, wv = tid>>6, wm = wv&1, wn = wv>>1;
  f32x4 acc[2][4] = {};
  if(y < 32){
    int m0 = y*BM;
    mm_tile(h + kc*KC2, Fm, nullptr, m0, cf_w2 + (size_t)kc*KC2*Dm, Dm, KC2, n0, As, Bs, acc);
    float* outp = ycf2 + (size_t)kc*NT*Dm;
    #pragma unroll
    for(int fi=0; fi<2; fi++)
      #pragma unroll
      for(int fj=0; fj<4; fj++)
        #pragma unroll
        for(int r=0; r<4; r++){
          int row = m0 + wm*32 + fi*16 + ((lane>>4)<<2) + r;
          int col = n0 + wn*64 + fj*16 + (lane&15);
          outp[(size_t)row*Dm + col] = acc[fi][fj][r] + (kc==0 ? cf_b2[col] : 0.f);
        }
  } else {
    int i = y - 32;
    if(i >= ntl[0]) return;
    int v = tlist[i], g = v>>8, t = v&255;
    int cnt = gcnt[g], r0 = t*BM, pos0 = gbase[g] + r0;
    __shared__ int rows[BM];
    __shared__ int orows[BM];
    if(tid < BM){
      int ok = (r0 + tid < cnt);
      rows[tid]  = ok ? (pos0 + tid) : -1;
      orows[tid] = ok ? idxl[pos0 + tid] : -1;
    }
    __syncthreads();
    mm_tile(hg + kc*KC2, Fm, rows, 0,
            uf_w2 + (size_t)g*Fm*Dm + (size_t)kc*KC2*Dm, Dm, KC2, n0, As, Bs, acc);
    const float* bias = uf_b2 + (size_t)g*Dm;
    float* outp = yuo2 + (size_t)kc*NT*Dm;
    #pragma unroll
    for(int fi=0; fi<2; fi++)
      #pragma unroll
      for(int fj=0; fj<4; fj++)
        #pragma unroll
        for(int r=0; r<4; r++){
          int lr = wm*32 + fi*16 + ((lane>>4)<<2) + r;
          int rm = orows[lr];
          if(rm < 0) continue;
          int col = n0 + wn*64 + fj*16 + (lane&15);
          float vv = acc[fi][fj][r] + (kc==0 ? bias[col] : 0.f);
          outp[(size_t)rm*Dm + col] = vv * tokp[rm];
        }
  }
}

// ================= batch-level routing =================
__global__ __launch_bounds__(256) void k_route_batch(const float* __restrict__ xf,
    const float* __restrict__ sw_w, const float* __restrict__ sw_b,
    float* __restrict__ pmax_b, int* __restrict__ route_b){
  int b = blockIdx.x, tid = threadIdx.x;
  __shared__ float xm[Dm];
  for(int d=tid; d<Dm; d+=256){
    float s=0.f;
    const float* xp = xf + ((size_t)b*Sm)*Dm + d;
    for(int ss=0; ss<Sm; ss++) s += xp[(size_t)ss*Dm];
    xm[d] = s*(1.0f/Sm);
  }
  __syncthreads();
  float a0=0,a1=0,a2=0,a3=0;
  for(int d=tid; d<Dm; d+=256){
    float xv = xm[d];
    a0 += xv*sw_w[d*4+0]; a1 += xv*sw_w[d*4+1];
    a2 += xv*sw_w[d*4+2]; a3 += xv*sw_w[d*4+3];
  }
  __shared__ float red[4][256];
  red[0][tid]=a0; red[1][tid]=a1; red[2][tid]=a2; red[3][tid]=a3;
  for(int off=128; off>0; off>>=1){
    __syncthreads();
    if(tid<off){ for(int u=0;u<4;u++) red[u][tid]+=red[u][tid+off]; }
  }
  __syncthreads();
  if(tid==0){
    float l[4]; for(int u=0;u<4;u++) l[u]=red[u][0]+sw_b[u];
    float m=l[0]; int arg=0;
    for(int u=1;u<4;u++) if(l[u]>m){ m=l[u]; arg=u; }
    float s=0; for(int u=0;u<4;u++) s+=expf(l[u]-m);
    pmax_b[b]=1.0f/s;
    route_b[b]=arg;
  }
}

// ================= attention (f32 in/out; ctx -> [2048][1536], unique pre-scaled) =================
__global__ __launch_bounds__(256) void k_attn_f(const float* __restrict__ qkv,
    const float* __restrict__ mask, const float* __restrict__ pmaxb, float* __restrict__ ctx)
{
  int h = blockIdx.x, b = blockIdx.y, z = blockIdx.z;
  int qh = z & 1, kind = z >> 1;
  const float* Q  = qkv + (size_t)(kind*3+0)*NT*Dm;
  const float* Kp = qkv + (size_t)(kind*3+1)*NT*Dm;
  const float* Vp = qkv + (size_t)(kind*3+2)*NT*Dm;
  int tid = threadIdx.x;
  __shared__ float kv[128][64];
  __shared__ float sS[64][128];
  size_t base = ((size_t)b*Sm)*Dm + h*DHm;
  for(int l=tid; l<2048; l+=256){
    int s=l>>4, d0=(l&15)*4;
    float4 v = *(const float4*)(Kp + base + (size_t)s*Dm + d0);
    kv[s][d0]=v.x; kv[s][d0+1]=v.y; kv[s][d0+2]=v.z; kv[s][d0+3]=v.w;
  }
  __syncthreads();
  int ql = tid>>2, quarter = tid&3;
  int qi = qh*64 + ql;
  float qreg[64];
  const float* qp = Q + base + (size_t)qi*Dm;
  #pragma unroll
  for(int d=0; d<64; d++) qreg[d] = qp[d];
  int kb = quarter*32;
  for(int ki=kb; ki<kb+32; ki++){
    float s=0.f;
    #pragma unroll
    for(int d=0; d<64; d++) s += qreg[d]*kv[ki][d];
    sS[ql][ki] = s*0.125f + mask[b*Sm+ki];
  }
  __syncthreads();
  if(tid < 64){
    float m = -3.4e38f;
    for(int ki=0; ki<128; ki++) m = fmaxf(m, sS[tid][ki]);
    float sum = 0.f;
    for(int ki=0; ki<128; ki++){ float e = expf(sS[tid][ki]-m); sS[tid][ki]=e; sum+=e; }
    float inv = 1.0f/sum;
    for(int ki=0; ki<128; ki++) sS[tid][ki] *= inv;
  }
  __syncthreads();
  for(int l=tid; l<2048; l+=256){
    int s=l>>4, d0=(l&15)*4;
    float4 v = *(const float4*)(Vp + base + (size_t)s*Dm + d0);
    kv[s][d0]=v.x; kv[s][d0+1]=v.y; kv[s][d0+2]=v.z; kv[s][d0+3]=v.w;
  }
  __syncthreads();
  float sc = kind ? pmaxb[b] : 1.0f;
  int d0 = quarter*16;
  for(int d=d0; d<d0+16; d++){
    float s=0.f;
    for(int ki=0; ki<128; ki++) s += sS[ql][ki]*kv[ki][d];
    ctx[((size_t)b*Sm + qi)*1536 + kind*Dm + h*DHm + d] = s*sc;
  }
}

// ================= token-level Switch routing =================
__global__ __launch_bounds__(256) void k_tok_route(const float* __restrict__ att,
    const float* __restrict__ ur_w, const float* __restrict__ ur_b,
    const int* __restrict__ route_b, float* __restrict__ tok_pmax,
    int* __restrict__ tok_e, int* __restrict__ grp_count)
{
  int n = blockIdx.x, tid = threadIdx.x;
  int i = route_b[n>>7];
  const float* w = ur_w + (size_t)i*Dm*4;
  const float* ap = att + (size_t)n*Dm;
  float a0=0,a1=0,a2=0,a3=0;
  for(int d=tid; d<Dm; d+=256){
    float a = ap[d];
    a0 += a*w[d*4+0]; a1 += a*w[d*4+1];
    a2 += a*w[d*4+2]; a3 += a*w[d*4+3];
  }
  __shared__ float red[4][256];
  red[0][tid]=a0; red[1][tid]=a1; red[2][tid]=a2; red[3][tid]=a3;
  for(int off=128; off>0; off>>=1){
    __syncthreads();
    if(tid<off){ for(int u=0;u<4;u++) red[u][tid]+=red[u][tid+off]; }
  }
  __syncthreads();
  if(tid==0){
    float l[4]; for(int u=0;u<4;u++) l[u]=red[u][0]+ur_b[i*4+u];
    float m=l[0]; int arg=0;
    for(int u=1;u<4;u++) if(l[u]>m){ m=l[u]; arg=u; }
    float s=0; for(int u=0;u<4;u++) s+=expf(l[u]-m);
    tok_pmax[n] = 1.0f/s;
    tok_e[n] = arg;
    atomicAdd(&grp_count[i*4+arg], 1);
  }
}

// ================= prefix + tile worklist =================
__global__ void k_prefix(const int* __restrict__ cnt, int* __restrict__ base,
                         int* __restrict__ cur, int* __restrict__ tlist, int* __restrict__ ntl){
  if(threadIdx.x==0 && blockIdx.x==0){
    int s=0, nt=0;
    for(int g=0; g<16; g++){
      base[g]=s; cur[g]=s;
      int tg = (cnt[g] + BM - 1)/BM;
      for(int t=0; t<tg; t++){ if(nt<64) tlist[nt++] = (g<<8)|t; }
      s += cnt[g];
    }
    ntl[0] = nt;
  }
}

__global__ void k_scatter(const int* __restrict__ route_b, const int* __restrict__ tok_e,
                          int* __restrict__ cur, int* __restrict__ idxl){
  int n = blockIdx.x*256 + threadIdx.x;
  if(n < NT){
    int g = route_b[n>>7]*4 + tok_e[n];
    int pos = atomicAdd(&cur[g], 1);
    idxl[pos] = n;
  }
}

// ================= final residual add + LayerNorm (sums split-K partials) =================
__global__ __launch_bounds__(256) void k_final_ln(const float* __restrict__ att,
    const float* __restrict__ ycf2, const float* __restrict__ yuo2,
    const float* __restrict__ ln_g, const float* __restrict__ ln_b, float* __restrict__ out)
{
  int n = blockIdx.x, tid = threadIdx.x;
  __shared__ float yb[Dm];
  __shared__ float red[256];
  size_t base = (size_t)n*Dm;
  const size_t P = (size_t)NT*Dm;
  float ps = 0.f;
  for(int d=tid; d<Dm; d+=256){
    float v = att[base+d] + ycf2[base+d] + ycf2[P+base+d] + yuo2[base+d] + yuo2[P+base+d];
    yb[d]=v; ps+=v;
  }
  red[tid]=ps;
  for(int off=128; off>0; off>>=1){ __syncthreads(); if(tid<off) red[tid]+=red[tid+off]; }
  __syncthreads();
  float mu = red[0]*(1.0f/Dm);
  __syncthreads();
  float pv = 0.f;
  for(int d=tid; d<Dm; d+=256){ float t = yb[d]-mu; pv += t*t; }
  red[tid]=pv;
  for(int off=128; off>0; off>>=1){ __syncthreads(); if(tid<off) red[tid]+=red[tid+off]; }
  __syncthreads();
  float var = red[0]*(1.0f/Dm);
  float rstd = rsqrtf(var + 1e-12f);
  for(int d=tid; d<Dm; d+=256){
    out[base+d] = (yb[d]-mu)*rstd*ln_g[d] + ln_b[d];
  }
}

extern "C" void kernel_launch(void* const* d_in, const int* in_sizes, int n_in,
                              void* d_out, int out_size, void* d_ws, size_t ws_size,
                              hipStream_t stream)
{
  const float* x     =(const float*)d_in[0];
  const float* mask  =(const float*)d_in[1];
  const float* sw_w  =(const float*)d_in[2];
  const float* sw_b  =(const float*)d_in[3];
  const float* ca_wq =(const float*)d_in[4];
  const float* ca_bq =(const float*)d_in[5];
  const float* ca_wk =(const float*)d_in[6];
  const float* ca_bk =(const float*)d_in[7];
  const float* ca_wv =(const float*)d_in[8];
  const float* ca_bv =(const float*)d_in[9];
  const float* ca_wo =(const float*)d_in[10];
  const float* ca_bo =(const float*)d_in[11];
  const float* ua_wq =(const float*)d_in[12];
  const float* ua_bq =(const float*)d_in[13];
  const float* ua_wk =(const float*)d_in[14];
  const float* ua_bk =(const float*)d_in[15];
  const float* ua_wv =(const float*)d_in[16];
  const float* ua_bv =(const float*)d_in[17];
  const float* ua_wo =(const float*)d_in[18];
  const float* ua_bo =(const float*)d_in[19];
  const float* cf_w1 =(const float*)d_in[20];
  const float* cf_b1 =(const float*)d_in[21];
  const float* cf_w2 =(const float*)d_in[22];
  const float* cf_b2 =(const float*)d_in[23];
  const float* ur_w  =(const float*)d_in[24];
  const float* ur_b  =(const float*)d_in[25];
  const float* uf_w1 =(const float*)d_in[26];
  const float* uf_b1 =(const float*)d_in[27];
  const float* uf_w2 =(const float*)d_in[28];
  const float* uf_b2 =(const float*)d_in[29];
  const float* ln_g  =(const float*)d_in[30];
  const float* ln_b  =(const float*)d_in[31];

  // ---- workspace (phase-aliased region of 8*NT*Dm f32 units = 50.3MB) ----
  // phase A: qkv f32 [6][NT][Dm] | ctx f32 [NT][1536]
  // phase B: h_bf [NT][Fm] bf16 | hg_bf [NT][Fm] bf16 | ycf2 f32[2][NT][Dm] | yuo2 f32[2][NT][Dm]
  float* region = (float*)d_ws;
  float* qkv = region;                                  // 6*NT*Dm f32
  float* ctx = region + (size_t)6*NT*Dm;                // NT*1536 f32
  short* h_bf  = (short*)region;                        // NT*Fm bf16
  short* hg_bf = (short*)region + (size_t)NT*Fm;        // NT*Fm bf16
  float* ycf2  = (float*)((short*)region + (size_t)2*NT*Fm);   // 2*NT*Dm f32
  float* yuo2  = ycf2 + (size_t)2*NT*Dm;                // 2*NT*Dm f32
  float* fp    = region + (size_t)8*NT*Dm;              // end of region
  float* att   = fp; fp += (size_t)NT*Dm;
  float* tokp  = fp; fp += NT;
  float* pmaxb = fp; fp += 16;
  short* att_bf = (short*)fp;
  int*   ip     = (int*)(att_bf + (size_t)NT*Dm);
  int* routeb = ip; ip += 16;
  int* toke   = ip; ip += NT;
  int* gcnt   = ip; ip += 16;
  int* gbase  = ip; ip += 16;
  int* gcur   = ip; ip += 16;
  int* idxl   = ip; ip += NT;
  int* tlist  = ip; ip += 64;
  int* ntl    = ip; ip += 1;
  size_t need = (size_t)((char*)ip - (char*)d_ws);
  if(need > ws_size) return;   // bail visibly (output stays 0)

  (void)hipMemsetAsync(gcnt, 0, 16*sizeof(int), stream);

  k_route_batch<<<16, 256, 0, stream>>>(x, sw_w, sw_b, pmaxb, routeb);

  // fused QKV (split precision): z = {cq,ck,cv,uq,uk,uv}
  PtrArr6 pa;
  pa.w[0]=ca_wq; pa.w[1]=ca_wk; pa.w[2]=ca_wv; pa.w[3]=ua_wq; pa.w[4]=ua_wk; pa.w[5]=ua_wv;
  pa.b[0]=ca_bq; pa.b[1]=ca_bk; pa.b[2]=ca_bv; pa.b[3]=ua_bq; pa.b[4]=ua_bk; pa.b[5]=ua_bv;
  mm3_qkv<<<dim3(Dm/BN, NT/BM, 6), 256, 0, stream>>>(x, pa, routeb, qkv);

  // attention (f32): z = qh + 2*kind
  k_attn_f<<<dim3(Hm, Bm, 4), 256, 0, stream>>>(qkv, mask, pmaxb, ctx);

  // fused output projection (split precision, K=1536)
  mm3_outproj<<<dim3(Dm/BN, NT/BM), 256, 0, stream>>>(ctx, ca_wo, ua_wo, ca_bo, ua_bo,
                                                      routeb, pmaxb, att, att_bf);

  // token routing + grouping (from f32 att -> flip-safe)
  k_tok_route<<<NT, 256, 0, stream>>>(att, ur_w, ur_b, routeb, tokp, toke, gcnt);
  k_prefix<<<1, 64, 0, stream>>>(gcnt, gbase, gcur, tlist, ntl);
  k_scatter<<<NT/256, 256, 0, stream>>>(routeb, toke, gcur, idxl);

  // F-stage: common FFN1 + grouped Switch-FFN1 in one dispatch
  mm_fstage<<<dim3(Fm/BN, 32+48), 256, 0, stream>>>(att_bf, cf_w1, cf_b1, uf_w1, uf_b1,
                                                    idxl, gbase, gcnt, tlist, ntl, h_bf, hg_bf);

  // D-stage: split-K (2 chunks) common FFN2 + grouped FFN2, partial buffers
  mm_dstage<<<dim3(Dm/BN, 32+48, 2), 256, 0, stream>>>(h_bf, hg_bf, cf_w2, cf_b2, uf_w2, uf_b2,
                                                       idxl, gbase, gcnt, tlist, ntl, tokp,
                                                       ycf2, yuo2);

  k_final_ln<<<NT, 256, 0, stream>>>(att, ycf2, yuo2, ln_g, ln_b, (float*)d_out);
}

// Round 7
// 828.193 us; speedup vs baseline: 4.0701x; 1.0523x over previous
//
#include <hip/hip_runtime.h>

#define NT 2048
#define Dm 768
#define Fm 3072
#define Bm 16
#define Sm 128
#define Hm 12
#define DHm 64

#define BM 64
#define BN 128
#define BK 32

typedef __attribute__((ext_vector_type(8))) short bf16x8;
typedef __attribute__((ext_vector_type(4))) float f32x4;

__device__ __forceinline__ unsigned short f2bf(float f){
  unsigned u = __float_as_uint(f);
  unsigned r = (u + 0x7fffu + ((u>>16)&1u)) >> 16;   // round-nearest-even
  return (unsigned short)r;
}
__device__ __forceinline__ float bf2f(unsigned short h){ return __uint_as_float(((unsigned)h)<<16); }
// split f32 into hi/lo bf16 pair, packed: hi = bits[15:0], lo = bits[31:16]
__device__ __forceinline__ unsigned fsplit2(float x){
  unsigned short h = f2bf(x);
  unsigned short l = f2bf(x - bf2f(h));
  return (unsigned)h | ((unsigned)l << 16);
}
__device__ __forceinline__ float gelu_f(float x){
  return 0.5f*x*(1.0f + erff(x*0.70710678118654752f));
}
// byte offset of 8-elem k-group (row,kg) in a [rows][32]-bf16 LDS tile (64B/row);
// XOR swizzle spreads same-kg column reads across banks (2-way residual = free).
__device__ __forceinline__ int lswz(int row, int kg){
  return (row<<6) | (((kg ^ ((row>>1)&3))&3)<<4);
}

// ================= plain bf16 MFMA tile loop (post-routing GEMMs) =================
__device__ __forceinline__ void mm_tile(
    const short* __restrict__ Abf, int lda, const int* rowsLds, int m0,
    const float* __restrict__ W0, int N, int K, int n0,
    short* As, short* Bs, f32x4 acc[2][4])
{
  int tid = threadIdx.x;
  int lane = tid & 63, wv = tid >> 6;
  int wm = wv & 1, wn = wv >> 1;
  int ar = tid >> 2, aseg = tid & 3;
  int bkq = tid & 3, bn2 = tid >> 2;
  int grow = rowsLds ? rowsLds[ar] : (m0 + ar);
  int aoff[2], boff[4];
  #pragma unroll
  for(int fi=0; fi<2; fi++) aoff[fi] = lswz(wm*32 + fi*16 + (lane&15), lane>>4);
  #pragma unroll
  for(int fj=0; fj<4; fj++) boff[fj] = lswz(wn*64 + fj*16 + (lane&15), lane>>4);

  for(int k0=0; k0<K; k0+=BK){
    {
      bf16x8 av = {0,0,0,0,0,0,0,0};
      if(grow >= 0) av = *(const bf16x8*)(Abf + (size_t)grow*lda + k0 + aseg*8);
      *(bf16x8*)((char*)As + lswz(ar, aseg)) = av;
    }
    {
      int kk = k0 + bkq*8;
      const float* wp = W0 + (size_t)kk*N + n0 + bn2*2;
      bf16x8 v0, v1;
      #pragma unroll
      for(int i=0;i<8;i++){
        float2 w = *(const float2*)(wp + (size_t)i*N);
        v0[i] = (short)f2bf(w.x);
        v1[i] = (short)f2bf(w.y);
      }
      *(bf16x8*)((char*)Bs + lswz(bn2*2,   bkq)) = v0;
      *(bf16x8*)((char*)Bs + lswz(bn2*2+1, bkq)) = v1;
    }
    __syncthreads();
    bf16x8 af[2], bfr[4];
    #pragma unroll
    for(int fi=0; fi<2; fi++) af[fi] = *(const bf16x8*)((const char*)As + aoff[fi]);
    #pragma unroll
    for(int fj=0; fj<4; fj++) bfr[fj] = *(const bf16x8*)((const char*)Bs + boff[fj]);
    #pragma unroll
    for(int fi=0; fi<2; fi++)
      #pragma unroll
      for(int fj=0; fj<4; fj++)
        acc[fi][fj] = __builtin_amdgcn_mfma_f32_16x16x32_bf16(af[fi], bfr[fj], acc[fi][fj], 0, 0, 0);
    __syncthreads();
  }
}

// ===== split-bf16 tile loop, A pre-split as bf16 hi/lo arrays, W f32 (split at load) =====
__device__ __forceinline__ void mm_tile3b(
    const short* __restrict__ Ahi, const short* __restrict__ Alo, int lda, int m0, int acol,
    const float* __restrict__ W0, int N, int K, int n0,
    short* AsH, short* AsL, short* BsH, short* BsL, f32x4 acc[2][4])
{
  int tid = threadIdx.x;
  int lane = tid & 63, wv = tid >> 6;
  int wm = wv & 1, wn = wv >> 1;
  int ar = tid >> 2, aseg = tid & 3;
  int bkq = tid & 3, bn2 = tid >> 2;
  int aoff[2], boff[4];
  #pragma unroll
  for(int fi=0; fi<2; fi++) aoff[fi] = lswz(wm*32 + fi*16 + (lane&15), lane>>4);
  #pragma unroll
  for(int fj=0; fj<4; fj++) boff[fj] = lswz(wn*64 + fj*16 + (lane&15), lane>>4);
  size_t abase = (size_t)(m0+ar)*lda + acol + aseg*8;

  for(int k0=0; k0<K; k0+=BK){
    {
      *(bf16x8*)((char*)AsH + lswz(ar, aseg)) = *(const bf16x8*)(Ahi + abase + k0);
      *(bf16x8*)((char*)AsL + lswz(ar, aseg)) = *(const bf16x8*)(Alo + abase + k0);
    }
    {
      int kk = k0 + bkq*8;
      const float* wp = W0 + (size_t)kk*N + n0 + bn2*2;
      bf16x8 h0,l0,h1,l1;
      #pragma unroll
      for(int i=0;i<8;i++){
        float2 w = *(const float2*)(wp + (size_t)i*N);
        unsigned p0 = fsplit2(w.x);
        unsigned p1 = fsplit2(w.y);
        h0[i]=(short)(p0&0xffff); l0[i]=(short)(p0>>16);
        h1[i]=(short)(p1&0xffff); l1[i]=(short)(p1>>16);
      }
      *(bf16x8*)((char*)BsH + lswz(bn2*2,   bkq)) = h0;
      *(bf16x8*)((char*)BsL + lswz(bn2*2,   bkq)) = l0;
      *(bf16x8*)((char*)BsH + lswz(bn2*2+1, bkq)) = h1;
      *(bf16x8*)((char*)BsL + lswz(bn2*2+1, bkq)) = l1;
    }
    __syncthreads();
    bf16x8 ah[2], al[2], bh[4], bl[4];
    #pragma unroll
    for(int fi=0; fi<2; fi++){
      ah[fi] = *(const bf16x8*)((const char*)AsH + aoff[fi]);
      al[fi] = *(const bf16x8*)((const char*)AsL + aoff[fi]);
    }
    #pragma unroll
    for(int fj=0; fj<4; fj++){
      bh[fj] = *(const bf16x8*)((const char*)BsH + boff[fj]);
      bl[fj] = *(const bf16x8*)((const char*)BsL + boff[fj]);
    }
    #pragma unroll
    for(int fi=0; fi<2; fi++)
      #pragma unroll
      for(int fj=0; fj<4; fj++){
        acc[fi][fj] = __builtin_amdgcn_mfma_f32_16x16x32_bf16(ah[fi], bh[fj], acc[fi][fj], 0, 0, 0);
        acc[fi][fj] = __builtin_amdgcn_mfma_f32_16x16x32_bf16(ah[fi], bl[fj], acc[fi][fj], 0, 0, 0);
        acc[fi][fj] = __builtin_amdgcn_mfma_f32_16x16x32_bf16(al[fi], bh[fj], acc[fi][fj], 0, 0, 0);
      }
    __syncthreads();
  }
}

// ================= x -> hi/lo bf16 pre-split =================
__global__ __launch_bounds__(256) void k_split_x(const float* __restrict__ in,
    short* __restrict__ hi, short* __restrict__ lo, int n4){
  int i = blockIdx.x*256 + threadIdx.x;
  if(i < n4){
    float4 v = ((const float4*)in)[i];
    unsigned p0 = fsplit2(v.x), p1 = fsplit2(v.y), p2 = fsplit2(v.z), p3 = fsplit2(v.w);
    short4 h, l;
    h.x=(short)(p0&0xffff); l.x=(short)(p0>>16);
    h.y=(short)(p1&0xffff); l.y=(short)(p1>>16);
    h.z=(short)(p2&0xffff); l.z=(short)(p2>>16);
    h.w=(short)(p3&0xffff); l.w=(short)(p3>>16);
    ((short4*)hi)[i] = h;
    ((short4*)lo)[i] = l;
  }
}

// ================= fused QKV (common + unique), split precision, f32 out =================
struct PtrArr6 { const float* w[6]; const float* b[6]; };

__global__ __launch_bounds__(256) void mm3_qkv(const short* __restrict__ x_hi,
    const short* __restrict__ x_lo, PtrArr6 pa,
    const int* __restrict__ routeb, float* __restrict__ qkvout)
{
  int n0 = blockIdx.x*BN, m0 = blockIdx.y*BM, z = blockIdx.z;
  int bidx = m0 >> 7;
  const float* W = pa.w[z]; const float* bias = pa.b[z];
  if(z >= 3){ int e = routeb[bidx]; W += (size_t)e*Dm*Dm; bias += (size_t)e*Dm; }
  __shared__ short AsH[BM*BK], AsL[BM*BK];
  __shared__ short BsH[BN*BK], BsL[BN*BK];
  f32x4 acc[2][4] = {};
  mm_tile3b(x_hi, x_lo, Dm, m0, 0, W, Dm, Dm, n0, AsH, AsL, BsH, BsL, acc);
  float* outp = qkvout + (size_t)z*NT*Dm;
  int lane = threadIdx.x&63, wv = threadIdx.x>>6, wm = wv&1, wn = wv>>1;
  #pragma unroll
  for(int fi=0; fi<2; fi++)
    #pragma unroll
    for(int fj=0; fj<4; fj++)
      #pragma unroll
      for(int r=0; r<4; r++){
        int row = m0 + wm*32 + fi*16 + ((lane>>4)<<2) + r;
        int col = n0 + wn*64 + fj*16 + (lane&15);
        outp[(size_t)row*Dm + col] = acc[fi][fj][r] + bias[col];
      }
}

// ================= output projection, split-K via z (kc=0 common, kc=1 unique) =================
__global__ __launch_bounds__(256) void mm3_outproj(const short* __restrict__ ctx_hi,
    const short* __restrict__ ctx_lo,
    const float* __restrict__ ca_wo, const float* __restrict__ ua_wo,
    const float* __restrict__ ca_bo, const float* __restrict__ ua_bo,
    const int* __restrict__ routeb, const float* __restrict__ pmaxb,
    float* __restrict__ att2)
{
  int n0 = blockIdx.x*BN, m0 = blockIdx.y*BM, kc = blockIdx.z;
  int bidx = m0 >> 7;
  int e = routeb[bidx];
  const float* W    = kc ? (ua_wo + (size_t)e*Dm*Dm) : ca_wo;
  const float* bias = kc ? (ua_bo + (size_t)e*Dm)    : ca_bo;
  float bscale = kc ? pmaxb[bidx] : 1.0f;
  __shared__ short AsH[BM*BK], AsL[BM*BK];
  __shared__ short BsH[BN*BK], BsL[BN*BK];
  f32x4 acc[2][4] = {};
  mm_tile3b(ctx_hi, ctx_lo, 1536, m0, kc*Dm, W, Dm, Dm, n0, AsH, AsL, BsH, BsL, acc);
  float* outp = att2 + (size_t)kc*NT*Dm;
  int lane = threadIdx.x&63, wv = threadIdx.x>>6, wm = wv&1, wn = wv>>1;
  #pragma unroll
  for(int fi=0; fi<2; fi++)
    #pragma unroll
    for(int fj=0; fj<4; fj++)
      #pragma unroll
      for(int r=0; r<4; r++){
        int row = m0 + wm*32 + fi*16 + ((lane>>4)<<2) + r;
        int col = n0 + wn*64 + fj*16 + (lane&15);
        outp[(size_t)row*Dm + col] = acc[fi][fj][r] + bscale*bias[col];
      }
}

// ================= att = att2[0] + att2[1]; also emit bf16 =================
__global__ __launch_bounds__(256) void k_att_sum(const float* __restrict__ att2,
    float* __restrict__ att, short* __restrict__ attbf, int n4){
  int i = blockIdx.x*256 + threadIdx.x;
  if(i < n4){
    const size_t P4 = (size_t)NT*Dm/4;
    float4 a = ((const float4*)att2)[i];
    float4 b = ((const float4*)att2)[P4 + i];
    float4 v; v.x=a.x+b.x; v.y=a.y+b.y; v.z=a.z+b.z; v.w=a.w+b.w;
    ((float4*)att)[i] = v;
    short4 o;
    o.x=(short)f2bf(v.x); o.y=(short)f2bf(v.y); o.z=(short)f2bf(v.z); o.w=(short)f2bf(v.w);
    ((short4*)attbf)[i] = o;
  }
}

// ================= F-stage: common FFN1 (y<32) + grouped Switch-FFN1 (tile list) =================
__global__ __launch_bounds__(256) void mm_fstage(const short* __restrict__ attbf,
    const float* __restrict__ cf_w1, const float* __restrict__ cf_b1,
    const float* __restrict__ uf_w1, const float* __restrict__ uf_b1,
    const int* __restrict__ idxl, const int* __restrict__ gbase, const int* __restrict__ gcnt,
    const int* __restrict__ tlist, const int* __restrict__ ntl,
    short* __restrict__ h, short* __restrict__ hg)
{
  int n0 = blockIdx.x*BN, y = blockIdx.y;
  int tid = threadIdx.x;
  __shared__ short As[BM*BK];
  __shared__ short Bs[BN*BK];
  int lane = tid&63, wv = tid>>6, wm = wv&1, wn = wv>>1;
  f32x4 acc[2][4] = {};
  if(y < 32){
    int m0 = y*BM;
    mm_tile(attbf, Dm, nullptr, m0, cf_w1, Fm, Dm, n0, As, Bs, acc);
    #pragma unroll
    for(int fi=0; fi<2; fi++)
      #pragma unroll
      for(int fj=0; fj<4; fj++)
        #pragma unroll
        for(int r=0; r<4; r++){
          int row = m0 + wm*32 + fi*16 + ((lane>>4)<<2) + r;
          int col = n0 + wn*64 + fj*16 + (lane&15);
          h[(size_t)row*Fm + col] = (short)f2bf(gelu_f(acc[fi][fj][r] + cf_b1[col]));
        }
  } else {
    int i = y - 32;
    if(i >= ntl[0]) return;
    int v = tlist[i], g = v>>8, t = v&255;
    int cnt = gcnt[g], r0 = t*BM, pos0 = gbase[g] + r0;
    __shared__ int rows[BM];
    if(tid < BM) rows[tid] = (r0 + tid < cnt) ? idxl[pos0 + tid] : -1;
    __syncthreads();
    mm_tile(attbf, Dm, rows, 0, uf_w1 + (size_t)g*Dm*Fm, Fm, Dm, n0, As, Bs, acc);
    const float* bias = uf_b1 + (size_t)g*Fm;
    #pragma unroll
    for(int fi=0; fi<2; fi++)
      #pragma unroll
      for(int fj=0; fj<4; fj++)
        #pragma unroll
        for(int r=0; r<4; r++){
          int lr = wm*32 + fi*16 + ((lane>>4)<<2) + r;
          if(r0 + lr >= cnt) continue;
          int col = n0 + wn*64 + fj*16 + (lane&15);
          hg[(size_t)(pos0+lr)*Fm + col] = (short)f2bf(gelu_f(acc[fi][fj][r] + bias[col]));
        }
  }
}

// ================= D-stage: split-K (z=kc of 4), bf16 partials =================
__global__ __launch_bounds__(256) void mm_dstage(const short* __restrict__ h,
    const short* __restrict__ hg,
    const float* __restrict__ cf_w2, const float* __restrict__ cf_b2,
    const float* __restrict__ uf_w2, const float* __restrict__ uf_b2,
    const int* __restrict__ idxl, const int* __restrict__ gbase, const int* __restrict__ gcnt,
    const int* __restrict__ tlist, const int* __restrict__ ntl,
    const float* __restrict__ tokp, short* __restrict__ ycf4, short* __restrict__ yuo4)
{
  const int KC = Fm/4;   // 768
  int n0 = blockIdx.x*BN, y = blockIdx.y, kc = blockIdx.z;
  int tid = threadIdx.x;
  __shared__ short As[BM*BK];
  __shared__ short Bs[BN*BK];
  int lane = tid&63, wv = tid>>6, wm = wv&1, wn = wv>>1;
  f32x4 acc[2][4] = {};
  if(y < 32){
    int m0 = y*BM;
    mm_tile(h + kc*KC, Fm, nullptr, m0, cf_w2 + (size_t)kc*KC*Dm, Dm, KC, n0, As, Bs, acc);
    short* outp = ycf4 + (size_t)kc*NT*Dm;
    #pragma unroll
    for(int fi=0; fi<2; fi++)
      #pragma unroll
      for(int fj=0; fj<4; fj++)
        #pragma unroll
        for(int r=0; r<4; r++){
          int row = m0 + wm*32 + fi*16 + ((lane>>4)<<2) + r;
          int col = n0 + wn*64 + fj*16 + (lane&15);
          outp[(size_t)row*Dm + col] = (short)f2bf(acc[fi][fj][r] + (kc==0 ? cf_b2[col] : 0.f));
        }
  } else {
    int i = y - 32;
    if(i >= ntl[0]) return;
    int v = tlist[i], g = v>>8, t = v&255;
    int cnt = gcnt[g], r0 = t*BM, pos0 = gbase[g] + r0;
    __shared__ int rows[BM];
    __shared__ int orows[BM];
    if(tid < BM){
      int ok = (r0 + tid < cnt);
      rows[tid]  = ok ? (pos0 + tid) : -1;
      orows[tid] = ok ? idxl[pos0 + tid] : -1;
    }
    __syncthreads();
    mm_tile(hg + kc*KC, Fm, rows, 0,
            uf_w2 + (size_t)g*Fm*Dm + (size_t)kc*KC*Dm, Dm, KC, n0, As, Bs, acc);
    const float* bias = uf_b2 + (size_t)g*Dm;
    short* outp = yuo4 + (size_t)kc*NT*Dm;
    #pragma unroll
    for(int fi=0; fi<2; fi++)
      #pragma unroll
      for(int fj=0; fj<4; fj++)
        #pragma unroll
        for(int r=0; r<4; r++){
          int lr = wm*32 + fi*16 + ((lane>>4)<<2) + r;
          int rm = orows[lr];
          if(rm < 0) continue;
          int col = n0 + wn*64 + fj*16 + (lane&15);
          float vv = acc[fi][fj][r] + (kc==0 ? bias[col] : 0.f);
          outp[(size_t)rm*Dm + col] = (short)f2bf(vv * tokp[rm]);
        }
  }
}

// ================= batch-level routing =================
__global__ __launch_bounds__(256) void k_route_batch(const float* __restrict__ xf,
    const float* __restrict__ sw_w, const float* __restrict__ sw_b,
    float* __restrict__ pmax_b, int* __restrict__ route_b){
  int b = blockIdx.x, tid = threadIdx.x;
  __shared__ float xm[Dm];
  for(int d=tid; d<Dm; d+=256){
    float s=0.f;
    const float* xp = xf + ((size_t)b*Sm)*Dm + d;
    for(int ss=0; ss<Sm; ss++) s += xp[(size_t)ss*Dm];
    xm[d] = s*(1.0f/Sm);
  }
  __syncthreads();
  float a0=0,a1=0,a2=0,a3=0;
  for(int d=tid; d<Dm; d+=256){
    float xv = xm[d];
    a0 += xv*sw_w[d*4+0]; a1 += xv*sw_w[d*4+1];
    a2 += xv*sw_w[d*4+2]; a3 += xv*sw_w[d*4+3];
  }
  __shared__ float red[4][256];
  red[0][tid]=a0; red[1][tid]=a1; red[2][tid]=a2; red[3][tid]=a3;
  for(int off=128; off>0; off>>=1){
    __syncthreads();
    if(tid<off){ for(int u=0;u<4;u++) red[u][tid]+=red[u][tid+off]; }
  }
  __syncthreads();
  if(tid==0){
    float l[4]; for(int u=0;u<4;u++) l[u]=red[u][0]+sw_b[u];
    float m=l[0]; int arg=0;
    for(int u=1;u<4;u++) if(l[u]>m){ m=l[u]; arg=u; }
    float s=0; for(int u=0;u<4;u++) s+=expf(l[u]-m);
    pmax_b[b]=1.0f/s;
    route_b[b]=arg;
  }
}

// ====== attention (f32 in; ctx out as hi/lo bf16 [2048][1536], unique pre-scaled) ======
__global__ __launch_bounds__(256) void k_attn_f(const float* __restrict__ qkv,
    const float* __restrict__ mask, const float* __restrict__ pmaxb,
    short* __restrict__ ctx_hi, short* __restrict__ ctx_lo)
{
  int h = blockIdx.x, b = blockIdx.y, z = blockIdx.z;
  int qh = z & 1, kind = z >> 1;
  const float* Q  = qkv + (size_t)(kind*3+0)*NT*Dm;
  const float* Kp = qkv + (size_t)(kind*3+1)*NT*Dm;
  const float* Vp = qkv + (size_t)(kind*3+2)*NT*Dm;
  int tid = threadIdx.x;
  __shared__ float kv[128][64];
  __shared__ float sS[64][128];
  size_t base = ((size_t)b*Sm)*Dm + h*DHm;
  for(int l=tid; l<2048; l+=256){
    int s=l>>4, d0=(l&15)*4;
    float4 v = *(const float4*)(Kp + base + (size_t)s*Dm + d0);
    kv[s][d0]=v.x; kv[s][d0+1]=v.y; kv[s][d0+2]=v.z; kv[s][d0+3]=v.w;
  }
  __syncthreads();
  int ql = tid>>2, quarter = tid&3;
  int qi = qh*64 + ql;
  float qreg[64];
  const float* qp = Q + base + (size_t)qi*Dm;
  #pragma unroll
  for(int d=0; d<64; d++) qreg[d] = qp[d];
  int kb = quarter*32;
  for(int ki=kb; ki<kb+32; ki++){
    float s=0.f;
    #pragma unroll
    for(int d=0; d<64; d++) s += qreg[d]*kv[ki][d];
    sS[ql][ki] = s*0.125f + mask[b*Sm+ki];
  }
  __syncthreads();
  if(tid < 64){
    float m = -3.4e38f;
    for(int ki=0; ki<128; ki++) m = fmaxf(m, sS[tid][ki]);
    float sum = 0.f;
    for(int ki=0; ki<128; ki++){ float e = expf(sS[tid][ki]-m); sS[tid][ki]=e; sum+=e; }
    float inv = 1.0f/sum;
    for(int ki=0; ki<128; ki++) sS[tid][ki] *= inv;
  }
  __syncthreads();
  for(int l=tid; l<2048; l+=256){
    int s=l>>4, d0=(l&15)*4;
    float4 v = *(const float4*)(Vp + base + (size_t)s*Dm + d0);
    kv[s][d0]=v.x; kv[s][d0+1]=v.y; kv[s][d0+2]=v.z; kv[s][d0+3]=v.w;
  }
  __syncthreads();
  float sc = kind ? pmaxb[b] : 1.0f;
  int d0 = quarter*16;
  for(int d=d0; d<d0+16; d++){
    float s=0.f;
    for(int ki=0; ki<128; ki++) s += sS[ql][ki]*kv[ki][d];
    float v = s*sc;
    size_t idx = ((size_t)b*Sm + qi)*1536 + kind*Dm + h*DHm + d;
    unsigned short hh = f2bf(v);
    ctx_hi[idx] = (short)hh;
    ctx_lo[idx] = (short)f2bf(v - bf2f(hh));
  }
}

// ================= token-level Switch routing =================
__global__ __launch_bounds__(256) void k_tok_route(const float* __restrict__ att,
    const float* __restrict__ ur_w, const float* __restrict__ ur_b,
    const int* __restrict__ route_b, float* __restrict__ tok_pmax,
    int* __restrict__ tok_e, int* __restrict__ grp_count)
{
  int n = blockIdx.x, tid = threadIdx.x;
  int i = route_b[n>>7];
  const float* w = ur_w + (size_t)i*Dm*4;
  const float* ap = att + (size_t)n*Dm;
  float a0=0,a1=0,a2=0,a3=0;
  for(int d=tid; d<Dm; d+=256){
    float a = ap[d];
    a0 += a*w[d*4+0]; a1 += a*w[d*4+1];
    a2 += a*w[d*4+2]; a3 += a*w[d*4+3];
  }
  __shared__ float red[4][256];
  red[0][tid]=a0; red[1][tid]=a1; red[2][tid]=a2; red[3][tid]=a3;
  for(int off=128; off>0; off>>=1){
    __syncthreads();
    if(tid<off){ for(int u=0;u<4;u++) red[u][tid]+=red[u][tid+off]; }
  }
  __syncthreads();
  if(tid==0){
    float l[4]; for(int u=0;u<4;u++) l[u]=red[u][0]+ur_b[i*4+u];
    float m=l[0]; int arg=0;
    for(int u=1;u<4;u++) if(l[u]>m){ m=l[u]; arg=u; }
    float s=0; for(int u=0;u<4;u++) s+=expf(l[u]-m);
    tok_pmax[n] = 1.0f/s;
    tok_e[n] = arg;
    atomicAdd(&grp_count[i*4+arg], 1);
  }
}

// ================= prefix + tile worklist =================
__global__ void k_prefix(const int* __restrict__ cnt, int* __restrict__ base,
                         int* __restrict__ cur, int* __restrict__ tlist, int* __restrict__ ntl){
  if(threadIdx.x==0 && blockIdx.x==0){
    int s=0, nt=0;
    for(int g=0; g<16; g++){
      base[g]=s; cur[g]=s;
      int tg = (cnt[g] + BM - 1)/BM;
      for(int t=0; t<tg; t++){ if(nt<64) tlist[nt++] = (g<<8)|t; }
      s += cnt[g];
    }
    ntl[0] = nt;
  }
}

__global__ void k_scatter(const int* __restrict__ route_b, const int* __restrict__ tok_e,
                          int* __restrict__ cur, int* __restrict__ idxl){
  int n = blockIdx.x*256 + threadIdx.x;
  if(n < NT){
    int g = route_b[n>>7]*4 + tok_e[n];
    int pos = atomicAdd(&cur[g], 1);
    idxl[pos] = n;
  }
}

// ======= final residual add + LayerNorm (sums 4+4 bf16 split-K partials) =======
__global__ __launch_bounds__(256) void k_final_ln(const float* __restrict__ att,
    const short* __restrict__ ycf4, const short* __restrict__ yuo4,
    const float* __restrict__ ln_g, const float* __restrict__ ln_b, float* __restrict__ out)
{
  int n = blockIdx.x, tid = threadIdx.x;
  __shared__ float yb[Dm];
  __shared__ float red[256];
  size_t base = (size_t)n*Dm;
  const size_t P = (size_t)NT*Dm;
  float ps = 0.f;
  for(int d=tid; d<Dm; d+=256){
    float v = att[base+d];
    #pragma unroll
    for(int c=0; c<4; c++){
      v += bf2f((unsigned short)ycf4[c*P + base + d]);
      v += bf2f((unsigned short)yuo4[c*P + base + d]);
    }
    yb[d]=v; ps+=v;
  }
  red[tid]=ps;
  for(int off=128; off>0; off>>=1){ __syncthreads(); if(tid<off) red[tid]+=red[tid+off]; }
  __syncthreads();
  float mu = red[0]*(1.0f/Dm);
  __syncthreads();
  float pv = 0.f;
  for(int d=tid; d<Dm; d+=256){ float t = yb[d]-mu; pv += t*t; }
  red[tid]=pv;
  for(int off=128; off>0; off>>=1){ __syncthreads(); if(tid<off) red[tid]+=red[tid+off]; }
  __syncthreads();
  float var = red[0]*(1.0f/Dm);
  float rstd = rsqrtf(var + 1e-12f);
  for(int d=tid; d<Dm; d+=256){
    out[base+d] = (yb[d]-mu)*rstd*ln_g[d] + ln_b[d];
  }
}

extern "C" void kernel_launch(void* const* d_in, const int* in_sizes, int n_in,
                              void* d_out, int out_size, void* d_ws, size_t ws_size,
                              hipStream_t stream)
{
  const float* x     =(const float*)d_in[0];
  const float* mask  =(const float*)d_in[1];
  const float* sw_w  =(const float*)d_in[2];
  const float* sw_b  =(const float*)d_in[3];
  const float* ca_wq =(const float*)d_in[4];
  const float* ca_bq =(const float*)d_in[5];
  const float* ca_wk =(const float*)d_in[6];
  const float* ca_bk =(const float*)d_in[7];
  const float* ca_wv =(const float*)d_in[8];
  const float* ca_bv =(const float*)d_in[9];
  const float* ca_wo =(const float*)d_in[10];
  const float* ca_bo =(const float*)d_in[11];
  const float* ua_wq =(const float*)d_in[12];
  const float* ua_bq =(const float*)d_in[13];
  const float* ua_wk =(const float*)d_in[14];
  const float* ua_bk =(const float*)d_in[15];
  const float* ua_wv =(const float*)d_in[16];
  const float* ua_bv =(const float*)d_in[17];
  const float* ua_wo =(const float*)d_in[18];
  const float* ua_bo =(const float*)d_in[19];
  const float* cf_w1 =(const float*)d_in[20];
  const float* cf_b1 =(const float*)d_in[21];
  const float* cf_w2 =(const float*)d_in[22];
  const float* cf_b2 =(const float*)d_in[23];
  const float* ur_w  =(const float*)d_in[24];
  const float* ur_b  =(const float*)d_in[25];
  const float* uf_w1 =(const float*)d_in[26];
  const float* uf_b1 =(const float*)d_in[27];
  const float* uf_w2 =(const float*)d_in[28];
  const float* uf_b2 =(const float*)d_in[29];
  const float* ln_g  =(const float*)d_in[30];
  const float* ln_b  =(const float*)d_in[31];

  // ---- workspace: region of 8 units (1 unit = NT*Dm f32 = 6.29MB), phase-aliased ----
  // phase A : qkv f32 units0-5 | ctx_hi unit6 (NT*1536 bf16) | ctx_lo unit7
  // phase A2: att2 f32 partials units0-1 (qkv dead)
  // phase B : h_bf units0-1 | hg_bf units2-3 | ycf4 (4 bf16 chunks) units4-5 | yuo4 units6-7
  float* region = (float*)d_ws;
  float* qkv    = region;
  short* ctx_hi = (short*)(region + (size_t)6*NT*Dm);
  short* ctx_lo = (short*)(region + (size_t)7*NT*Dm);
  float* att2   = region;
  short* h_bf   = (short*)region;
  short* hg_bf  = (short*)region + (size_t)NT*Fm;
  short* ycf4   = (short*)(region + (size_t)4*NT*Dm);
  short* yuo4   = (short*)(region + (size_t)6*NT*Dm);
  float* fp     = region + (size_t)8*NT*Dm;
  short* x_hi   = (short*)fp;                 // alive only during mm3_qkv
  short* x_lo   = x_hi + (size_t)NT*Dm;
  float* att    = fp; fp += (size_t)NT*Dm;    // written by k_att_sum (x_hi/lo dead)
  float* tokp   = fp; fp += NT;
  float* pmaxb  = fp; fp += 16;
  short* att_bf = (short*)fp;
  int*   ip     = (int*)(att_bf + (size_t)NT*Dm);
  int* routeb = ip; ip += 16;
  int* toke   = ip; ip += NT;
  int* gcnt   = ip; ip += 16;
  int* gbase  = ip; ip += 16;
  int* gcur   = ip; ip += 16;
  int* idxl   = ip; ip += NT;
  int* tlist  = ip; ip += 64;
  int* ntl    = ip; ip += 1;
  size_t need = (size_t)((char*)ip - (char*)d_ws);
  if(need > ws_size) return;   // bail visibly (output stays 0)

  (void)hipMemsetAsync(gcnt, 0, 16*sizeof(int), stream);

  k_route_batch<<<16, 256, 0, stream>>>(x, sw_w, sw_b, pmaxb, routeb);
  k_split_x<<<(NT*Dm/4 + 255)/256, 256, 0, stream>>>(x, x_hi, x_lo, NT*Dm/4);

  // fused QKV (split precision): z = {cq,ck,cv,uq,uk,uv}
  PtrArr6 pa;
  pa.w[0]=ca_wq; pa.w[1]=ca_wk; pa.w[2]=ca_wv; pa.w[3]=ua_wq; pa.w[4]=ua_wk; pa.w[5]=ua_wv;
  pa.b[0]=ca_bq; pa.b[1]=ca_bk; pa.b[2]=ca_bv; pa.b[3]=ua_bq; pa.b[4]=ua_bk; pa.b[5]=ua_bv;
  mm3_qkv<<<dim3(Dm/BN, NT/BM, 6), 256, 0, stream>>>(x_hi, x_lo, pa, routeb, qkv);

  // attention (f32 -> ctx hi/lo bf16): z = qh + 2*kind
  k_attn_f<<<dim3(Hm, Bm, 4), 256, 0, stream>>>(qkv, mask, pmaxb, ctx_hi, ctx_lo);

  // output projection, split-K=2 (z): partials into dead qkv units
  mm3_outproj<<<dim3(Dm/BN, NT/BM, 2), 256, 0, stream>>>(ctx_hi, ctx_lo, ca_wo, ua_wo,
                                                         ca_bo, ua_bo, routeb, pmaxb, att2);
  k_att_sum<<<(NT*Dm/4 + 255)/256, 256, 0, stream>>>(att2, att, att_bf, NT*Dm/4);

  // token routing + grouping (from f32 att -> flip-safe)
  k_tok_route<<<NT, 256, 0, stream>>>(att, ur_w, ur_b, routeb, tokp, toke, gcnt);
  k_prefix<<<1, 64, 0, stream>>>(gcnt, gbase, gcur, tlist, ntl);
  k_scatter<<<NT/256, 256, 0, stream>>>(routeb, toke, gcur, idxl);

  // F-stage: common FFN1 + grouped Switch-FFN1 in one dispatch
  mm_fstage<<<dim3(Fm/BN, 32+48), 256, 0, stream>>>(att_bf, cf_w1, cf_b1, uf_w1, uf_b1,
                                                    idxl, gbase, gcnt, tlist, ntl, h_bf, hg_bf);

  // D-stage: split-K=4, bf16 partial buffers
  mm_dstage<<<dim3(Dm/BN, 32+48, 4), 256, 0, stream>>>(h_bf, hg_bf, cf_w2, cf_b2, uf_w2, uf_b2,
                                                       idxl, gbase, gcnt, tlist, ntl, tokp,
                                                       ycf4, yuo4);

  k_final_ln<<<NT, 256, 0, stream>>>(att, ycf4, yuo4, ln_g, ln_b, (float*)d_out);
}

// Round 8
// 781.976 us; speedup vs baseline: 4.3107x; 1.0591x over previous
//
#include <hip/hip_runtime.h>

#define NT 2048
#define Dm 768
#define Fm 3072
#define Bm 16
#define Sm 128
#define Hm 12
#define DHm 64

#define BM 64
#define BN 128
#define BK 32

typedef __attribute__((ext_vector_type(8))) short bf16x8;
typedef __attribute__((ext_vector_type(4))) float f32x4;

__device__ __forceinline__ unsigned short f2bf(float f){
  unsigned u = __float_as_uint(f);
  unsigned r = (u + 0x7fffu + ((u>>16)&1u)) >> 16;   // round-nearest-even
  return (unsigned short)r;
}
__device__ __forceinline__ float bf2f(unsigned short h){ return __uint_as_float(((unsigned)h)<<16); }
// split f32 into hi/lo bf16 pair, packed: hi = bits[15:0], lo = bits[31:16]
__device__ __forceinline__ unsigned fsplit2(float x){
  unsigned short h = f2bf(x);
  unsigned short l = f2bf(x - bf2f(h));
  return (unsigned)h | ((unsigned)l << 16);
}
__device__ __forceinline__ float gelu_f(float x){
  return 0.5f*x*(1.0f + erff(x*0.70710678118654752f));
}
// byte offset of 8-elem k-group (row,kg) in a [rows][32]-bf16 LDS tile (64B/row);
// XOR swizzle spreads same-kg column reads across banks (2-way residual = free).
__device__ __forceinline__ int lswz(int row, int kg){
  return (row<<6) | (((kg ^ ((row>>1)&3))&3)<<4);
}

// ========== pipelined plain bf16 MFMA tile loop (reg prefetch + LDS double buffer) ==========
// As: 2*BM*BK shorts, Bs: 2*BN*BK shorts. One barrier per K-step.
__device__ __forceinline__ void mm_tile(
    const short* __restrict__ Abf, int lda, const int* rowsLds, int m0,
    const float* __restrict__ W0, int N, int K, int n0,
    short* As, short* Bs, f32x4 acc[2][4])
{
  int tid = threadIdx.x;
  int lane = tid & 63, wv = tid >> 6;
  int wm = wv & 1, wn = wv >> 1;
  int ar = tid >> 2, aseg = tid & 3;
  int bkq = tid & 3, bn2 = tid >> 2;
  int grow = rowsLds ? rowsLds[ar] : (m0 + ar);
  bool aok = (grow >= 0);
  const short* aptr = Abf + (size_t)(aok ? grow : 0)*lda + aseg*8;
  const float* bptr = W0 + (size_t)(bkq*8)*N + n0 + bn2*2;
  int aoff[2], boff[4];
  #pragma unroll
  for(int fi=0; fi<2; fi++) aoff[fi] = lswz(wm*32 + fi*16 + (lane&15), lane>>4);
  #pragma unroll
  for(int fj=0; fj<4; fj++) boff[fj] = lswz(wn*64 + fj*16 + (lane&15), lane>>4);
  int awo = lswz(ar, aseg);
  int bwo0 = lswz(bn2*2, bkq), bwo1 = lswz(bn2*2+1, bkq);
  const int ASZ = BM*BK, BSZ = BN*BK;

  bf16x8 avA = {0,0,0,0,0,0,0,0};
  if(aok) avA = *(const bf16x8*)aptr;
  float2 wr[8];
  #pragma unroll
  for(int i=0;i<8;i++) wr[i] = *(const float2*)(bptr + (size_t)i*N);

  for(int k0=0; k0<K; k0+=BK){
    short* Asc = As + ((k0>>5)&1)*ASZ;
    short* Bsc = Bs + ((k0>>5)&1)*BSZ;
    *(bf16x8*)((char*)Asc + awo) = avA;
    {
      bf16x8 v0, v1;
      #pragma unroll
      for(int i=0;i<8;i++){ v0[i]=(short)f2bf(wr[i].x); v1[i]=(short)f2bf(wr[i].y); }
      *(bf16x8*)((char*)Bsc + bwo0) = v0;
      *(bf16x8*)((char*)Bsc + bwo1) = v1;
    }
    if(k0+BK < K){
      if(aok) avA = *(const bf16x8*)(aptr + k0 + BK);
      const float* bp = bptr + (size_t)(k0+BK)*N;
      #pragma unroll
      for(int i=0;i<8;i++) wr[i] = *(const float2*)(bp + (size_t)i*N);
    }
    __syncthreads();
    bf16x8 af[2], bfr[4];
    #pragma unroll
    for(int fi=0; fi<2; fi++) af[fi] = *(const bf16x8*)((const char*)Asc + aoff[fi]);
    #pragma unroll
    for(int fj=0; fj<4; fj++) bfr[fj] = *(const bf16x8*)((const char*)Bsc + boff[fj]);
    #pragma unroll
    for(int fi=0; fi<2; fi++)
      #pragma unroll
      for(int fj=0; fj<4; fj++)
        acc[fi][fj] = __builtin_amdgcn_mfma_f32_16x16x32_bf16(af[fi], bfr[fj], acc[fi][fj], 0, 0, 0);
  }
}

// ===== pipelined split-bf16 tile loop, A pre-split bf16 hi/lo, W f32 (split on the fly) =====
// AsH/AsL: 2*BM*BK shorts each; BsH/BsL: 2*BN*BK shorts each.
__device__ __forceinline__ void mm_tile3b(
    const short* __restrict__ Ahi, const short* __restrict__ Alo, int lda, int m0, int acol,
    const float* __restrict__ W0, int N, int K, int n0,
    short* AsH, short* AsL, short* BsH, short* BsL, f32x4 acc[2][4])
{
  int tid = threadIdx.x;
  int lane = tid & 63, wv = tid >> 6;
  int wm = wv & 1, wn = wv >> 1;
  int ar = tid >> 2, aseg = tid & 3;
  int bkq = tid & 3, bn2 = tid >> 2;
  int aoff[2], boff[4];
  #pragma unroll
  for(int fi=0; fi<2; fi++) aoff[fi] = lswz(wm*32 + fi*16 + (lane&15), lane>>4);
  #pragma unroll
  for(int fj=0; fj<4; fj++) boff[fj] = lswz(wn*64 + fj*16 + (lane&15), lane>>4);
  size_t abase = (size_t)(m0+ar)*lda + acol + aseg*8;
  const float* bptr = W0 + (size_t)(bkq*8)*N + n0 + bn2*2;
  int awo = lswz(ar, aseg);
  int bwo0 = lswz(bn2*2, bkq), bwo1 = lswz(bn2*2+1, bkq);
  const int ASZ = BM*BK, BSZ = BN*BK;

  bf16x8 avH = *(const bf16x8*)(Ahi + abase);
  bf16x8 avL = *(const bf16x8*)(Alo + abase);
  float2 wr[8];
  #pragma unroll
  for(int i=0;i<8;i++) wr[i] = *(const float2*)(bptr + (size_t)i*N);

  for(int k0=0; k0<K; k0+=BK){
    int cur = (k0>>5)&1;
    short* AsHc = AsH + cur*ASZ; short* AsLc = AsL + cur*ASZ;
    short* BsHc = BsH + cur*BSZ; short* BsLc = BsL + cur*BSZ;
    *(bf16x8*)((char*)AsHc + awo) = avH;
    *(bf16x8*)((char*)AsLc + awo) = avL;
    {
      bf16x8 h0,l0,h1,l1;
      #pragma unroll
      for(int i=0;i<8;i++){
        unsigned p0 = fsplit2(wr[i].x);
        unsigned p1 = fsplit2(wr[i].y);
        h0[i]=(short)(p0&0xffff); l0[i]=(short)(p0>>16);
        h1[i]=(short)(p1&0xffff); l1[i]=(short)(p1>>16);
      }
      *(bf16x8*)((char*)BsHc + bwo0) = h0;
      *(bf16x8*)((char*)BsLc + bwo0) = l0;
      *(bf16x8*)((char*)BsHc + bwo1) = h1;
      *(bf16x8*)((char*)BsLc + bwo1) = l1;
    }
    if(k0+BK < K){
      avH = *(const bf16x8*)(Ahi + abase + k0 + BK);
      avL = *(const bf16x8*)(Alo + abase + k0 + BK);
      const float* bp = bptr + (size_t)(k0+BK)*N;
      #pragma unroll
      for(int i=0;i<8;i++) wr[i] = *(const float2*)(bp + (size_t)i*N);
    }
    __syncthreads();
    bf16x8 ah[2], al[2], bh[4], bl[4];
    #pragma unroll
    for(int fi=0; fi<2; fi++){
      ah[fi] = *(const bf16x8*)((const char*)AsHc + aoff[fi]);
      al[fi] = *(const bf16x8*)((const char*)AsLc + aoff[fi]);
    }
    #pragma unroll
    for(int fj=0; fj<4; fj++){
      bh[fj] = *(const bf16x8*)((const char*)BsHc + boff[fj]);
      bl[fj] = *(const bf16x8*)((const char*)BsLc + boff[fj]);
    }
    #pragma unroll
    for(int fi=0; fi<2; fi++)
      #pragma unroll
      for(int fj=0; fj<4; fj++){
        acc[fi][fj] = __builtin_amdgcn_mfma_f32_16x16x32_bf16(ah[fi], bh[fj], acc[fi][fj], 0, 0, 0);
        acc[fi][fj] = __builtin_amdgcn_mfma_f32_16x16x32_bf16(ah[fi], bl[fj], acc[fi][fj], 0, 0, 0);
        acc[fi][fj] = __builtin_amdgcn_mfma_f32_16x16x32_bf16(al[fi], bh[fj], acc[fi][fj], 0, 0, 0);
      }
  }
}

// ================= x -> hi/lo bf16 pre-split =================
__global__ __launch_bounds__(256) void k_split_x(const float* __restrict__ in,
    short* __restrict__ hi, short* __restrict__ lo, int n4){
  int i = blockIdx.x*256 + threadIdx.x;
  if(i < n4){
    float4 v = ((const float4*)in)[i];
    unsigned p0 = fsplit2(v.x), p1 = fsplit2(v.y), p2 = fsplit2(v.z), p3 = fsplit2(v.w);
    short4 h, l;
    h.x=(short)(p0&0xffff); l.x=(short)(p0>>16);
    h.y=(short)(p1&0xffff); l.y=(short)(p1>>16);
    h.z=(short)(p2&0xffff); l.z=(short)(p2>>16);
    h.w=(short)(p3&0xffff); l.w=(short)(p3>>16);
    ((short4*)hi)[i] = h;
    ((short4*)lo)[i] = l;
  }
}

// ================= fused QKV (common + unique), split precision, f32 out =================
struct PtrArr6 { const float* w[6]; const float* b[6]; };

__global__ __launch_bounds__(256) void mm3_qkv(const short* __restrict__ x_hi,
    const short* __restrict__ x_lo, PtrArr6 pa,
    const int* __restrict__ routeb, float* __restrict__ qkvout)
{
  int n0 = blockIdx.x*BN, m0 = blockIdx.y*BM, z = blockIdx.z;
  int bidx = m0 >> 7;
  const float* W = pa.w[z]; const float* bias = pa.b[z];
  if(z >= 3){ int e = routeb[bidx]; W += (size_t)e*Dm*Dm; bias += (size_t)e*Dm; }
  __shared__ short AsH[2*BM*BK], AsL[2*BM*BK];
  __shared__ short BsH[2*BN*BK], BsL[2*BN*BK];
  f32x4 acc[2][4] = {};
  mm_tile3b(x_hi, x_lo, Dm, m0, 0, W, Dm, Dm, n0, AsH, AsL, BsH, BsL, acc);
  float* outp = qkvout + (size_t)z*NT*Dm;
  int lane = threadIdx.x&63, wv = threadIdx.x>>6, wm = wv&1, wn = wv>>1;
  #pragma unroll
  for(int fi=0; fi<2; fi++)
    #pragma unroll
    for(int fj=0; fj<4; fj++)
      #pragma unroll
      for(int r=0; r<4; r++){
        int row = m0 + wm*32 + fi*16 + ((lane>>4)<<2) + r;
        int col = n0 + wn*64 + fj*16 + (lane&15);
        outp[(size_t)row*Dm + col] = acc[fi][fj][r] + bias[col];
      }
}

// ================= output projection, split-K via z (kc=0 common, kc=1 unique) =================
__global__ __launch_bounds__(256) void mm3_outproj(const short* __restrict__ ctx_hi,
    const short* __restrict__ ctx_lo,
    const float* __restrict__ ca_wo, const float* __restrict__ ua_wo,
    const float* __restrict__ ca_bo, const float* __restrict__ ua_bo,
    const int* __restrict__ routeb, const float* __restrict__ pmaxb,
    float* __restrict__ att2)
{
  int n0 = blockIdx.x*BN, m0 = blockIdx.y*BM, kc = blockIdx.z;
  int bidx = m0 >> 7;
  int e = routeb[bidx];
  const float* W    = kc ? (ua_wo + (size_t)e*Dm*Dm) : ca_wo;
  const float* bias = kc ? (ua_bo + (size_t)e*Dm)    : ca_bo;
  float bscale = kc ? pmaxb[bidx] : 1.0f;
  __shared__ short AsH[2*BM*BK], AsL[2*BM*BK];
  __shared__ short BsH[2*BN*BK], BsL[2*BN*BK];
  f32x4 acc[2][4] = {};
  mm_tile3b(ctx_hi, ctx_lo, 1536, m0, kc*Dm, W, Dm, Dm, n0, AsH, AsL, BsH, BsL, acc);
  float* outp = att2 + (size_t)kc*NT*Dm;
  int lane = threadIdx.x&63, wv = threadIdx.x>>6, wm = wv&1, wn = wv>>1;
  #pragma unroll
  for(int fi=0; fi<2; fi++)
    #pragma unroll
    for(int fj=0; fj<4; fj++)
      #pragma unroll
      for(int r=0; r<4; r++){
        int row = m0 + wm*32 + fi*16 + ((lane>>4)<<2) + r;
        int col = n0 + wn*64 + fj*16 + (lane&15);
        outp[(size_t)row*Dm + col] = acc[fi][fj][r] + bscale*bias[col];
      }
}

// ================= att = att2[0] + att2[1]; also emit bf16 =================
__global__ __launch_bounds__(256) void k_att_sum(const float* __restrict__ att2,
    float* __restrict__ att, short* __restrict__ attbf, int n4){
  int i = blockIdx.x*256 + threadIdx.x;
  if(i < n4){
    const size_t P4 = (size_t)NT*Dm/4;
    float4 a = ((const float4*)att2)[i];
    float4 b = ((const float4*)att2)[P4 + i];
    float4 v; v.x=a.x+b.x; v.y=a.y+b.y; v.z=a.z+b.z; v.w=a.w+b.w;
    ((float4*)att)[i] = v;
    short4 o;
    o.x=(short)f2bf(v.x); o.y=(short)f2bf(v.y); o.z=(short)f2bf(v.z); o.w=(short)f2bf(v.w);
    ((short4*)attbf)[i] = o;
  }
}

// ================= F-stage: common FFN1 (y<32) + grouped Switch-FFN1 (tile list) =================
__global__ __launch_bounds__(256) void mm_fstage(const short* __restrict__ attbf,
    const float* __restrict__ cf_w1, const float* __restrict__ cf_b1,
    const float* __restrict__ uf_w1, const float* __restrict__ uf_b1,
    const int* __restrict__ idxl, const int* __restrict__ gbase, const int* __restrict__ gcnt,
    const int* __restrict__ tlist, const int* __restrict__ ntl,
    short* __restrict__ h, short* __restrict__ hg)
{
  int n0 = blockIdx.x*BN, y = blockIdx.y;
  int tid = threadIdx.x;
  __shared__ short As[2*BM*BK];
  __shared__ short Bs[2*BN*BK];
  int lane = tid&63, wv = tid>>6, wm = wv&1, wn = wv>>1;
  f32x4 acc[2][4] = {};
  if(y < 32){
    int m0 = y*BM;
    mm_tile(attbf, Dm, nullptr, m0, cf_w1, Fm, Dm, n0, As, Bs, acc);
    #pragma unroll
    for(int fi=0; fi<2; fi++)
      #pragma unroll
      for(int fj=0; fj<4; fj++)
        #pragma unroll
        for(int r=0; r<4; r++){
          int row = m0 + wm*32 + fi*16 + ((lane>>4)<<2) + r;
          int col = n0 + wn*64 + fj*16 + (lane&15);
          h[(size_t)row*Fm + col] = (short)f2bf(gelu_f(acc[fi][fj][r] + cf_b1[col]));
        }
  } else {
    int i = y - 32;
    if(i >= ntl[0]) return;
    int v = tlist[i], g = v>>8, t = v&255;
    int cnt = gcnt[g], r0 = t*BM, pos0 = gbase[g] + r0;
    __shared__ int rows[BM];
    if(tid < BM) rows[tid] = (r0 + tid < cnt) ? idxl[pos0 + tid] : -1;
    __syncthreads();
    mm_tile(attbf, Dm, rows, 0, uf_w1 + (size_t)g*Dm*Fm, Fm, Dm, n0, As, Bs, acc);
    const float* bias = uf_b1 + (size_t)g*Fm;
    #pragma unroll
    for(int fi=0; fi<2; fi++)
      #pragma unroll
      for(int fj=0; fj<4; fj++)
        #pragma unroll
        for(int r=0; r<4; r++){
          int lr = wm*32 + fi*16 + ((lane>>4)<<2) + r;
          if(r0 + lr >= cnt) continue;
          int col = n0 + wn*64 + fj*16 + (lane&15);
          hg[(size_t)(pos0+lr)*Fm + col] = (short)f2bf(gelu_f(acc[fi][fj][r] + bias[col]));
        }
  }
}

// ================= D-stage: split-K (z=kc of 4), bf16 partials =================
__global__ __launch_bounds__(256) void mm_dstage(const short* __restrict__ h,
    const short* __restrict__ hg,
    const float* __restrict__ cf_w2, const float* __restrict__ cf_b2,
    const float* __restrict__ uf_w2, const float* __restrict__ uf_b2,
    const int* __restrict__ idxl, const int* __restrict__ gbase, const int* __restrict__ gcnt,
    const int* __restrict__ tlist, const int* __restrict__ ntl,
    const float* __restrict__ tokp, short* __restrict__ ycf4, short* __restrict__ yuo4)
{
  const int KC = Fm/4;   // 768
  int n0 = blockIdx.x*BN, y = blockIdx.y, kc = blockIdx.z;
  int tid = threadIdx.x;
  __shared__ short As[2*BM*BK];
  __shared__ short Bs[2*BN*BK];
  int lane = tid&63, wv = tid>>6, wm = wv&1, wn = wv>>1;
  f32x4 acc[2][4] = {};
  if(y < 32){
    int m0 = y*BM;
    mm_tile(h + kc*KC, Fm, nullptr, m0, cf_w2 + (size_t)kc*KC*Dm, Dm, KC, n0, As, Bs, acc);
    short* outp = ycf4 + (size_t)kc*NT*Dm;
    #pragma unroll
    for(int fi=0; fi<2; fi++)
      #pragma unroll
      for(int fj=0; fj<4; fj++)
        #pragma unroll
        for(int r=0; r<4; r++){
          int row = m0 + wm*32 + fi*16 + ((lane>>4)<<2) + r;
          int col = n0 + wn*64 + fj*16 + (lane&15);
          outp[(size_t)row*Dm + col] = (short)f2bf(acc[fi][fj][r] + (kc==0 ? cf_b2[col] : 0.f));
        }
  } else {
    int i = y - 32;
    if(i >= ntl[0]) return;
    int v = tlist[i], g = v>>8, t = v&255;
    int cnt = gcnt[g], r0 = t*BM, pos0 = gbase[g] + r0;
    __shared__ int rows[BM];
    __shared__ int orows[BM];
    if(tid < BM){
      int ok = (r0 + tid < cnt);
      rows[tid]  = ok ? (pos0 + tid) : -1;
      orows[tid] = ok ? idxl[pos0 + tid] : -1;
    }
    __syncthreads();
    mm_tile(hg + kc*KC, Fm, rows, 0,
            uf_w2 + (size_t)g*Fm*Dm + (size_t)kc*KC*Dm, Dm, KC, n0, As, Bs, acc);
    const float* bias = uf_b2 + (size_t)g*Dm;
    short* outp = yuo4 + (size_t)kc*NT*Dm;
    #pragma unroll
    for(int fi=0; fi<2; fi++)
      #pragma unroll
      for(int fj=0; fj<4; fj++)
        #pragma unroll
        for(int r=0; r<4; r++){
          int lr = wm*32 + fi*16 + ((lane>>4)<<2) + r;
          int rm = orows[lr];
          if(rm < 0) continue;
          int col = n0 + wn*64 + fj*16 + (lane&15);
          float vv = acc[fi][fj][r] + (kc==0 ? bias[col] : 0.f);
          outp[(size_t)rm*Dm + col] = (short)f2bf(vv * tokp[rm]);
        }
  }
}

// ================= batch-level routing =================
__global__ __launch_bounds__(256) void k_route_batch(const float* __restrict__ xf,
    const float* __restrict__ sw_w, const float* __restrict__ sw_b,
    float* __restrict__ pmax_b, int* __restrict__ route_b){
  int b = blockIdx.x, tid = threadIdx.x;
  __shared__ float xm[Dm];
  for(int d=tid; d<Dm; d+=256){
    float s=0.f;
    const float* xp = xf + ((size_t)b*Sm)*Dm + d;
    for(int ss=0; ss<Sm; ss++) s += xp[(size_t)ss*Dm];
    xm[d] = s*(1.0f/Sm);
  }
  __syncthreads();
  float a0=0,a1=0,a2=0,a3=0;
  for(int d=tid; d<Dm; d+=256){
    float xv = xm[d];
    a0 += xv*sw_w[d*4+0]; a1 += xv*sw_w[d*4+1];
    a2 += xv*sw_w[d*4+2]; a3 += xv*sw_w[d*4+3];
  }
  __shared__ float red[4][256];
  red[0][tid]=a0; red[1][tid]=a1; red[2][tid]=a2; red[3][tid]=a3;
  for(int off=128; off>0; off>>=1){
    __syncthreads();
    if(tid<off){ for(int u=0;u<4;u++) red[u][tid]+=red[u][tid+off]; }
  }
  __syncthreads();
  if(tid==0){
    float l[4]; for(int u=0;u<4;u++) l[u]=red[u][0]+sw_b[u];
    float m=l[0]; int arg=0;
    for(int u=1;u<4;u++) if(l[u]>m){ m=l[u]; arg=u; }
    float s=0; for(int u=0;u<4;u++) s+=expf(l[u]-m);
    pmax_b[b]=1.0f/s;
    route_b[b]=arg;
  }
}

// ====== attention (f32 in; ctx out as hi/lo bf16 [2048][1536], unique pre-scaled) ======
__global__ __launch_bounds__(256) void k_attn_f(const float* __restrict__ qkv,
    const float* __restrict__ mask, const float* __restrict__ pmaxb,
    short* __restrict__ ctx_hi, short* __restrict__ ctx_lo)
{
  int h = blockIdx.x, b = blockIdx.y, z = blockIdx.z;
  int qh = z & 1, kind = z >> 1;
  const float* Q  = qkv + (size_t)(kind*3+0)*NT*Dm;
  const float* Kp = qkv + (size_t)(kind*3+1)*NT*Dm;
  const float* Vp = qkv + (size_t)(kind*3+2)*NT*Dm;
  int tid = threadIdx.x;
  __shared__ float kv[128][64];
  __shared__ float sS[64][128];
  size_t base = ((size_t)b*Sm)*Dm + h*DHm;
  for(int l=tid; l<2048; l+=256){
    int s=l>>4, d0=(l&15)*4;
    float4 v = *(const float4*)(Kp + base + (size_t)s*Dm + d0);
    kv[s][d0]=v.x; kv[s][d0+1]=v.y; kv[s][d0+2]=v.z; kv[s][d0+3]=v.w;
  }
  __syncthreads();
  int ql = tid>>2, quarter = tid&3;
  int qi = qh*64 + ql;
  float qreg[64];
  const float* qp = Q + base + (size_t)qi*Dm;
  #pragma unroll
  for(int d=0; d<64; d++) qreg[d] = qp[d];
  int kb = quarter*32;
  for(int ki=kb; ki<kb+32; ki++){
    float s=0.f;
    #pragma unroll
    for(int d=0; d<64; d++) s += qreg[d]*kv[ki][d];
    sS[ql][ki] = s*0.125f + mask[b*Sm+ki];
  }
  __syncthreads();
  if(tid < 64){
    float m = -3.4e38f;
    for(int ki=0; ki<128; ki++) m = fmaxf(m, sS[tid][ki]);
    float sum = 0.f;
    for(int ki=0; ki<128; ki++){ float e = expf(sS[tid][ki]-m); sS[tid][ki]=e; sum+=e; }
    float inv = 1.0f/sum;
    for(int ki=0; ki<128; ki++) sS[tid][ki] *= inv;
  }
  __syncthreads();
  for(int l=tid; l<2048; l+=256){
    int s=l>>4, d0=(l&15)*4;
    float4 v = *(const float4*)(Vp + base + (size_t)s*Dm + d0);
    kv[s][d0]=v.x; kv[s][d0+1]=v.y; kv[s][d0+2]=v.z; kv[s][d0+3]=v.w;
  }
  __syncthreads();
  float sc = kind ? pmaxb[b] : 1.0f;
  int d0 = quarter*16;
  for(int d=d0; d<d0+16; d++){
    float s=0.f;
    for(int ki=0; ki<128; ki++) s += sS[ql][ki]*kv[ki][d];
    float v = s*sc;
    size_t idx = ((size_t)b*Sm + qi)*1536 + kind*Dm + h*DHm + d;
    unsigned short hh = f2bf(v);
    ctx_hi[idx] = (short)hh;
    ctx_lo[idx] = (short)f2bf(v - bf2f(hh));
  }
}

// ================= token-level Switch routing =================
__global__ __launch_bounds__(256) void k_tok_route(const float* __restrict__ att,
    const float* __restrict__ ur_w, const float* __restrict__ ur_b,
    const int* __restrict__ route_b, float* __restrict__ tok_pmax,
    int* __restrict__ tok_e, int* __restrict__ grp_count)
{
  int n = blockIdx.x, tid = threadIdx.x;
  int i = route_b[n>>7];
  const float* w = ur_w + (size_t)i*Dm*4;
  const float* ap = att + (size_t)n*Dm;
  float a0=0,a1=0,a2=0,a3=0;
  for(int d=tid; d<Dm; d+=256){
    float a = ap[d];
    a0 += a*w[d*4+0]; a1 += a*w[d*4+1];
    a2 += a*w[d*4+2]; a3 += a*w[d*4+3];
  }
  __shared__ float red[4][256];
  red[0][tid]=a0; red[1][tid]=a1; red[2][tid]=a2; red[3][tid]=a3;
  for(int off=128; off>0; off>>=1){
    __syncthreads();
    if(tid<off){ for(int u=0;u<4;u++) red[u][tid]+=red[u][tid+off]; }
  }
  __syncthreads();
  if(tid==0){
    float l[4]; for(int u=0;u<4;u++) l[u]=red[u][0]+ur_b[i*4+u];
    float m=l[0]; int arg=0;
    for(int u=1;u<4;u++) if(l[u]>m){ m=l[u]; arg=u; }
    float s=0; for(int u=0;u<4;u++) s+=expf(l[u]-m);
    tok_pmax[n] = 1.0f/s;
    tok_e[n] = arg;
    atomicAdd(&grp_count[i*4+arg], 1);
  }
}

// ================= prefix + tile worklist =================
__global__ void k_prefix(const int* __restrict__ cnt, int* __restrict__ base,
                         int* __restrict__ cur, int* __restrict__ tlist, int* __restrict__ ntl){
  if(threadIdx.x==0 && blockIdx.x==0){
    int s=0, nt=0;
    for(int g=0; g<16; g++){
      base[g]=s; cur[g]=s;
      int tg = (cnt[g] + BM - 1)/BM;
      for(int t=0; t<tg; t++){ if(nt<64) tlist[nt++] = (g<<8)|t; }
      s += cnt[g];
    }
    ntl[0] = nt;
  }
}

__global__ void k_scatter(const int* __restrict__ route_b, const int* __restrict__ tok_e,
                          int* __restrict__ cur, int* __restrict__ idxl){
  int n = blockIdx.x*256 + threadIdx.x;
  if(n < NT){
    int g = route_b[n>>7]*4 + tok_e[n];
    int pos = atomicAdd(&cur[g], 1);
    idxl[pos] = n;
  }
}

// ======= final residual add + LayerNorm (sums 4+4 bf16 split-K partials) =======
__global__ __launch_bounds__(256) void k_final_ln(const float* __restrict__ att,
    const short* __restrict__ ycf4, const short* __restrict__ yuo4,
    const float* __restrict__ ln_g, const float* __restrict__ ln_b, float* __restrict__ out)
{
  int n = blockIdx.x, tid = threadIdx.x;
  __shared__ float yb[Dm];
  __shared__ float red[256];
  size_t base = (size_t)n*Dm;
  const size_t P = (size_t)NT*Dm;
  float ps = 0.f;
  for(int d=tid; d<Dm; d+=256){
    float v = att[base+d];
    #pragma unroll
    for(int c=0; c<4; c++){
      v += bf2f((unsigned short)ycf4[c*P + base + d]);
      v += bf2f((unsigned short)yuo4[c*P + base + d]);
    }
    yb[d]=v; ps+=v;
  }
  red[tid]=ps;
  for(int off=128; off>0; off>>=1){ __syncthreads(); if(tid<off) red[tid]+=red[tid+off]; }
  __syncthreads();
  float mu = red[0]*(1.0f/Dm);
  __syncthreads();
  float pv = 0.f;
  for(int d=tid; d<Dm; d+=256){ float t = yb[d]-mu; pv += t*t; }
  red[tid]=pv;
  for(int off=128; off>0; off>>=1){ __syncthreads(); if(tid<off) red[tid]+=red[tid+off]; }
  __syncthreads();
  float var = red[0]*(1.0f/Dm);
  float rstd = rsqrtf(var + 1e-12f);
  for(int d=tid; d<Dm; d+=256){
    out[base+d] = (yb[d]-mu)*rstd*ln_g[d] + ln_b[d];
  }
}

extern "C" void kernel_launch(void* const* d_in, const int* in_sizes, int n_in,
                              void* d_out, int out_size, void* d_ws, size_t ws_size,
                              hipStream_t stream)
{
  const float* x     =(const float*)d_in[0];
  const float* mask  =(const float*)d_in[1];
  const float* sw_w  =(const float*)d_in[2];
  const float* sw_b  =(const float*)d_in[3];
  const float* ca_wq =(const float*)d_in[4];
  const float* ca_bq =(const float*)d_in[5];
  const float* ca_wk =(const float*)d_in[6];
  const float* ca_bk =(const float*)d_in[7];
  const float* ca_wv =(const float*)d_in[8];
  const float* ca_bv =(const float*)d_in[9];
  const float* ca_wo =(const float*)d_in[10];
  const float* ca_bo =(const float*)d_in[11];
  const float* ua_wq =(const float*)d_in[12];
  const float* ua_bq =(const float*)d_in[13];
  const float* ua_wk =(const float*)d_in[14];
  const float* ua_bk =(const float*)d_in[15];
  const float* ua_wv =(const float*)d_in[16];
  const float* ua_bv =(const float*)d_in[17];
  const float* ua_wo =(const float*)d_in[18];
  const float* ua_bo =(const float*)d_in[19];
  const float* cf_w1 =(const float*)d_in[20];
  const float* cf_b1 =(const float*)d_in[21];
  const float* cf_w2 =(const float*)d_in[22];
  const float* cf_b2 =(const float*)d_in[23];
  const float* ur_w  =(const float*)d_in[24];
  const float* ur_b  =(const float*)d_in[25];
  const float* uf_w1 =(const float*)d_in[26];
  const float* uf_b1 =(const float*)d_in[27];
  const float* uf_w2 =(const float*)d_in[28];
  const float* uf_b2 =(const float*)d_in[29];
  const float* ln_g  =(const float*)d_in[30];
  const float* ln_b  =(const float*)d_in[31];

  // ---- workspace: region of 8 units (1 unit = NT*Dm f32 = 6.29MB), phase-aliased ----
  // phase A : qkv f32 units0-5 | ctx_hi unit6 (NT*1536 bf16) | ctx_lo unit7
  // phase A2: att2 f32 partials units0-1 (qkv dead)
  // phase B : h_bf units0-1 | hg_bf units2-3 | ycf4 (4 bf16 chunks) units4-5 | yuo4 units6-7
  float* region = (float*)d_ws;
  float* qkv    = region;
  short* ctx_hi = (short*)(region + (size_t)6*NT*Dm);
  short* ctx_lo = (short*)(region + (size_t)7*NT*Dm);
  float* att2   = region;
  short* h_bf   = (short*)region;
  short* hg_bf  = (short*)region + (size_t)NT*Fm;
  short* ycf4   = (short*)(region + (size_t)4*NT*Dm);
  short* yuo4   = (short*)(region + (size_t)6*NT*Dm);
  float* fp     = region + (size_t)8*NT*Dm;
  short* x_hi   = (short*)fp;                 // alive only during mm3_qkv
  short* x_lo   = x_hi + (size_t)NT*Dm;
  float* att    = fp; fp += (size_t)NT*Dm;    // written by k_att_sum (x_hi/lo dead)
  float* tokp   = fp; fp += NT;
  float* pmaxb  = fp; fp += 16;
  short* att_bf = (short*)fp;
  int*   ip     = (int*)(att_bf + (size_t)NT*Dm);
  int* routeb = ip; ip += 16;
  int* toke   = ip; ip += NT;
  int* gcnt   = ip; ip += 16;
  int* gbase  = ip; ip += 16;
  int* gcur   = ip; ip += 16;
  int* idxl   = ip; ip += NT;
  int* tlist  = ip; ip += 64;
  int* ntl    = ip; ip += 1;
  size_t need = (size_t)((char*)ip - (char*)d_ws);
  if(need > ws_size) return;   // bail visibly (output stays 0)

  (void)hipMemsetAsync(gcnt, 0, 16*sizeof(int), stream);

  k_route_batch<<<16, 256, 0, stream>>>(x, sw_w, sw_b, pmaxb, routeb);
  k_split_x<<<(NT*Dm/4 + 255)/256, 256, 0, stream>>>(x, x_hi, x_lo, NT*Dm/4);

  // fused QKV (split precision): z = {cq,ck,cv,uq,uk,uv}
  PtrArr6 pa;
  pa.w[0]=ca_wq; pa.w[1]=ca_wk; pa.w[2]=ca_wv; pa.w[3]=ua_wq; pa.w[4]=ua_wk; pa.w[5]=ua_wv;
  pa.b[0]=ca_bq; pa.b[1]=ca_bk; pa.b[2]=ca_bv; pa.b[3]=ua_bq; pa.b[4]=ua_bk; pa.b[5]=ua_bv;
  mm3_qkv<<<dim3(Dm/BN, NT/BM, 6), 256, 0, stream>>>(x_hi, x_lo, pa, routeb, qkv);

  // attention (f32 -> ctx hi/lo bf16): z = qh + 2*kind
  k_attn_f<<<dim3(Hm, Bm, 4), 256, 0, stream>>>(qkv, mask, pmaxb, ctx_hi, ctx_lo);

  // output projection, split-K=2 (z): partials into dead qkv units
  mm3_outproj<<<dim3(Dm/BN, NT/BM, 2), 256, 0, stream>>>(ctx_hi, ctx_lo, ca_wo, ua_wo,
                                                         ca_bo, ua_bo, routeb, pmaxb, att2);
  k_att_sum<<<(NT*Dm/4 + 255)/256, 256, 0, stream>>>(att2, att, att_bf, NT*Dm/4);

  // token routing + grouping (from f32 att -> flip-safe)
  k_tok_route<<<NT, 256, 0, stream>>>(att, ur_w, ur_b, routeb, tokp, toke, gcnt);
  k_prefix<<<1, 64, 0, stream>>>(gcnt, gbase, gcur, tlist, ntl);
  k_scatter<<<NT/256, 256, 0, stream>>>(routeb, toke, gcur, idxl);

  // F-stage: common FFN1 + grouped Switch-FFN1 in one dispatch
  mm_fstage<<<dim3(Fm/BN, 32+48), 256, 0, stream>>>(att_bf, cf_w1, cf_b1, uf_w1, uf_b1,
                                                    idxl, gbase, gcnt, tlist, ntl, h_bf, hg_bf);

  // D-stage: split-K=4, bf16 partial buffers
  mm_dstage<<<dim3(Dm/BN, 32+48, 4), 256, 0, stream>>>(h_bf, hg_bf, cf_w2, cf_b2, uf_w2, uf_b2,
                                                       idxl, gbase, gcnt, tlist, ntl, tokp,
                                                       ycf4, yuo4);

  k_final_ln<<<NT, 256, 0, stream>>>(att, ycf4, yuo4, ln_g, ln_b, (float*)d_out);
}

// Round 9
// 678.745 us; speedup vs baseline: 4.9663x; 1.1521x over previous
//
#include <hip/hip_runtime.h>

#define NT 2048
#define Dm 768
#define Fm 3072
#define Bm 16
#define Sm 128
#define Hm 12
#define DHm 64

#define BM 64
#define BN 128
#define BK 32

typedef __attribute__((ext_vector_type(8))) short bf16x8;
typedef __attribute__((ext_vector_type(4))) float f32x4;

__device__ __forceinline__ unsigned short f2bf(float f){
  unsigned u = __float_as_uint(f);
  unsigned r = (u + 0x7fffu + ((u>>16)&1u)) >> 16;   // round-nearest-even
  return (unsigned short)r;
}
__device__ __forceinline__ float bf2f(unsigned short h){ return __uint_as_float(((unsigned)h)<<16); }
// split f32 into hi/lo bf16 pair, packed: hi = bits[15:0], lo = bits[31:16]
__device__ __forceinline__ unsigned fsplit2(float x){
  unsigned short h = f2bf(x);
  unsigned short l = f2bf(x - bf2f(h));
  return (unsigned)h | ((unsigned)l << 16);
}
__device__ __forceinline__ float gelu_f(float x){
  return 0.5f*x*(1.0f + erff(x*0.70710678118654752f));
}

// ========== barrier-free direct-to-register bf16 MFMA tile loop ==========
// Each wave loads its own fragments straight from global; no LDS, no __syncthreads.
// gidx: optional row gather (grow = gidx[m0+lr]); mbound: valid row count (pad -> zeros).
__device__ __forceinline__ void mm_tile(
    const short* __restrict__ Abf, int lda,
    const int* __restrict__ gidx, int m0, int mbound,
    const float* __restrict__ W0, int N, int K, int n0,
    f32x4 acc[2][4])
{
  int lane = threadIdx.x & 63, wv = threadIdx.x >> 6;
  int wm = wv & 1, wn = wv >> 1;
  int oct = lane >> 4, l16 = lane & 15;
  const short* aptr[2];
  #pragma unroll
  for(int fi=0; fi<2; fi++){
    int lr = wm*32 + fi*16 + l16;
    int grow = (lr < mbound) ? (gidx ? gidx[m0 + lr] : (m0 + lr)) : -1;
    aptr[fi] = (grow >= 0) ? (Abf + (size_t)grow*lda + oct*8) : nullptr;
  }
  const float* bptr[4];
  #pragma unroll
  for(int fj=0; fj<4; fj++)
    bptr[fj] = W0 + (size_t)(oct*8)*N + (n0 + wn*64 + fj*16 + l16);

  const bf16x8 zz = {0,0,0,0,0,0,0,0};
  bf16x8 av[2]; float bw[4][8];
  #pragma unroll
  for(int fi=0; fi<2; fi++) av[fi] = aptr[fi] ? *(const bf16x8*)(aptr[fi]) : zz;
  #pragma unroll
  for(int fj=0; fj<4; fj++)
    #pragma unroll
    for(int i=0;i<8;i++) bw[fj][i] = bptr[fj][(size_t)i*N];

  for(int k0=0; k0<K; k0+=BK){
    bf16x8 af[2]; af[0]=av[0]; af[1]=av[1];
    bf16x8 bfr[4];
    #pragma unroll
    for(int fj=0; fj<4; fj++)
      #pragma unroll
      for(int i=0;i<8;i++) bfr[fj][i] = (short)f2bf(bw[fj][i]);
    if(k0+BK < K){
      int kn = k0 + BK;
      #pragma unroll
      for(int fi=0; fi<2; fi++) av[fi] = aptr[fi] ? *(const bf16x8*)(aptr[fi] + kn) : zz;
      #pragma unroll
      for(int fj=0; fj<4; fj++)
        #pragma unroll
        for(int i=0;i<8;i++) bw[fj][i] = bptr[fj][(size_t)(kn + i)*N];
    }
    #pragma unroll
    for(int fi=0; fi<2; fi++)
      #pragma unroll
      for(int fj=0; fj<4; fj++)
        acc[fi][fj] = __builtin_amdgcn_mfma_f32_16x16x32_bf16(af[fi], bfr[fj], acc[fi][fj], 0, 0, 0);
  }
}

// ===== barrier-free split-bf16 ("bf16x3") tile loop: A pre-split hi/lo, W split on the fly =====
__device__ __forceinline__ void mm_tile3b(
    const short* __restrict__ Ahi, const short* __restrict__ Alo, int lda, int m0, int acol,
    const float* __restrict__ W0, int N, int K, int n0,
    f32x4 acc[2][4])
{
  int lane = threadIdx.x & 63, wv = threadIdx.x >> 6;
  int wm = wv & 1, wn = wv >> 1;
  int oct = lane >> 4, l16 = lane & 15;
  size_t aoffs[2];
  #pragma unroll
  for(int fi=0; fi<2; fi++){
    int lr = wm*32 + fi*16 + l16;
    aoffs[fi] = (size_t)(m0 + lr)*lda + acol + oct*8;
  }
  const float* bptr[4];
  #pragma unroll
  for(int fj=0; fj<4; fj++)
    bptr[fj] = W0 + (size_t)(oct*8)*N + (n0 + wn*64 + fj*16 + l16);

  bf16x8 avH[2], avL[2]; float bw[4][8];
  #pragma unroll
  for(int fi=0; fi<2; fi++){
    avH[fi] = *(const bf16x8*)(Ahi + aoffs[fi]);
    avL[fi] = *(const bf16x8*)(Alo + aoffs[fi]);
  }
  #pragma unroll
  for(int fj=0; fj<4; fj++)
    #pragma unroll
    for(int i=0;i<8;i++) bw[fj][i] = bptr[fj][(size_t)i*N];

  for(int k0=0; k0<K; k0+=BK){
    bf16x8 ah[2], al[2];
    #pragma unroll
    for(int fi=0; fi<2; fi++){ ah[fi]=avH[fi]; al[fi]=avL[fi]; }
    bf16x8 bh[4], bl[4];
    #pragma unroll
    for(int fj=0; fj<4; fj++)
      #pragma unroll
      for(int i=0;i<8;i++){
        unsigned p = fsplit2(bw[fj][i]);
        bh[fj][i] = (short)(p & 0xffff);
        bl[fj][i] = (short)(p >> 16);
      }
    if(k0+BK < K){
      int kn = k0 + BK;
      #pragma unroll
      for(int fi=0; fi<2; fi++){
        avH[fi] = *(const bf16x8*)(Ahi + aoffs[fi] + kn);
        avL[fi] = *(const bf16x8*)(Alo + aoffs[fi] + kn);
      }
      #pragma unroll
      for(int fj=0; fj<4; fj++)
        #pragma unroll
        for(int i=0;i<8;i++) bw[fj][i] = bptr[fj][(size_t)(kn + i)*N];
    }
    #pragma unroll
    for(int fi=0; fi<2; fi++)
      #pragma unroll
      for(int fj=0; fj<4; fj++){
        acc[fi][fj] = __builtin_amdgcn_mfma_f32_16x16x32_bf16(ah[fi], bh[fj], acc[fi][fj], 0, 0, 0);
        acc[fi][fj] = __builtin_amdgcn_mfma_f32_16x16x32_bf16(ah[fi], bl[fj], acc[fi][fj], 0, 0, 0);
        acc[fi][fj] = __builtin_amdgcn_mfma_f32_16x16x32_bf16(al[fi], bh[fj], acc[fi][fj], 0, 0, 0);
      }
  }
}

// ================= x -> hi/lo bf16 pre-split =================
__global__ __launch_bounds__(256) void k_split_x(const float* __restrict__ in,
    short* __restrict__ hi, short* __restrict__ lo, int n4){
  int i = blockIdx.x*256 + threadIdx.x;
  if(i < n4){
    float4 v = ((const float4*)in)[i];
    unsigned p0 = fsplit2(v.x), p1 = fsplit2(v.y), p2 = fsplit2(v.z), p3 = fsplit2(v.w);
    short4 h, l;
    h.x=(short)(p0&0xffff); l.x=(short)(p0>>16);
    h.y=(short)(p1&0xffff); l.y=(short)(p1>>16);
    h.z=(short)(p2&0xffff); l.z=(short)(p2>>16);
    h.w=(short)(p3&0xffff); l.w=(short)(p3>>16);
    ((short4*)hi)[i] = h;
    ((short4*)lo)[i] = l;
  }
}

// ================= fused QKV (common + unique), split precision, f32 out =================
struct PtrArr6 { const float* w[6]; const float* b[6]; };

__global__ __launch_bounds__(256) void mm3_qkv(const short* __restrict__ x_hi,
    const short* __restrict__ x_lo, PtrArr6 pa,
    const int* __restrict__ routeb, float* __restrict__ qkvout)
{
  int n0 = blockIdx.x*BN, m0 = blockIdx.y*BM, z = blockIdx.z;
  int bidx = m0 >> 7;
  const float* W = pa.w[z]; const float* bias = pa.b[z];
  if(z >= 3){ int e = routeb[bidx]; W += (size_t)e*Dm*Dm; bias += (size_t)e*Dm; }
  f32x4 acc[2][4] = {};
  mm_tile3b(x_hi, x_lo, Dm, m0, 0, W, Dm, Dm, n0, acc);
  float* outp = qkvout + (size_t)z*NT*Dm;
  int lane = threadIdx.x&63, wv = threadIdx.x>>6, wm = wv&1, wn = wv>>1;
  #pragma unroll
  for(int fi=0; fi<2; fi++)
    #pragma unroll
    for(int fj=0; fj<4; fj++)
      #pragma unroll
      for(int r=0; r<4; r++){
        int row = m0 + wm*32 + fi*16 + ((lane>>4)<<2) + r;
        int col = n0 + wn*64 + fj*16 + (lane&15);
        outp[(size_t)row*Dm + col] = acc[fi][fj][r] + bias[col];
      }
}

// ================= output projection, split-K via z (kc=0 common, kc=1 unique) =================
__global__ __launch_bounds__(256) void mm3_outproj(const short* __restrict__ ctx_hi,
    const short* __restrict__ ctx_lo,
    const float* __restrict__ ca_wo, const float* __restrict__ ua_wo,
    const float* __restrict__ ca_bo, const float* __restrict__ ua_bo,
    const int* __restrict__ routeb, const float* __restrict__ pmaxb,
    float* __restrict__ att2)
{
  int n0 = blockIdx.x*BN, m0 = blockIdx.y*BM, kc = blockIdx.z;
  int bidx = m0 >> 7;
  int e = routeb[bidx];
  const float* W    = kc ? (ua_wo + (size_t)e*Dm*Dm) : ca_wo;
  const float* bias = kc ? (ua_bo + (size_t)e*Dm)    : ca_bo;
  float bscale = kc ? pmaxb[bidx] : 1.0f;
  f32x4 acc[2][4] = {};
  mm_tile3b(ctx_hi, ctx_lo, 1536, m0, kc*Dm, W, Dm, Dm, n0, acc);
  float* outp = att2 + (size_t)kc*NT*Dm;
  int lane = threadIdx.x&63, wv = threadIdx.x>>6, wm = wv&1, wn = wv>>1;
  #pragma unroll
  for(int fi=0; fi<2; fi++)
    #pragma unroll
    for(int fj=0; fj<4; fj++)
      #pragma unroll
      for(int r=0; r<4; r++){
        int row = m0 + wm*32 + fi*16 + ((lane>>4)<<2) + r;
        int col = n0 + wn*64 + fj*16 + (lane&15);
        outp[(size_t)row*Dm + col] = acc[fi][fj][r] + bscale*bias[col];
      }
}

// ================= att = att2[0] + att2[1]; also emit bf16 =================
__global__ __launch_bounds__(256) void k_att_sum(const float* __restrict__ att2,
    float* __restrict__ att, short* __restrict__ attbf, int n4){
  int i = blockIdx.x*256 + threadIdx.x;
  if(i < n4){
    const size_t P4 = (size_t)NT*Dm/4;
    float4 a = ((const float4*)att2)[i];
    float4 b = ((const float4*)att2)[P4 + i];
    float4 v; v.x=a.x+b.x; v.y=a.y+b.y; v.z=a.z+b.z; v.w=a.w+b.w;
    ((float4*)att)[i] = v;
    short4 o;
    o.x=(short)f2bf(v.x); o.y=(short)f2bf(v.y); o.z=(short)f2bf(v.z); o.w=(short)f2bf(v.w);
    ((short4*)attbf)[i] = o;
  }
}

// ================= F-stage: common FFN1 (y<32) + grouped Switch-FFN1 (tile list) =================
__global__ __launch_bounds__(256) void mm_fstage(const short* __restrict__ attbf,
    const float* __restrict__ cf_w1, const float* __restrict__ cf_b1,
    const float* __restrict__ uf_w1, const float* __restrict__ uf_b1,
    const int* __restrict__ idxl, const int* __restrict__ gbase, const int* __restrict__ gcnt,
    const int* __restrict__ tlist, const int* __restrict__ ntl,
    short* __restrict__ h, short* __restrict__ hg)
{
  int n0 = blockIdx.x*BN, y = blockIdx.y;
  int lane = threadIdx.x&63, wv = threadIdx.x>>6, wm = wv&1, wn = wv>>1;
  f32x4 acc[2][4] = {};
  if(y < 32){
    int m0 = y*BM;
    mm_tile(attbf, Dm, nullptr, m0, BM, cf_w1, Fm, Dm, n0, acc);
    #pragma unroll
    for(int fi=0; fi<2; fi++)
      #pragma unroll
      for(int fj=0; fj<4; fj++)
        #pragma unroll
        for(int r=0; r<4; r++){
          int row = m0 + wm*32 + fi*16 + ((lane>>4)<<2) + r;
          int col = n0 + wn*64 + fj*16 + (lane&15);
          h[(size_t)row*Fm + col] = (short)f2bf(gelu_f(acc[fi][fj][r] + cf_b1[col]));
        }
  } else {
    int i = y - 32;
    if(i >= ntl[0]) return;
    int v = tlist[i], g = v>>8, t = v&255;
    int cnt = gcnt[g], r0 = t*BM, pos0 = gbase[g] + r0;
    mm_tile(attbf, Dm, idxl, pos0, cnt - r0, uf_w1 + (size_t)g*Dm*Fm, Fm, Dm, n0, acc);
    const float* bias = uf_b1 + (size_t)g*Fm;
    #pragma unroll
    for(int fi=0; fi<2; fi++)
      #pragma unroll
      for(int fj=0; fj<4; fj++)
        #pragma unroll
        for(int r=0; r<4; r++){
          int lr = wm*32 + fi*16 + ((lane>>4)<<2) + r;
          if(r0 + lr >= cnt) continue;
          int col = n0 + wn*64 + fj*16 + (lane&15);
          hg[(size_t)(pos0+lr)*Fm + col] = (short)f2bf(gelu_f(acc[fi][fj][r] + bias[col]));
        }
  }
}

// ================= D-stage: split-K (z=kc of 4), bf16 partials =================
__global__ __launch_bounds__(256) void mm_dstage(const short* __restrict__ h,
    const short* __restrict__ hg,
    const float* __restrict__ cf_w2, const float* __restrict__ cf_b2,
    const float* __restrict__ uf_w2, const float* __restrict__ uf_b2,
    const int* __restrict__ idxl, const int* __restrict__ gbase, const int* __restrict__ gcnt,
    const int* __restrict__ tlist, const int* __restrict__ ntl,
    const float* __restrict__ tokp, short* __restrict__ ycf4, short* __restrict__ yuo4)
{
  const int KC = Fm/4;   // 768
  int n0 = blockIdx.x*BN, y = blockIdx.y, kc = blockIdx.z;
  int lane = threadIdx.x&63, wv = threadIdx.x>>6, wm = wv&1, wn = wv>>1;
  f32x4 acc[2][4] = {};
  if(y < 32){
    int m0 = y*BM;
    mm_tile(h + kc*KC, Fm, nullptr, m0, BM, cf_w2 + (size_t)kc*KC*Dm, Dm, KC, n0, acc);
    short* outp = ycf4 + (size_t)kc*NT*Dm;
    #pragma unroll
    for(int fi=0; fi<2; fi++)
      #pragma unroll
      for(int fj=0; fj<4; fj++)
        #pragma unroll
        for(int r=0; r<4; r++){
          int row = m0 + wm*32 + fi*16 + ((lane>>4)<<2) + r;
          int col = n0 + wn*64 + fj*16 + (lane&15);
          outp[(size_t)row*Dm + col] = (short)f2bf(acc[fi][fj][r] + (kc==0 ? cf_b2[col] : 0.f));
        }
  } else {
    int i = y - 32;
    if(i >= ntl[0]) return;
    int v = tlist[i], g = v>>8, t = v&255;
    int cnt = gcnt[g], r0 = t*BM, pos0 = gbase[g] + r0;
    mm_tile(hg + kc*KC, Fm, nullptr, pos0, cnt - r0,
            uf_w2 + (size_t)g*Fm*Dm + (size_t)kc*KC*Dm, Dm, KC, n0, acc);
    const float* bias = uf_b2 + (size_t)g*Dm;
    short* outp = yuo4 + (size_t)kc*NT*Dm;
    #pragma unroll
    for(int fi=0; fi<2; fi++)
      #pragma unroll
      for(int fj=0; fj<4; fj++)
        #pragma unroll
        for(int r=0; r<4; r++){
          int lr = wm*32 + fi*16 + ((lane>>4)<<2) + r;
          int rm = (r0 + lr < cnt) ? idxl[pos0 + lr] : -1;
          if(rm < 0) continue;
          int col = n0 + wn*64 + fj*16 + (lane&15);
          float vv = acc[fi][fj][r] + (kc==0 ? bias[col] : 0.f);
          outp[(size_t)rm*Dm + col] = (short)f2bf(vv * tokp[rm]);
        }
  }
}

// ================= batch-level routing =================
__global__ __launch_bounds__(256) void k_route_batch(const float* __restrict__ xf,
    const float* __restrict__ sw_w, const float* __restrict__ sw_b,
    float* __restrict__ pmax_b, int* __restrict__ route_b){
  int b = blockIdx.x, tid = threadIdx.x;
  __shared__ float xm[Dm];
  for(int d=tid; d<Dm; d+=256){
    float s=0.f;
    const float* xp = xf + ((size_t)b*Sm)*Dm + d;
    for(int ss=0; ss<Sm; ss++) s += xp[(size_t)ss*Dm];
    xm[d] = s*(1.0f/Sm);
  }
  __syncthreads();
  float a0=0,a1=0,a2=0,a3=0;
  for(int d=tid; d<Dm; d+=256){
    float xv = xm[d];
    a0 += xv*sw_w[d*4+0]; a1 += xv*sw_w[d*4+1];
    a2 += xv*sw_w[d*4+2]; a3 += xv*sw_w[d*4+3];
  }
  __shared__ float red[4][256];
  red[0][tid]=a0; red[1][tid]=a1; red[2][tid]=a2; red[3][tid]=a3;
  for(int off=128; off>0; off>>=1){
    __syncthreads();
    if(tid<off){ for(int u=0;u<4;u++) red[u][tid]+=red[u][tid+off]; }
  }
  __syncthreads();
  if(tid==0){
    float l[4]; for(int u=0;u<4;u++) l[u]=red[u][0]+sw_b[u];
    float m=l[0]; int arg=0;
    for(int u=1;u<4;u++) if(l[u]>m){ m=l[u]; arg=u; }
    float s=0; for(int u=0;u<4;u++) s+=expf(l[u]-m);
    pmax_b[b]=1.0f/s;
    route_b[b]=arg;
  }
}

// ====== attention (f32 in; ctx out as hi/lo bf16 [2048][1536], unique pre-scaled) ======
__global__ __launch_bounds__(256) void k_attn_f(const float* __restrict__ qkv,
    const float* __restrict__ mask, const float* __restrict__ pmaxb,
    short* __restrict__ ctx_hi, short* __restrict__ ctx_lo)
{
  int h = blockIdx.x, b = blockIdx.y, z = blockIdx.z;
  int qh = z & 1, kind = z >> 1;
  const float* Q  = qkv + (size_t)(kind*3+0)*NT*Dm;
  const float* Kp = qkv + (size_t)(kind*3+1)*NT*Dm;
  const float* Vp = qkv + (size_t)(kind*3+2)*NT*Dm;
  int tid = threadIdx.x;
  __shared__ float kv[128][64];
  __shared__ float sS[64][128];
  size_t base = ((size_t)b*Sm)*Dm + h*DHm;
  for(int l=tid; l<2048; l+=256){
    int s=l>>4, d0=(l&15)*4;
    float4 v = *(const float4*)(Kp + base + (size_t)s*Dm + d0);
    kv[s][d0]=v.x; kv[s][d0+1]=v.y; kv[s][d0+2]=v.z; kv[s][d0+3]=v.w;
  }
  __syncthreads();
  int ql = tid>>2, quarter = tid&3;
  int qi = qh*64 + ql;
  float qreg[64];
  const float* qp = Q + base + (size_t)qi*Dm;
  #pragma unroll
  for(int d=0; d<64; d++) qreg[d] = qp[d];
  int kb = quarter*32;
  for(int ki=kb; ki<kb+32; ki++){
    float s=0.f;
    #pragma unroll
    for(int d=0; d<64; d++) s += qreg[d]*kv[ki][d];
    sS[ql][ki] = s*0.125f + mask[b*Sm+ki];
  }
  __syncthreads();
  if(tid < 64){
    float m = -3.4e38f;
    for(int ki=0; ki<128; ki++) m = fmaxf(m, sS[tid][ki]);
    float sum = 0.f;
    for(int ki=0; ki<128; ki++){ float e = expf(sS[tid][ki]-m); sS[tid][ki]=e; sum+=e; }
    float inv = 1.0f/sum;
    for(int ki=0; ki<128; ki++) sS[tid][ki] *= inv;
  }
  __syncthreads();
  for(int l=tid; l<2048; l+=256){
    int s=l>>4, d0=(l&15)*4;
    float4 v = *(const float4*)(Vp + base + (size_t)s*Dm + d0);
    kv[s][d0]=v.x; kv[s][d0+1]=v.y; kv[s][d0+2]=v.z; kv[s][d0+3]=v.w;
  }
  __syncthreads();
  float sc = kind ? pmaxb[b] : 1.0f;
  int d0 = quarter*16;
  for(int d=d0; d<d0+16; d++){
    float s=0.f;
    for(int ki=0; ki<128; ki++) s += sS[ql][ki]*kv[ki][d];
    float v = s*sc;
    size_t idx = ((size_t)b*Sm + qi)*1536 + kind*Dm + h*DHm + d;
    unsigned short hh = f2bf(v);
    ctx_hi[idx] = (short)hh;
    ctx_lo[idx] = (short)f2bf(v - bf2f(hh));
  }
}

// ================= token-level Switch routing =================
__global__ __launch_bounds__(256) void k_tok_route(const float* __restrict__ att,
    const float* __restrict__ ur_w, const float* __restrict__ ur_b,
    const int* __restrict__ route_b, float* __restrict__ tok_pmax,
    int* __restrict__ tok_e, int* __restrict__ grp_count)
{
  int n = blockIdx.x, tid = threadIdx.x;
  int i = route_b[n>>7];
  const float* w = ur_w + (size_t)i*Dm*4;
  const float* ap = att + (size_t)n*Dm;
  float a0=0,a1=0,a2=0,a3=0;
  for(int d=tid; d<Dm; d+=256){
    float a = ap[d];
    a0 += a*w[d*4+0]; a1 += a*w[d*4+1];
    a2 += a*w[d*4+2]; a3 += a*w[d*4+3];
  }
  __shared__ float red[4][256];
  red[0][tid]=a0; red[1][tid]=a1; red[2][tid]=a2; red[3][tid]=a3;
  for(int off=128; off>0; off>>=1){
    __syncthreads();
    if(tid<off){ for(int u=0;u<4;u++) red[u][tid]+=red[u][tid+off]; }
  }
  __syncthreads();
  if(tid==0){
    float l[4]; for(int u=0;u<4;u++) l[u]=red[u][0]+ur_b[i*4+u];
    float m=l[0]; int arg=0;
    for(int u=1;u<4;u++) if(l[u]>m){ m=l[u]; arg=u; }
    float s=0; for(int u=0;u<4;u++) s+=expf(l[u]-m);
    tok_pmax[n] = 1.0f/s;
    tok_e[n] = arg;
    atomicAdd(&grp_count[i*4+arg], 1);
  }
}

// ================= prefix + tile worklist =================
__global__ void k_prefix(const int* __restrict__ cnt, int* __restrict__ base,
                         int* __restrict__ cur, int* __restrict__ tlist, int* __restrict__ ntl){
  if(threadIdx.x==0 && blockIdx.x==0){
    int s=0, nt=0;
    for(int g=0; g<16; g++){
      base[g]=s; cur[g]=s;
      int tg = (cnt[g] + BM - 1)/BM;
      for(int t=0; t<tg; t++){ if(nt<64) tlist[nt++] = (g<<8)|t; }
      s += cnt[g];
    }
    ntl[0] = nt;
  }
}

__global__ void k_scatter(const int* __restrict__ route_b, const int* __restrict__ tok_e,
                          int* __restrict__ cur, int* __restrict__ idxl){
  int n = blockIdx.x*256 + threadIdx.x;
  if(n < NT){
    int g = route_b[n>>7]*4 + tok_e[n];
    int pos = atomicAdd(&cur[g], 1);
    idxl[pos] = n;
  }
}

// ======= final residual add + LayerNorm (sums 4+4 bf16 split-K partials) =======
__global__ __launch_bounds__(256) void k_final_ln(const float* __restrict__ att,
    const short* __restrict__ ycf4, const short* __restrict__ yuo4,
    const float* __restrict__ ln_g, const float* __restrict__ ln_b, float* __restrict__ out)
{
  int n = blockIdx.x, tid = threadIdx.x;
  __shared__ float yb[Dm];
  __shared__ float red[256];
  size_t base = (size_t)n*Dm;
  const size_t P = (size_t)NT*Dm;
  float ps = 0.f;
  for(int d=tid; d<Dm; d+=256){
    float v = att[base+d];
    #pragma unroll
    for(int c=0; c<4; c++){
      v += bf2f((unsigned short)ycf4[c*P + base + d]);
      v += bf2f((unsigned short)yuo4[c*P + base + d]);
    }
    yb[d]=v; ps+=v;
  }
  red[tid]=ps;
  for(int off=128; off>0; off>>=1){ __syncthreads(); if(tid<off) red[tid]+=red[tid+off]; }
  __syncthreads();
  float mu = red[0]*(1.0f/Dm);
  __syncthreads();
  float pv = 0.f;
  for(int d=tid; d<Dm; d+=256){ float t = yb[d]-mu; pv += t*t; }
  red[tid]=pv;
  for(int off=128; off>0; off>>=1){ __syncthreads(); if(tid<off) red[tid]+=red[tid+off]; }
  __syncthreads();
  float var = red[0]*(1.0f/Dm);
  float rstd = rsqrtf(var + 1e-12f);
  for(int d=tid; d<Dm; d+=256){
    out[base+d] = (yb[d]-mu)*rstd*ln_g[d] + ln_b[d];
  }
}

extern "C" void kernel_launch(void* const* d_in, const int* in_sizes, int n_in,
                              void* d_out, int out_size, void* d_ws, size_t ws_size,
                              hipStream_t stream)
{
  const float* x     =(const float*)d_in[0];
  const float* mask  =(const float*)d_in[1];
  const float* sw_w  =(const float*)d_in[2];
  const float* sw_b  =(const float*)d_in[3];
  const float* ca_wq =(const float*)d_in[4];
  const float* ca_bq =(const float*)d_in[5];
  const float* ca_wk =(const float*)d_in[6];
  const float* ca_bk =(const float*)d_in[7];
  const float* ca_wv =(const float*)d_in[8];
  const float* ca_bv =(const float*)d_in[9];
  const float* ca_wo =(const float*)d_in[10];
  const float* ca_bo =(const float*)d_in[11];
  const float* ua_wq =(const float*)d_in[12];
  const float* ua_bq =(const float*)d_in[13];
  const float* ua_wk =(const float*)d_in[14];
  const float* ua_bk =(const float*)d_in[15];
  const float* ua_wv =(const float*)d_in[16];
  const float* ua_bv =(const float*)d_in[17];
  const float* ua_wo =(const float*)d_in[18];
  const float* ua_bo =(const float*)d_in[19];
  const float* cf_w1 =(const float*)d_in[20];
  const float* cf_b1 =(const float*)d_in[21];
  const float* cf_w2 =(const float*)d_in[22];
  const float* cf_b2 =(const float*)d_in[23];
  const float* ur_w  =(const float*)d_in[24];
  const float* ur_b  =(const float*)d_in[25];
  const float* uf_w1 =(const float*)d_in[26];
  const float* uf_b1 =(const float*)d_in[27];
  const float* uf_w2 =(const float*)d_in[28];
  const float* uf_b2 =(const float*)d_in[29];
  const float* ln_g  =(const float*)d_in[30];
  const float* ln_b  =(const float*)d_in[31];

  // ---- workspace: region of 8 units (1 unit = NT*Dm f32 = 6.29MB), phase-aliased ----
  // phase A : qkv f32 units0-5 | ctx_hi unit6 (NT*1536 bf16) | ctx_lo unit7
  // phase A2: att2 f32 partials units0-1 (qkv dead)
  // phase B : h_bf units0-1 | hg_bf units2-3 | ycf4 (4 bf16 chunks) units4-5 | yuo4 units6-7
  float* region = (float*)d_ws;
  float* qkv    = region;
  short* ctx_hi = (short*)(region + (size_t)6*NT*Dm);
  short* ctx_lo = (short*)(region + (size_t)7*NT*Dm);
  float* att2   = region;
  short* h_bf   = (short*)region;
  short* hg_bf  = (short*)region + (size_t)NT*Fm;
  short* ycf4   = (short*)(region + (size_t)4*NT*Dm);
  short* yuo4   = (short*)(region + (size_t)6*NT*Dm);
  float* fp     = region + (size_t)8*NT*Dm;
  short* x_hi   = (short*)fp;                 // alive only during mm3_qkv
  short* x_lo   = x_hi + (size_t)NT*Dm;
  float* att    = fp; fp += (size_t)NT*Dm;    // written by k_att_sum (x_hi/lo dead)
  float* tokp   = fp; fp += NT;
  float* pmaxb  = fp; fp += 16;
  short* att_bf = (short*)fp;
  int*   ip     = (int*)(att_bf + (size_t)NT*Dm);
  int* routeb = ip; ip += 16;
  int* toke   = ip; ip += NT;
  int* gcnt   = ip; ip += 16;
  int* gbase  = ip; ip += 16;
  int* gcur   = ip; ip += 16;
  int* idxl   = ip; ip += NT;
  int* tlist  = ip; ip += 64;
  int* ntl    = ip; ip += 1;
  size_t need = (size_t)((char*)ip - (char*)d_ws);
  if(need > ws_size) return;   // bail visibly (output stays 0)

  (void)hipMemsetAsync(gcnt, 0, 16*sizeof(int), stream);

  k_route_batch<<<16, 256, 0, stream>>>(x, sw_w, sw_b, pmaxb, routeb);
  k_split_x<<<(NT*Dm/4 + 255)/256, 256, 0, stream>>>(x, x_hi, x_lo, NT*Dm/4);

  // fused QKV (split precision): z = {cq,ck,cv,uq,uk,uv}
  PtrArr6 pa;
  pa.w[0]=ca_wq; pa.w[1]=ca_wk; pa.w[2]=ca_wv; pa.w[3]=ua_wq; pa.w[4]=ua_wk; pa.w[5]=ua_wv;
  pa.b[0]=ca_bq; pa.b[1]=ca_bk; pa.b[2]=ca_bv; pa.b[3]=ua_bq; pa.b[4]=ua_bk; pa.b[5]=ua_bv;
  mm3_qkv<<<dim3(Dm/BN, NT/BM, 6), 256, 0, stream>>>(x_hi, x_lo, pa, routeb, qkv);

  // attention (f32 -> ctx hi/lo bf16): z = qh + 2*kind
  k_attn_f<<<dim3(Hm, Bm, 4), 256, 0, stream>>>(qkv, mask, pmaxb, ctx_hi, ctx_lo);

  // output projection, split-K=2 (z): partials into dead qkv units
  mm3_outproj<<<dim3(Dm/BN, NT/BM, 2), 256, 0, stream>>>(ctx_hi, ctx_lo, ca_wo, ua_wo,
                                                         ca_bo, ua_bo, routeb, pmaxb, att2);
  k_att_sum<<<(NT*Dm/4 + 255)/256, 256, 0, stream>>>(att2, att, att_bf, NT*Dm/4);

  // token routing + grouping (from f32 att -> flip-safe)
  k_tok_route<<<NT, 256, 0, stream>>>(att, ur_w, ur_b, routeb, tokp, toke, gcnt);
  k_prefix<<<1, 64, 0, stream>>>(gcnt, gbase, gcur, tlist, ntl);
  k_scatter<<<NT/256, 256, 0, stream>>>(routeb, toke, gcur, idxl);

  // F-stage: common FFN1 + grouped Switch-FFN1 in one dispatch
  mm_fstage<<<dim3(Fm/BN, 32+48), 256, 0, stream>>>(att_bf, cf_w1, cf_b1, uf_w1, uf_b1,
                                                    idxl, gbase, gcnt, tlist, ntl, h_bf, hg_bf);

  // D-stage: split-K=4, bf16 partial buffers
  mm_dstage<<<dim3(Dm/BN, 32+48, 4), 256, 0, stream>>>(h_bf, hg_bf, cf_w2, cf_b2, uf_w2, uf_b2,
                                                       idxl, gbase, gcnt, tlist, ntl, tokp,
                                                       ycf4, yuo4);

  k_final_ln<<<NT, 256, 0, stream>>>(att, ycf4, yuo4, ln_g, ln_b, (float*)d_out);
}

// Round 10
// 602.765 us; speedup vs baseline: 5.5923x; 1.1261x over previous
//
#include <hip/hip_runtime.h>

#define NT 2048
#define Dm 768
#define Fm 3072
#define Bm 16
#define Sm 128
#define Hm 12
#define DHm 64

#define BM 64
#define BN 128
#define BK 32

typedef __attribute__((ext_vector_type(8))) short bf16x8;
typedef __attribute__((ext_vector_type(4))) float f32x4;

__device__ __forceinline__ unsigned short f2bf(float f){
  unsigned u = __float_as_uint(f);
  unsigned r = (u + 0x7fffu + ((u>>16)&1u)) >> 16;   // round-nearest-even
  return (unsigned short)r;
}
__device__ __forceinline__ float bf2f(unsigned short h){ return __uint_as_float(((unsigned)h)<<16); }
// split f32 into hi/lo bf16 pair, packed: hi = bits[15:0], lo = bits[31:16]
__device__ __forceinline__ unsigned fsplit2(float x){
  unsigned short h = f2bf(x);
  unsigned short l = f2bf(x - bf2f(h));
  return (unsigned)h | ((unsigned)l << 16);
}
__device__ __forceinline__ float gelu_f(float x){
  return 0.5f*x*(1.0f + erff(x*0.70710678118654752f));
}

// ========== barrier-free direct-to-register bf16 MFMA tile loop ==========
__device__ __forceinline__ void mm_tile(
    const short* __restrict__ Abf, int lda,
    const int* __restrict__ gidx, int m0, int mbound,
    const float* __restrict__ W0, int N, int K, int n0,
    f32x4 acc[2][4])
{
  int lane = threadIdx.x & 63, wv = threadIdx.x >> 6;
  int wm = wv & 1, wn = wv >> 1;
  int oct = lane >> 4, l16 = lane & 15;
  const short* aptr[2];
  #pragma unroll
  for(int fi=0; fi<2; fi++){
    int lr = wm*32 + fi*16 + l16;
    int grow = (lr < mbound) ? (gidx ? gidx[m0 + lr] : (m0 + lr)) : -1;
    aptr[fi] = (grow >= 0) ? (Abf + (size_t)grow*lda + oct*8) : nullptr;
  }
  const float* bptr[4];
  #pragma unroll
  for(int fj=0; fj<4; fj++)
    bptr[fj] = W0 + (size_t)(oct*8)*N + (n0 + wn*64 + fj*16 + l16);

  const bf16x8 zz = {0,0,0,0,0,0,0,0};
  bf16x8 av[2]; float bw[4][8];
  #pragma unroll
  for(int fi=0; fi<2; fi++) av[fi] = aptr[fi] ? *(const bf16x8*)(aptr[fi]) : zz;
  #pragma unroll
  for(int fj=0; fj<4; fj++)
    #pragma unroll
    for(int i=0;i<8;i++) bw[fj][i] = bptr[fj][(size_t)i*N];

  for(int k0=0; k0<K; k0+=BK){
    bf16x8 af[2]; af[0]=av[0]; af[1]=av[1];
    bf16x8 bfr[4];
    #pragma unroll
    for(int fj=0; fj<4; fj++)
      #pragma unroll
      for(int i=0;i<8;i++) bfr[fj][i] = (short)f2bf(bw[fj][i]);
    if(k0+BK < K){
      int kn = k0 + BK;
      #pragma unroll
      for(int fi=0; fi<2; fi++) av[fi] = aptr[fi] ? *(const bf16x8*)(aptr[fi] + kn) : zz;
      #pragma unroll
      for(int fj=0; fj<4; fj++)
        #pragma unroll
        for(int i=0;i<8;i++) bw[fj][i] = bptr[fj][(size_t)(kn + i)*N];
    }
    #pragma unroll
    for(int fi=0; fi<2; fi++)
      #pragma unroll
      for(int fj=0; fj<4; fj++)
        acc[fi][fj] = __builtin_amdgcn_mfma_f32_16x16x32_bf16(af[fi], bfr[fj], acc[fi][fj], 0, 0, 0);
  }
}

// ===== barrier-free split-bf16 ("bf16x3") tile loop: A pre-split hi/lo, W split on the fly =====
__device__ __forceinline__ void mm_tile3b(
    const short* __restrict__ Ahi, const short* __restrict__ Alo, int lda, int m0, int acol,
    const float* __restrict__ W0, int N, int K, int n0,
    f32x4 acc[2][4])
{
  int lane = threadIdx.x & 63, wv = threadIdx.x >> 6;
  int wm = wv & 1, wn = wv >> 1;
  int oct = lane >> 4, l16 = lane & 15;
  size_t aoffs[2];
  #pragma unroll
  for(int fi=0; fi<2; fi++){
    int lr = wm*32 + fi*16 + l16;
    aoffs[fi] = (size_t)(m0 + lr)*lda + acol + oct*8;
  }
  const float* bptr[4];
  #pragma unroll
  for(int fj=0; fj<4; fj++)
    bptr[fj] = W0 + (size_t)(oct*8)*N + (n0 + wn*64 + fj*16 + l16);

  bf16x8 avH[2], avL[2]; float bw[4][8];
  #pragma unroll
  for(int fi=0; fi<2; fi++){
    avH[fi] = *(const bf16x8*)(Ahi + aoffs[fi]);
    avL[fi] = *(const bf16x8*)(Alo + aoffs[fi]);
  }
  #pragma unroll
  for(int fj=0; fj<4; fj++)
    #pragma unroll
    for(int i=0;i<8;i++) bw[fj][i] = bptr[fj][(size_t)i*N];

  for(int k0=0; k0<K; k0+=BK){
    bf16x8 ah[2], al[2];
    #pragma unroll
    for(int fi=0; fi<2; fi++){ ah[fi]=avH[fi]; al[fi]=avL[fi]; }
    bf16x8 bh[4], bl[4];
    #pragma unroll
    for(int fj=0; fj<4; fj++)
      #pragma unroll
      for(int i=0;i<8;i++){
        unsigned p = fsplit2(bw[fj][i]);
        bh[fj][i] = (short)(p & 0xffff);
        bl[fj][i] = (short)(p >> 16);
      }
    if(k0+BK < K){
      int kn = k0 + BK;
      #pragma unroll
      for(int fi=0; fi<2; fi++){
        avH[fi] = *(const bf16x8*)(Ahi + aoffs[fi] + kn);
        avL[fi] = *(const bf16x8*)(Alo + aoffs[fi] + kn);
      }
      #pragma unroll
      for(int fj=0; fj<4; fj++)
        #pragma unroll
        for(int i=0;i<8;i++) bw[fj][i] = bptr[fj][(size_t)(kn + i)*N];
    }
    #pragma unroll
    for(int fi=0; fi<2; fi++)
      #pragma unroll
      for(int fj=0; fj<4; fj++){
        acc[fi][fj] = __builtin_amdgcn_mfma_f32_16x16x32_bf16(ah[fi], bh[fj], acc[fi][fj], 0, 0, 0);
        acc[fi][fj] = __builtin_amdgcn_mfma_f32_16x16x32_bf16(ah[fi], bl[fj], acc[fi][fj], 0, 0, 0);
        acc[fi][fj] = __builtin_amdgcn_mfma_f32_16x16x32_bf16(al[fi], bh[fj], acc[fi][fj], 0, 0, 0);
      }
  }
}

// ================= x -> hi/lo bf16 pre-split =================
__global__ __launch_bounds__(256) void k_split_x(const float* __restrict__ in,
    short* __restrict__ hi, short* __restrict__ lo, int n4){
  int i = blockIdx.x*256 + threadIdx.x;
  if(i < n4){
    float4 v = ((const float4*)in)[i];
    unsigned p0 = fsplit2(v.x), p1 = fsplit2(v.y), p2 = fsplit2(v.z), p3 = fsplit2(v.w);
    short4 h, l;
    h.x=(short)(p0&0xffff); l.x=(short)(p0>>16);
    h.y=(short)(p1&0xffff); l.y=(short)(p1>>16);
    h.z=(short)(p2&0xffff); l.z=(short)(p2>>16);
    h.w=(short)(p3&0xffff); l.w=(short)(p3>>16);
    ((short4*)hi)[i] = h;
    ((short4*)lo)[i] = l;
  }
}

// ================= fused QKV (common + unique), split precision, f32 out =================
struct PtrArr6 { const float* w[6]; const float* b[6]; };

__global__ __launch_bounds__(256) void mm3_qkv(const short* __restrict__ x_hi,
    const short* __restrict__ x_lo, PtrArr6 pa,
    const int* __restrict__ routeb, float* __restrict__ qkvout)
{
  int n0 = blockIdx.x*BN, m0 = blockIdx.y*BM, z = blockIdx.z;
  int bidx = m0 >> 7;
  const float* W = pa.w[z]; const float* bias = pa.b[z];
  if(z >= 3){ int e = routeb[bidx]; W += (size_t)e*Dm*Dm; bias += (size_t)e*Dm; }
  f32x4 acc[2][4] = {};
  mm_tile3b(x_hi, x_lo, Dm, m0, 0, W, Dm, Dm, n0, acc);
  float* outp = qkvout + (size_t)z*NT*Dm;
  int lane = threadIdx.x&63, wv = threadIdx.x>>6, wm = wv&1, wn = wv>>1;
  #pragma unroll
  for(int fi=0; fi<2; fi++)
    #pragma unroll
    for(int fj=0; fj<4; fj++)
      #pragma unroll
      for(int r=0; r<4; r++){
        int row = m0 + wm*32 + fi*16 + ((lane>>4)<<2) + r;
        int col = n0 + wn*64 + fj*16 + (lane&15);
        outp[(size_t)row*Dm + col] = acc[fi][fj][r] + bias[col];
      }
}

// ================= output projection, split-K via z (kc=0 common, kc=1 unique) =================
__global__ __launch_bounds__(256) void mm3_outproj(const short* __restrict__ ctx_hi,
    const short* __restrict__ ctx_lo,
    const float* __restrict__ ca_wo, const float* __restrict__ ua_wo,
    const float* __restrict__ ca_bo, const float* __restrict__ ua_bo,
    const int* __restrict__ routeb, const float* __restrict__ pmaxb,
    float* __restrict__ att2)
{
  int n0 = blockIdx.x*BN, m0 = blockIdx.y*BM, kc = blockIdx.z;
  int bidx = m0 >> 7;
  int e = routeb[bidx];
  const float* W    = kc ? (ua_wo + (size_t)e*Dm*Dm) : ca_wo;
  const float* bias = kc ? (ua_bo + (size_t)e*Dm)    : ca_bo;
  float bscale = kc ? pmaxb[bidx] : 1.0f;
  f32x4 acc[2][4] = {};
  mm_tile3b(ctx_hi, ctx_lo, 1536, m0, kc*Dm, W, Dm, Dm, n0, acc);
  float* outp = att2 + (size_t)kc*NT*Dm;
  int lane = threadIdx.x&63, wv = threadIdx.x>>6, wm = wv&1, wn = wv>>1;
  #pragma unroll
  for(int fi=0; fi<2; fi++)
    #pragma unroll
    for(int fj=0; fj<4; fj++)
      #pragma unroll
      for(int r=0; r<4; r++){
        int row = m0 + wm*32 + fi*16 + ((lane>>4)<<2) + r;
        int col = n0 + wn*64 + fj*16 + (lane&15);
        outp[(size_t)row*Dm + col] = acc[fi][fj][r] + bscale*bias[col];
      }
}

// ================= att = att2[0] + att2[1]; also emit bf16 =================
__global__ __launch_bounds__(256) void k_att_sum(const float* __restrict__ att2,
    float* __restrict__ att, short* __restrict__ attbf, int n4){
  int i = blockIdx.x*256 + threadIdx.x;
  if(i < n4){
    const size_t P4 = (size_t)NT*Dm/4;
    float4 a = ((const float4*)att2)[i];
    float4 b = ((const float4*)att2)[P4 + i];
    float4 v; v.x=a.x+b.x; v.y=a.y+b.y; v.z=a.z+b.z; v.w=a.w+b.w;
    ((float4*)att)[i] = v;
    short4 o;
    o.x=(short)f2bf(v.x); o.y=(short)f2bf(v.y); o.z=(short)f2bf(v.z); o.w=(short)f2bf(v.w);
    ((short4*)attbf)[i] = o;
  }
}

// ================= F-stage: common FFN1 (y<32) + grouped Switch-FFN1 (tile list) =================
__global__ __launch_bounds__(256) void mm_fstage(const short* __restrict__ attbf,
    const float* __restrict__ cf_w1, const float* __restrict__ cf_b1,
    const float* __restrict__ uf_w1, const float* __restrict__ uf_b1,
    const int* __restrict__ idxl, const int* __restrict__ gbase, const int* __restrict__ gcnt,
    const int* __restrict__ tlist, const int* __restrict__ ntl,
    short* __restrict__ h, short* __restrict__ hg)
{
  int n0 = blockIdx.x*BN, y = blockIdx.y;
  int lane = threadIdx.x&63, wv = threadIdx.x>>6, wm = wv&1, wn = wv>>1;
  f32x4 acc[2][4] = {};
  if(y < 32){
    int m0 = y*BM;
    mm_tile(attbf, Dm, nullptr, m0, BM, cf_w1, Fm, Dm, n0, acc);
    #pragma unroll
    for(int fi=0; fi<2; fi++)
      #pragma unroll
      for(int fj=0; fj<4; fj++)
        #pragma unroll
        for(int r=0; r<4; r++){
          int row = m0 + wm*32 + fi*16 + ((lane>>4)<<2) + r;
          int col = n0 + wn*64 + fj*16 + (lane&15);
          h[(size_t)row*Fm + col] = (short)f2bf(gelu_f(acc[fi][fj][r] + cf_b1[col]));
        }
  } else {
    int i = y - 32;
    if(i >= ntl[0]) return;
    int v = tlist[i], g = v>>8, t = v&255;
    int cnt = gcnt[g], r0 = t*BM, pos0 = gbase[g] + r0;
    mm_tile(attbf, Dm, idxl, pos0, cnt - r0, uf_w1 + (size_t)g*Dm*Fm, Fm, Dm, n0, acc);
    const float* bias = uf_b1 + (size_t)g*Fm;
    #pragma unroll
    for(int fi=0; fi<2; fi++)
      #pragma unroll
      for(int fj=0; fj<4; fj++)
        #pragma unroll
        for(int r=0; r<4; r++){
          int lr = wm*32 + fi*16 + ((lane>>4)<<2) + r;
          if(r0 + lr >= cnt) continue;
          int col = n0 + wn*64 + fj*16 + (lane&15);
          hg[(size_t)(pos0+lr)*Fm + col] = (short)f2bf(gelu_f(acc[fi][fj][r] + bias[col]));
        }
  }
}

// ================= D-stage: split-K (z=kc of 4), bf16 partials =================
__global__ __launch_bounds__(256) void mm_dstage(const short* __restrict__ h,
    const short* __restrict__ hg,
    const float* __restrict__ cf_w2, const float* __restrict__ cf_b2,
    const float* __restrict__ uf_w2, const float* __restrict__ uf_b2,
    const int* __restrict__ idxl, const int* __restrict__ gbase, const int* __restrict__ gcnt,
    const int* __restrict__ tlist, const int* __restrict__ ntl,
    const float* __restrict__ tokp, short* __restrict__ ycf4, short* __restrict__ yuo4)
{
  const int KC = Fm/4;   // 768
  int n0 = blockIdx.x*BN, y = blockIdx.y, kc = blockIdx.z;
  int lane = threadIdx.x&63, wv = threadIdx.x>>6, wm = wv&1, wn = wv>>1;
  f32x4 acc[2][4] = {};
  if(y < 32){
    int m0 = y*BM;
    mm_tile(h + kc*KC, Fm, nullptr, m0, BM, cf_w2 + (size_t)kc*KC*Dm, Dm, KC, n0, acc);
    short* outp = ycf4 + (size_t)kc*NT*Dm;
    #pragma unroll
    for(int fi=0; fi<2; fi++)
      #pragma unroll
      for(int fj=0; fj<4; fj++)
        #pragma unroll
        for(int r=0; r<4; r++){
          int row = m0 + wm*32 + fi*16 + ((lane>>4)<<2) + r;
          int col = n0 + wn*64 + fj*16 + (lane&15);
          outp[(size_t)row*Dm + col] = (short)f2bf(acc[fi][fj][r] + (kc==0 ? cf_b2[col] : 0.f));
        }
  } else {
    int i = y - 32;
    if(i >= ntl[0]) return;
    int v = tlist[i], g = v>>8, t = v&255;
    int cnt = gcnt[g], r0 = t*BM, pos0 = gbase[g] + r0;
    mm_tile(hg + kc*KC, Fm, nullptr, pos0, cnt - r0,
            uf_w2 + (size_t)g*Fm*Dm + (size_t)kc*KC*Dm, Dm, KC, n0, acc);
    const float* bias = uf_b2 + (size_t)g*Dm;
    short* outp = yuo4 + (size_t)kc*NT*Dm;
    #pragma unroll
    for(int fi=0; fi<2; fi++)
      #pragma unroll
      for(int fj=0; fj<4; fj++)
        #pragma unroll
        for(int r=0; r<4; r++){
          int lr = wm*32 + fi*16 + ((lane>>4)<<2) + r;
          int rm = (r0 + lr < cnt) ? idxl[pos0 + lr] : -1;
          if(rm < 0) continue;
          int col = n0 + wn*64 + fj*16 + (lane&15);
          float vv = acc[fi][fj][r] + (kc==0 ? bias[col] : 0.f);
          outp[(size_t)rm*Dm + col] = (short)f2bf(vv * tokp[rm]);
        }
  }
}

// ================= batch-level routing =================
__global__ __launch_bounds__(256) void k_route_batch(const float* __restrict__ xf,
    const float* __restrict__ sw_w, const float* __restrict__ sw_b,
    float* __restrict__ pmax_b, int* __restrict__ route_b){
  int b = blockIdx.x, tid = threadIdx.x;
  __shared__ float xm[Dm];
  for(int d=tid; d<Dm; d+=256){
    float s=0.f;
    const float* xp = xf + ((size_t)b*Sm)*Dm + d;
    for(int ss=0; ss<Sm; ss++) s += xp[(size_t)ss*Dm];
    xm[d] = s*(1.0f/Sm);
  }
  __syncthreads();
  float a0=0,a1=0,a2=0,a3=0;
  for(int d=tid; d<Dm; d+=256){
    float xv = xm[d];
    a0 += xv*sw_w[d*4+0]; a1 += xv*sw_w[d*4+1];
    a2 += xv*sw_w[d*4+2]; a3 += xv*sw_w[d*4+3];
  }
  __shared__ float red[4][256];
  red[0][tid]=a0; red[1][tid]=a1; red[2][tid]=a2; red[3][tid]=a3;
  for(int off=128; off>0; off>>=1){
    __syncthreads();
    if(tid<off){ for(int u=0;u<4;u++) red[u][tid]+=red[u][tid+off]; }
  }
  __syncthreads();
  if(tid==0){
    float l[4]; for(int u=0;u<4;u++) l[u]=red[u][0]+sw_b[u];
    float m=l[0]; int arg=0;
    for(int u=1;u<4;u++) if(l[u]>m){ m=l[u]; arg=u; }
    float s=0; for(int u=0;u<4;u++) s+=expf(l[u]-m);
    pmax_b[b]=1.0f/s;
    route_b[b]=arg;
  }
}

// ====== attention v2: reg-resident scores, wave-local softmax, conflict-free LDS ======
// thread (ql, quarter): keys ki = quarter + 4*t (t=0..31); kv padded [128][68] (16B-aligned rows,
// quarter lanes hit banks {0,4,8,12} -> conflict-free float4 reads; ql lanes broadcast).
__global__ __launch_bounds__(256) void k_attn_f(const float* __restrict__ qkv,
    const float* __restrict__ mask, const float* __restrict__ pmaxb,
    short* __restrict__ ctx_hi, short* __restrict__ ctx_lo)
{
  int h = blockIdx.x, b = blockIdx.y, z = blockIdx.z;
  int qh = z & 1, kind = z >> 1;
  const float* Q  = qkv + (size_t)(kind*3+0)*NT*Dm;
  const float* Kp = qkv + (size_t)(kind*3+1)*NT*Dm;
  const float* Vp = qkv + (size_t)(kind*3+2)*NT*Dm;
  int tid = threadIdx.x;
  __shared__ float kv[128][68];
  size_t base = ((size_t)b*Sm)*Dm + h*DHm;
  // load K (float4, coalesced)
  for(int l=tid; l<2048; l+=256){
    int s=l>>4, d4=(l&15)*4;
    *(float4*)&kv[s][d4] = *(const float4*)(Kp + base + (size_t)s*Dm + d4);
  }
  int ql = tid>>2, quarter = tid&3;
  int qi = qh*64 + ql;
  float4 q4[16];
  const float* qp = Q + base + (size_t)qi*Dm;
  #pragma unroll
  for(int j=0;j<16;j++) q4[j] = *(const float4*)(qp + j*4);
  __syncthreads();
  // scores for my 32 keys
  float sc[32];
  #pragma unroll 4
  for(int t=0;t<32;t++){
    int ki = quarter + 4*t;
    float s=0.f;
    #pragma unroll
    for(int j=0;j<16;j++){
      float4 k4 = *(float4*)&kv[ki][j*4];
      s += q4[j].x*k4.x + q4[j].y*k4.y + q4[j].z*k4.z + q4[j].w*k4.w;
    }
    sc[t] = s*0.125f + mask[b*Sm+ki];
  }
  // row softmax across the 4 quarter-lanes
  float m = sc[0];
  #pragma unroll
  for(int t=1;t<32;t++) m = fmaxf(m, sc[t]);
  m = fmaxf(m, __shfl_xor(m,1));
  m = fmaxf(m, __shfl_xor(m,2));
  float sum = 0.f;
  #pragma unroll
  for(int t=0;t<32;t++){ sc[t] = expf(sc[t]-m); sum += sc[t]; }
  sum += __shfl_xor(sum,1);
  sum += __shfl_xor(sum,2);
  float inv = 1.0f/sum;
  #pragma unroll
  for(int t=0;t<32;t++) sc[t] *= inv;
  __syncthreads();
  // load V
  for(int l=tid; l<2048; l+=256){
    int s=l>>4, d4=(l&15)*4;
    *(float4*)&kv[s][d4] = *(const float4*)(Vp + base + (size_t)s*Dm + d4);
  }
  __syncthreads();
  // PV partial over my 32 keys, all 64 d
  float4 part[16];
  #pragma unroll
  for(int j=0;j<16;j++){ part[j].x=0; part[j].y=0; part[j].z=0; part[j].w=0; }
  #pragma unroll 4
  for(int t=0;t<32;t++){
    int ki = quarter + 4*t;
    float p = sc[t];
    #pragma unroll
    for(int j=0;j<16;j++){
      float4 v4 = *(float4*)&kv[ki][j*4];
      part[j].x += p*v4.x; part[j].y += p*v4.y; part[j].z += p*v4.z; part[j].w += p*v4.w;
    }
  }
  // reduce across quarter-lanes (butterfly); all lanes get full sums
  #pragma unroll
  for(int j=0;j<16;j++){
    part[j].x += __shfl_xor(part[j].x,1); part[j].x += __shfl_xor(part[j].x,2);
    part[j].y += __shfl_xor(part[j].y,1); part[j].y += __shfl_xor(part[j].y,2);
    part[j].z += __shfl_xor(part[j].z,1); part[j].z += __shfl_xor(part[j].z,2);
    part[j].w += __shfl_xor(part[j].w,1); part[j].w += __shfl_xor(part[j].w,2);
  }
  float sck = kind ? pmaxb[b] : 1.0f;
  size_t obase = ((size_t)b*Sm + qi)*1536 + kind*Dm + h*DHm;
  #pragma unroll
  for(int jj=0;jj<4;jj++){
    int j = quarter*4 + jj;
    float4 v = part[j];
    v.x *= sck; v.y *= sck; v.z *= sck; v.w *= sck;
    short4 hh, ll;
    unsigned short t0;
    t0=f2bf(v.x); hh.x=(short)t0; ll.x=(short)f2bf(v.x-bf2f(t0));
    t0=f2bf(v.y); hh.y=(short)t0; ll.y=(short)f2bf(v.y-bf2f(t0));
    t0=f2bf(v.z); hh.z=(short)t0; ll.z=(short)f2bf(v.z-bf2f(t0));
    t0=f2bf(v.w); hh.w=(short)t0; ll.w=(short)f2bf(v.w-bf2f(t0));
    *(short4*)(ctx_hi + obase + j*4) = hh;
    *(short4*)(ctx_lo + obase + j*4) = ll;
  }
}

// ================= token-level Switch routing =================
__global__ __launch_bounds__(256) void k_tok_route(const float* __restrict__ att,
    const float* __restrict__ ur_w, const float* __restrict__ ur_b,
    const int* __restrict__ route_b, float* __restrict__ tok_pmax,
    int* __restrict__ tok_e, int* __restrict__ grp_count)
{
  int n = blockIdx.x, tid = threadIdx.x;
  int i = route_b[n>>7];
  const float* w = ur_w + (size_t)i*Dm*4;
  const float* ap = att + (size_t)n*Dm;
  float a0=0,a1=0,a2=0,a3=0;
  for(int d=tid; d<Dm; d+=256){
    float a = ap[d];
    a0 += a*w[d*4+0]; a1 += a*w[d*4+1];
    a2 += a*w[d*4+2]; a3 += a*w[d*4+3];
  }
  __shared__ float red[4][256];
  red[0][tid]=a0; red[1][tid]=a1; red[2][tid]=a2; red[3][tid]=a3;
  for(int off=128; off>0; off>>=1){
    __syncthreads();
    if(tid<off){ for(int u=0;u<4;u++) red[u][tid]+=red[u][tid+off]; }
  }
  __syncthreads();
  if(tid==0){
    float l[4]; for(int u=0;u<4;u++) l[u]=red[u][0]+ur_b[i*4+u];
    float m=l[0]; int arg=0;
    for(int u=1;u<4;u++) if(l[u]>m){ m=l[u]; arg=u; }
    float s=0; for(int u=0;u<4;u++) s+=expf(l[u]-m);
    tok_pmax[n] = 1.0f/s;
    tok_e[n] = arg;
    atomicAdd(&grp_count[i*4+arg], 1);
  }
}

// ================= prefix + tile worklist =================
__global__ void k_prefix(const int* __restrict__ cnt, int* __restrict__ base,
                         int* __restrict__ cur, int* __restrict__ tlist, int* __restrict__ ntl){
  if(threadIdx.x==0 && blockIdx.x==0){
    int s=0, nt=0;
    for(int g=0; g<16; g++){
      base[g]=s; cur[g]=s;
      int tg = (cnt[g] + BM - 1)/BM;
      for(int t=0; t<tg; t++){ if(nt<64) tlist[nt++] = (g<<8)|t; }
      s += cnt[g];
    }
    ntl[0] = nt;
  }
}

__global__ void k_scatter(const int* __restrict__ route_b, const int* __restrict__ tok_e,
                          int* __restrict__ cur, int* __restrict__ idxl){
  int n = blockIdx.x*256 + threadIdx.x;
  if(n < NT){
    int g = route_b[n>>7]*4 + tok_e[n];
    int pos = atomicAdd(&cur[g], 1);
    idxl[pos] = n;
  }
}

// ======= final residual add + LayerNorm (sums 4+4 bf16 split-K partials) =======
__global__ __launch_bounds__(256) void k_final_ln(const float* __restrict__ att,
    const short* __restrict__ ycf4, const short* __restrict__ yuo4,
    const float* __restrict__ ln_g, const float* __restrict__ ln_b, float* __restrict__ out)
{
  int n = blockIdx.x, tid = threadIdx.x;
  __shared__ float yb[Dm];
  __shared__ float red[256];
  size_t base = (size_t)n*Dm;
  const size_t P = (size_t)NT*Dm;
  float ps = 0.f;
  for(int d=tid; d<Dm; d+=256){
    float v = att[base+d];
    #pragma unroll
    for(int c=0; c<4; c++){
      v += bf2f((unsigned short)ycf4[c*P + base + d]);
      v += bf2f((unsigned short)yuo4[c*P + base + d]);
    }
    yb[d]=v; ps+=v;
  }
  red[tid]=ps;
  for(int off=128; off>0; off>>=1){ __syncthreads(); if(tid<off) red[tid]+=red[tid+off]; }
  __syncthreads();
  float mu = red[0]*(1.0f/Dm);
  __syncthreads();
  float pv = 0.f;
  for(int d=tid; d<Dm; d+=256){ float t = yb[d]-mu; pv += t*t; }
  red[tid]=pv;
  for(int off=128; off>0; off>>=1){ __syncthreads(); if(tid<off) red[tid]+=red[tid+off]; }
  __syncthreads();
  float var = red[0]*(1.0f/Dm);
  float rstd = rsqrtf(var + 1e-12f);
  for(int d=tid; d<Dm; d+=256){
    out[base+d] = (yb[d]-mu)*rstd*ln_g[d] + ln_b[d];
  }
}

extern "C" void kernel_launch(void* const* d_in, const int* in_sizes, int n_in,
                              void* d_out, int out_size, void* d_ws, size_t ws_size,
                              hipStream_t stream)
{
  const float* x     =(const float*)d_in[0];
  const float* mask  =(const float*)d_in[1];
  const float* sw_w  =(const float*)d_in[2];
  const float* sw_b  =(const float*)d_in[3];
  const float* ca_wq =(const float*)d_in[4];
  const float* ca_bq =(const float*)d_in[5];
  const float* ca_wk =(const float*)d_in[6];
  const float* ca_bk =(const float*)d_in[7];
  const float* ca_wv =(const float*)d_in[8];
  const float* ca_bv =(const float*)d_in[9];
  const float* ca_wo =(const float*)d_in[10];
  const float* ca_bo =(const float*)d_in[11];
  const float* ua_wq =(const float*)d_in[12];
  const float* ua_bq =(const float*)d_in[13];
  const float* ua_wk =(const float*)d_in[14];
  const float* ua_bk =(const float*)d_in[15];
  const float* ua_wv =(const float*)d_in[16];
  const float* ua_bv =(const float*)d_in[17];
  const float* ua_wo =(const float*)d_in[18];
  const float* ua_bo =(const float*)d_in[19];
  const float* cf_w1 =(const float*)d_in[20];
  const float* cf_b1 =(const float*)d_in[21];
  const float* cf_w2 =(const float*)d_in[22];
  const float* cf_b2 =(const float*)d_in[23];
  const float* ur_w  =(const float*)d_in[24];
  const float* ur_b  =(const float*)d_in[25];
  const float* uf_w1 =(const float*)d_in[26];
  const float* uf_b1 =(const float*)d_in[27];
  const float* uf_w2 =(const float*)d_in[28];
  const float* uf_b2 =(const float*)d_in[29];
  const float* ln_g  =(const float*)d_in[30];
  const float* ln_b  =(const float*)d_in[31];

  // ---- workspace: region of 8 units (1 unit = NT*Dm f32 = 6.29MB), phase-aliased ----
  float* region = (float*)d_ws;
  float* qkv    = region;
  short* ctx_hi = (short*)(region + (size_t)6*NT*Dm);
  short* ctx_lo = (short*)(region + (size_t)7*NT*Dm);
  float* att2   = region;
  short* h_bf   = (short*)region;
  short* hg_bf  = (short*)region + (size_t)NT*Fm;
  short* ycf4   = (short*)(region + (size_t)4*NT*Dm);
  short* yuo4   = (short*)(region + (size_t)6*NT*Dm);
  float* fp     = region + (size_t)8*NT*Dm;
  short* x_hi   = (short*)fp;                 // alive only during mm3_qkv
  short* x_lo   = x_hi + (size_t)NT*Dm;
  float* att    = fp; fp += (size_t)NT*Dm;    // written by k_att_sum (x_hi/lo dead)
  float* tokp   = fp; fp += NT;
  float* pmaxb  = fp; fp += 16;
  short* att_bf = (short*)fp;
  int*   ip     = (int*)(att_bf + (size_t)NT*Dm);
  int* routeb = ip; ip += 16;
  int* toke   = ip; ip += NT;
  int* gcnt   = ip; ip += 16;
  int* gbase  = ip; ip += 16;
  int* gcur   = ip; ip += 16;
  int* idxl   = ip; ip += NT;
  int* tlist  = ip; ip += 64;
  int* ntl    = ip; ip += 1;
  size_t need = (size_t)((char*)ip - (char*)d_ws);
  if(need > ws_size) return;   // bail visibly (output stays 0)

  (void)hipMemsetAsync(gcnt, 0, 16*sizeof(int), stream);

  k_route_batch<<<16, 256, 0, stream>>>(x, sw_w, sw_b, pmaxb, routeb);
  k_split_x<<<(NT*Dm/4 + 255)/256, 256, 0, stream>>>(x, x_hi, x_lo, NT*Dm/4);

  PtrArr6 pa;
  pa.w[0]=ca_wq; pa.w[1]=ca_wk; pa.w[2]=ca_wv; pa.w[3]=ua_wq; pa.w[4]=ua_wk; pa.w[5]=ua_wv;
  pa.b[0]=ca_bq; pa.b[1]=ca_bk; pa.b[2]=ca_bv; pa.b[3]=ua_bq; pa.b[4]=ua_bk; pa.b[5]=ua_bv;
  mm3_qkv<<<dim3(Dm/BN, NT/BM, 6), 256, 0, stream>>>(x_hi, x_lo, pa, routeb, qkv);

  // attention v2 (f32 -> ctx hi/lo bf16): z = qh + 2*kind
  k_attn_f<<<dim3(Hm, Bm, 4), 256, 0, stream>>>(qkv, mask, pmaxb, ctx_hi, ctx_lo);

  // output projection, split-K=2 (z): partials into dead qkv units
  mm3_outproj<<<dim3(Dm/BN, NT/BM, 2), 256, 0, stream>>>(ctx_hi, ctx_lo, ca_wo, ua_wo,
                                                         ca_bo, ua_bo, routeb, pmaxb, att2);
  k_att_sum<<<(NT*Dm/4 + 255)/256, 256, 0, stream>>>(att2, att, att_bf, NT*Dm/4);

  // token routing + grouping (from f32 att -> flip-safe)
  k_tok_route<<<NT, 256, 0, stream>>>(att, ur_w, ur_b, routeb, tokp, toke, gcnt);
  k_prefix<<<1, 64, 0, stream>>>(gcnt, gbase, gcur, tlist, ntl);
  k_scatter<<<NT/256, 256, 0, stream>>>(routeb, toke, gcur, idxl);

  // F-stage: common FFN1 + grouped Switch-FFN1 in one dispatch
  mm_fstage<<<dim3(Fm/BN, 32+48), 256, 0, stream>>>(att_bf, cf_w1, cf_b1, uf_w1, uf_b1,
                                                    idxl, gbase, gcnt, tlist, ntl, h_bf, hg_bf);

  // D-stage: split-K=4, bf16 partial buffers
  mm_dstage<<<dim3(Dm/BN, 32+48, 4), 256, 0, stream>>>(h_bf, hg_bf, cf_w2, cf_b2, uf_w2, uf_b2,
                                                       idxl, gbase, gcnt, tlist, ntl, tokp,
                                                       ycf4, yuo4);

  k_final_ln<<<NT, 256, 0, stream>>>(att, ycf4, yuo4, ln_g, ln_b, (float*)d_out);
}

// Round 11
// 569.296 us; speedup vs baseline: 5.9211x; 1.0588x over previous
//
#include <hip/hip_runtime.h>

#define NT 2048
#define Dm 768
#define Fm 3072
#define Bm 16
#define Sm 128
#define Hm 12
#define DHm 64

#define BM 64
#define BM2 128
#define BN 128
#define BK 32

typedef __attribute__((ext_vector_type(8))) short bf16x8;
typedef __attribute__((ext_vector_type(4))) float f32x4;

__device__ __forceinline__ unsigned short f2bf(float f){
  unsigned u = __float_as_uint(f);
  unsigned r = (u + 0x7fffu + ((u>>16)&1u)) >> 16;   // round-nearest-even
  return (unsigned short)r;
}
__device__ __forceinline__ float bf2f(unsigned short h){ return __uint_as_float(((unsigned)h)<<16); }
// split f32 into hi/lo bf16 pair, packed: hi = bits[15:0], lo = bits[31:16]
__device__ __forceinline__ unsigned fsplit2(float x){
  unsigned short h = f2bf(x);
  unsigned short l = f2bf(x - bf2f(h));
  return (unsigned)h | ((unsigned)l << 16);
}
__device__ __forceinline__ float gelu_f(float x){
  return 0.5f*x*(1.0f + erff(x*0.70710678118654752f));
}

// ========== barrier-free reg-direct bf16 tile loop, BM2=128 (4 m-frags/wave) ==========
// 16 MFMA per K-step per wave; B converts via v_cvt_pk_bf16_f32 (hardware RNE).
__device__ __forceinline__ void mm_tile2(
    const short* __restrict__ Abf, int lda,
    const int* __restrict__ gidx, int m0, int mbound,
    const float* __restrict__ W0, int N, int K, int n0,
    f32x4 acc[4][4])
{
  int lane = threadIdx.x & 63, wv = threadIdx.x >> 6;
  int wm = wv & 1, wn = wv >> 1;
  int oct = lane >> 4, l16 = lane & 15;
  const short* aptr[4];
  #pragma unroll
  for(int fi=0; fi<4; fi++){
    int lr = wm*64 + fi*16 + l16;
    int grow = (lr < mbound) ? (gidx ? gidx[m0 + lr] : (m0 + lr)) : -1;
    aptr[fi] = (grow >= 0) ? (Abf + (size_t)grow*lda + oct*8) : nullptr;
  }
  const float* bptr[4];
  #pragma unroll
  for(int fj=0; fj<4; fj++)
    bptr[fj] = W0 + (size_t)(oct*8)*N + (n0 + wn*64 + fj*16 + l16);

  const bf16x8 zz = {0,0,0,0,0,0,0,0};
  bf16x8 av[4]; float bw[4][8];
  #pragma unroll
  for(int fi=0; fi<4; fi++) av[fi] = aptr[fi] ? *(const bf16x8*)(aptr[fi]) : zz;
  #pragma unroll
  for(int fj=0; fj<4; fj++)
    #pragma unroll
    for(int i=0;i<8;i++) bw[fj][i] = bptr[fj][(size_t)i*N];

  for(int k0=0; k0<K; k0+=BK){
    bf16x8 af[4];
    #pragma unroll
    for(int fi=0; fi<4; fi++) af[fi] = av[fi];
    bf16x8 bfr[4];
    #pragma unroll
    for(int fj=0; fj<4; fj++){
      unsigned o0,o1,o2,o3;
      asm("v_cvt_pk_bf16_f32 %0, %1, %2" : "=v"(o0) : "v"(bw[fj][0]), "v"(bw[fj][1]));
      asm("v_cvt_pk_bf16_f32 %0, %1, %2" : "=v"(o1) : "v"(bw[fj][2]), "v"(bw[fj][3]));
      asm("v_cvt_pk_bf16_f32 %0, %1, %2" : "=v"(o2) : "v"(bw[fj][4]), "v"(bw[fj][5]));
      asm("v_cvt_pk_bf16_f32 %0, %1, %2" : "=v"(o3) : "v"(bw[fj][6]), "v"(bw[fj][7]));
      union{ bf16x8 v; unsigned u[4]; } r;
      r.u[0]=o0; r.u[1]=o1; r.u[2]=o2; r.u[3]=o3;
      bfr[fj] = r.v;
    }
    if(k0+BK < K){
      int kn = k0 + BK;
      #pragma unroll
      for(int fi=0; fi<4; fi++) av[fi] = aptr[fi] ? *(const bf16x8*)(aptr[fi] + kn) : zz;
      #pragma unroll
      for(int fj=0; fj<4; fj++)
        #pragma unroll
        for(int i=0;i<8;i++) bw[fj][i] = bptr[fj][(size_t)(kn + i)*N];
    }
    #pragma unroll
    for(int fi=0; fi<4; fi++)
      #pragma unroll
      for(int fj=0; fj<4; fj++)
        acc[fi][fj] = __builtin_amdgcn_mfma_f32_16x16x32_bf16(af[fi], bfr[fj], acc[fi][fj], 0, 0, 0);
  }
}

// ===== barrier-free split-bf16 ("bf16x3") tile loop: A pre-split hi/lo, W split on the fly =====
__device__ __forceinline__ void mm_tile3b(
    const short* __restrict__ Ahi, const short* __restrict__ Alo, int lda, int m0, int acol,
    const float* __restrict__ W0, int N, int K, int n0,
    f32x4 acc[2][4])
{
  int lane = threadIdx.x & 63, wv = threadIdx.x >> 6;
  int wm = wv & 1, wn = wv >> 1;
  int oct = lane >> 4, l16 = lane & 15;
  size_t aoffs[2];
  #pragma unroll
  for(int fi=0; fi<2; fi++){
    int lr = wm*32 + fi*16 + l16;
    aoffs[fi] = (size_t)(m0 + lr)*lda + acol + oct*8;
  }
  const float* bptr[4];
  #pragma unroll
  for(int fj=0; fj<4; fj++)
    bptr[fj] = W0 + (size_t)(oct*8)*N + (n0 + wn*64 + fj*16 + l16);

  bf16x8 avH[2], avL[2]; float bw[4][8];
  #pragma unroll
  for(int fi=0; fi<2; fi++){
    avH[fi] = *(const bf16x8*)(Ahi + aoffs[fi]);
    avL[fi] = *(const bf16x8*)(Alo + aoffs[fi]);
  }
  #pragma unroll
  for(int fj=0; fj<4; fj++)
    #pragma unroll
    for(int i=0;i<8;i++) bw[fj][i] = bptr[fj][(size_t)i*N];

  for(int k0=0; k0<K; k0+=BK){
    bf16x8 ah[2], al[2];
    #pragma unroll
    for(int fi=0; fi<2; fi++){ ah[fi]=avH[fi]; al[fi]=avL[fi]; }
    bf16x8 bh[4], bl[4];
    #pragma unroll
    for(int fj=0; fj<4; fj++)
      #pragma unroll
      for(int i=0;i<8;i++){
        unsigned p = fsplit2(bw[fj][i]);
        bh[fj][i] = (short)(p & 0xffff);
        bl[fj][i] = (short)(p >> 16);
      }
    if(k0+BK < K){
      int kn = k0 + BK;
      #pragma unroll
      for(int fi=0; fi<2; fi++){
        avH[fi] = *(const bf16x8*)(Ahi + aoffs[fi] + kn);
        avL[fi] = *(const bf16x8*)(Alo + aoffs[fi] + kn);
      }
      #pragma unroll
      for(int fj=0; fj<4; fj++)
        #pragma unroll
        for(int i=0;i<8;i++) bw[fj][i] = bptr[fj][(size_t)(kn + i)*N];
    }
    #pragma unroll
    for(int fi=0; fi<2; fi++)
      #pragma unroll
      for(int fj=0; fj<4; fj++){
        acc[fi][fj] = __builtin_amdgcn_mfma_f32_16x16x32_bf16(ah[fi], bh[fj], acc[fi][fj], 0, 0, 0);
        acc[fi][fj] = __builtin_amdgcn_mfma_f32_16x16x32_bf16(ah[fi], bl[fj], acc[fi][fj], 0, 0, 0);
        acc[fi][fj] = __builtin_amdgcn_mfma_f32_16x16x32_bf16(al[fi], bh[fj], acc[fi][fj], 0, 0, 0);
      }
  }
}

// ================= x -> hi/lo bf16 pre-split =================
__global__ __launch_bounds__(256) void k_split_x(const float* __restrict__ in,
    short* __restrict__ hi, short* __restrict__ lo, int n4){
  int i = blockIdx.x*256 + threadIdx.x;
  if(i < n4){
    float4 v = ((const float4*)in)[i];
    unsigned p0 = fsplit2(v.x), p1 = fsplit2(v.y), p2 = fsplit2(v.z), p3 = fsplit2(v.w);
    short4 h, l;
    h.x=(short)(p0&0xffff); l.x=(short)(p0>>16);
    h.y=(short)(p1&0xffff); l.y=(short)(p1>>16);
    h.z=(short)(p2&0xffff); l.z=(short)(p2>>16);
    h.w=(short)(p3&0xffff); l.w=(short)(p3>>16);
    ((short4*)hi)[i] = h;
    ((short4*)lo)[i] = l;
  }
}

// ================= fused QKV (common + unique), split precision, f32 out =================
struct PtrArr6 { const float* w[6]; const float* b[6]; };

__global__ __launch_bounds__(256) void mm3_qkv(const short* __restrict__ x_hi,
    const short* __restrict__ x_lo, PtrArr6 pa,
    const int* __restrict__ routeb, float* __restrict__ qkvout)
{
  int n0 = blockIdx.x*BN, m0 = blockIdx.y*BM, z = blockIdx.z;
  int bidx = m0 >> 7;
  const float* W = pa.w[z]; const float* bias = pa.b[z];
  if(z >= 3){ int e = routeb[bidx]; W += (size_t)e*Dm*Dm; bias += (size_t)e*Dm; }
  f32x4 acc[2][4] = {};
  mm_tile3b(x_hi, x_lo, Dm, m0, 0, W, Dm, Dm, n0, acc);
  float* outp = qkvout + (size_t)z*NT*Dm;
  int lane = threadIdx.x&63, wv = threadIdx.x>>6, wm = wv&1, wn = wv>>1;
  #pragma unroll
  for(int fi=0; fi<2; fi++)
    #pragma unroll
    for(int fj=0; fj<4; fj++)
      #pragma unroll
      for(int r=0; r<4; r++){
        int row = m0 + wm*32 + fi*16 + ((lane>>4)<<2) + r;
        int col = n0 + wn*64 + fj*16 + (lane&15);
        outp[(size_t)row*Dm + col] = acc[fi][fj][r] + bias[col];
      }
}

// ================= output projection, split-K via z (kc=0 common, kc=1 unique) =================
__global__ __launch_bounds__(256) void mm3_outproj(const short* __restrict__ ctx_hi,
    const short* __restrict__ ctx_lo,
    const float* __restrict__ ca_wo, const float* __restrict__ ua_wo,
    const float* __restrict__ ca_bo, const float* __restrict__ ua_bo,
    const int* __restrict__ routeb, const float* __restrict__ pmaxb,
    float* __restrict__ att2)
{
  int n0 = blockIdx.x*BN, m0 = blockIdx.y*BM, kc = blockIdx.z;
  int bidx = m0 >> 7;
  int e = routeb[bidx];
  const float* W    = kc ? (ua_wo + (size_t)e*Dm*Dm) : ca_wo;
  const float* bias = kc ? (ua_bo + (size_t)e*Dm)    : ca_bo;
  float bscale = kc ? pmaxb[bidx] : 1.0f;
  f32x4 acc[2][4] = {};
  mm_tile3b(ctx_hi, ctx_lo, 1536, m0, kc*Dm, W, Dm, Dm, n0, acc);
  float* outp = att2 + (size_t)kc*NT*Dm;
  int lane = threadIdx.x&63, wv = threadIdx.x>>6, wm = wv&1, wn = wv>>1;
  #pragma unroll
  for(int fi=0; fi<2; fi++)
    #pragma unroll
    for(int fj=0; fj<4; fj++)
      #pragma unroll
      for(int r=0; r<4; r++){
        int row = m0 + wm*32 + fi*16 + ((lane>>4)<<2) + r;
        int col = n0 + wn*64 + fj*16 + (lane&15);
        outp[(size_t)row*Dm + col] = acc[fi][fj][r] + bscale*bias[col];
      }
}

// ================= att = att2[0] + att2[1]; also emit bf16 =================
__global__ __launch_bounds__(256) void k_att_sum(const float* __restrict__ att2,
    float* __restrict__ att, short* __restrict__ attbf, int n4){
  int i = blockIdx.x*256 + threadIdx.x;
  if(i < n4){
    const size_t P4 = (size_t)NT*Dm/4;
    float4 a = ((const float4*)att2)[i];
    float4 b = ((const float4*)att2)[P4 + i];
    float4 v; v.x=a.x+b.x; v.y=a.y+b.y; v.z=a.z+b.z; v.w=a.w+b.w;
    ((float4*)att)[i] = v;
    short4 o;
    o.x=(short)f2bf(v.x); o.y=(short)f2bf(v.y); o.z=(short)f2bf(v.z); o.w=(short)f2bf(v.w);
    ((short4*)attbf)[i] = o;
  }
}

// ================= F-stage: common FFN1 (y<16) + grouped Switch-FFN1 (tile list) =================
__global__ __launch_bounds__(256) void mm_fstage(const short* __restrict__ attbf,
    const float* __restrict__ cf_w1, const float* __restrict__ cf_b1,
    const float* __restrict__ uf_w1, const float* __restrict__ uf_b1,
    const int* __restrict__ idxl, const int* __restrict__ gbase, const int* __restrict__ gcnt,
    const int* __restrict__ tlist, const int* __restrict__ ntl,
    short* __restrict__ h, short* __restrict__ hg)
{
  int n0 = blockIdx.x*BN, y = blockIdx.y;
  int lane = threadIdx.x&63, wv = threadIdx.x>>6, wm = wv&1, wn = wv>>1;
  f32x4 acc[4][4] = {};
  if(y < 16){
    int m0 = y*BM2;
    mm_tile2(attbf, Dm, nullptr, m0, BM2, cf_w1, Fm, Dm, n0, acc);
    #pragma unroll
    for(int fi=0; fi<4; fi++)
      #pragma unroll
      for(int fj=0; fj<4; fj++)
        #pragma unroll
        for(int r=0; r<4; r++){
          int row = m0 + wm*64 + fi*16 + ((lane>>4)<<2) + r;
          int col = n0 + wn*64 + fj*16 + (lane&15);
          h[(size_t)row*Fm + col] = (short)f2bf(gelu_f(acc[fi][fj][r] + cf_b1[col]));
        }
  } else {
    int i = y - 16;
    if(i >= ntl[0]) return;
    int v = tlist[i], g = v>>8, t = v&255;
    int cnt = gcnt[g], r0 = t*BM2, pos0 = gbase[g] + r0;
    mm_tile2(attbf, Dm, idxl, pos0, cnt - r0, uf_w1 + (size_t)g*Dm*Fm, Fm, Dm, n0, acc);
    const float* bias = uf_b1 + (size_t)g*Fm;
    #pragma unroll
    for(int fi=0; fi<4; fi++)
      #pragma unroll
      for(int fj=0; fj<4; fj++)
        #pragma unroll
        for(int r=0; r<4; r++){
          int lr = wm*64 + fi*16 + ((lane>>4)<<2) + r;
          if(r0 + lr >= cnt) continue;
          int col = n0 + wn*64 + fj*16 + (lane&15);
          hg[(size_t)(pos0+lr)*Fm + col] = (short)f2bf(gelu_f(acc[fi][fj][r] + bias[col]));
        }
  }
}

// ================= D-stage: split-K (z=kc of 4), bf16 partials =================
__global__ __launch_bounds__(256) void mm_dstage(const short* __restrict__ h,
    const short* __restrict__ hg,
    const float* __restrict__ cf_w2, const float* __restrict__ cf_b2,
    const float* __restrict__ uf_w2, const float* __restrict__ uf_b2,
    const int* __restrict__ idxl, const int* __restrict__ gbase, const int* __restrict__ gcnt,
    const int* __restrict__ tlist, const int* __restrict__ ntl,
    const float* __restrict__ tokp, short* __restrict__ ycf4, short* __restrict__ yuo4)
{
  const int KC = Fm/4;   // 768
  int n0 = blockIdx.x*BN, y = blockIdx.y, kc = blockIdx.z;
  int lane = threadIdx.x&63, wv = threadIdx.x>>6, wm = wv&1, wn = wv>>1;
  f32x4 acc[4][4] = {};
  if(y < 16){
    int m0 = y*BM2;
    mm_tile2(h + kc*KC, Fm, nullptr, m0, BM2, cf_w2 + (size_t)kc*KC*Dm, Dm, KC, n0, acc);
    short* outp = ycf4 + (size_t)kc*NT*Dm;
    #pragma unroll
    for(int fi=0; fi<4; fi++)
      #pragma unroll
      for(int fj=0; fj<4; fj++)
        #pragma unroll
        for(int r=0; r<4; r++){
          int row = m0 + wm*64 + fi*16 + ((lane>>4)<<2) + r;
          int col = n0 + wn*64 + fj*16 + (lane&15);
          outp[(size_t)row*Dm + col] = (short)f2bf(acc[fi][fj][r] + (kc==0 ? cf_b2[col] : 0.f));
        }
  } else {
    int i = y - 16;
    if(i >= ntl[0]) return;
    int v = tlist[i], g = v>>8, t = v&255;
    int cnt = gcnt[g], r0 = t*BM2, pos0 = gbase[g] + r0;
    mm_tile2(hg + kc*KC, Fm, nullptr, pos0, cnt - r0,
             uf_w2 + (size_t)g*Fm*Dm + (size_t)kc*KC*Dm, Dm, KC, n0, acc);
    const float* bias = uf_b2 + (size_t)g*Dm;
    short* outp = yuo4 + (size_t)kc*NT*Dm;
    #pragma unroll
    for(int fi=0; fi<4; fi++)
      #pragma unroll
      for(int fj=0; fj<4; fj++)
        #pragma unroll
        for(int r=0; r<4; r++){
          int lr = wm*64 + fi*16 + ((lane>>4)<<2) + r;
          int rm = (r0 + lr < cnt) ? idxl[pos0 + lr] : -1;
          if(rm < 0) continue;
          int col = n0 + wn*64 + fj*16 + (lane&15);
          float vv = acc[fi][fj][r] + (kc==0 ? bias[col] : 0.f);
          outp[(size_t)rm*Dm + col] = (short)f2bf(vv * tokp[rm]);
        }
  }
}

// ================= batch-level routing =================
__global__ __launch_bounds__(256) void k_route_batch(const float* __restrict__ xf,
    const float* __restrict__ sw_w, const float* __restrict__ sw_b,
    float* __restrict__ pmax_b, int* __restrict__ route_b){
  int b = blockIdx.x, tid = threadIdx.x;
  __shared__ float xm[Dm];
  for(int d=tid; d<Dm; d+=256){
    float s=0.f;
    const float* xp = xf + ((size_t)b*Sm)*Dm + d;
    for(int ss=0; ss<Sm; ss++) s += xp[(size_t)ss*Dm];
    xm[d] = s*(1.0f/Sm);
  }
  __syncthreads();
  float a0=0,a1=0,a2=0,a3=0;
  for(int d=tid; d<Dm; d+=256){
    float xv = xm[d];
    a0 += xv*sw_w[d*4+0]; a1 += xv*sw_w[d*4+1];
    a2 += xv*sw_w[d*4+2]; a3 += xv*sw_w[d*4+3];
  }
  __shared__ float red[4][256];
  red[0][tid]=a0; red[1][tid]=a1; red[2][tid]=a2; red[3][tid]=a3;
  for(int off=128; off>0; off>>=1){
    __syncthreads();
    if(tid<off){ for(int u=0;u<4;u++) red[u][tid]+=red[u][tid+off]; }
  }
  __syncthreads();
  if(tid==0){
    float l[4]; for(int u=0;u<4;u++) l[u]=red[u][0]+sw_b[u];
    float m=l[0]; int arg=0;
    for(int u=1;u<4;u++) if(l[u]>m){ m=l[u]; arg=u; }
    float s=0; for(int u=0;u<4;u++) s+=expf(l[u]-m);
    pmax_b[b]=1.0f/s;
    route_b[b]=arg;
  }
}

// ====== attention v2: reg-resident scores, wave-local softmax, conflict-free LDS ======
__global__ __launch_bounds__(256) void k_attn_f(const float* __restrict__ qkv,
    const float* __restrict__ mask, const float* __restrict__ pmaxb,
    short* __restrict__ ctx_hi, short* __restrict__ ctx_lo)
{
  int h = blockIdx.x, b = blockIdx.y, z = blockIdx.z;
  int qh = z & 1, kind = z >> 1;
  const float* Q  = qkv + (size_t)(kind*3+0)*NT*Dm;
  const float* Kp = qkv + (size_t)(kind*3+1)*NT*Dm;
  const float* Vp = qkv + (size_t)(kind*3+2)*NT*Dm;
  int tid = threadIdx.x;
  __shared__ float kv[128][68];
  size_t base = ((size_t)b*Sm)*Dm + h*DHm;
  for(int l=tid; l<2048; l+=256){
    int s=l>>4, d4=(l&15)*4;
    *(float4*)&kv[s][d4] = *(const float4*)(Kp + base + (size_t)s*Dm + d4);
  }
  int ql = tid>>2, quarter = tid&3;
  int qi = qh*64 + ql;
  float4 q4[16];
  const float* qp = Q + base + (size_t)qi*Dm;
  #pragma unroll
  for(int j=0;j<16;j++) q4[j] = *(const float4*)(qp + j*4);
  __syncthreads();
  float sc[32];
  #pragma unroll 4
  for(int t=0;t<32;t++){
    int ki = quarter + 4*t;
    float s=0.f;
    #pragma unroll
    for(int j=0;j<16;j++){
      float4 k4 = *(float4*)&kv[ki][j*4];
      s += q4[j].x*k4.x + q4[j].y*k4.y + q4[j].z*k4.z + q4[j].w*k4.w;
    }
    sc[t] = s*0.125f + mask[b*Sm+ki];
  }
  float m = sc[0];
  #pragma unroll
  for(int t=1;t<32;t++) m = fmaxf(m, sc[t]);
  m = fmaxf(m, __shfl_xor(m,1));
  m = fmaxf(m, __shfl_xor(m,2));
  float sum = 0.f;
  #pragma unroll
  for(int t=0;t<32;t++){ sc[t] = expf(sc[t]-m); sum += sc[t]; }
  sum += __shfl_xor(sum,1);
  sum += __shfl_xor(sum,2);
  float inv = 1.0f/sum;
  #pragma unroll
  for(int t=0;t<32;t++) sc[t] *= inv;
  __syncthreads();
  for(int l=tid; l<2048; l+=256){
    int s=l>>4, d4=(l&15)*4;
    *(float4*)&kv[s][d4] = *(const float4*)(Vp + base + (size_t)s*Dm + d4);
  }
  __syncthreads();
  float4 part[16];
  #pragma unroll
  for(int j=0;j<16;j++){ part[j].x=0; part[j].y=0; part[j].z=0; part[j].w=0; }
  #pragma unroll 4
  for(int t=0;t<32;t++){
    int ki = quarter + 4*t;
    float p = sc[t];
    #pragma unroll
    for(int j=0;j<16;j++){
      float4 v4 = *(float4*)&kv[ki][j*4];
      part[j].x += p*v4.x; part[j].y += p*v4.y; part[j].z += p*v4.z; part[j].w += p*v4.w;
    }
  }
  #pragma unroll
  for(int j=0;j<16;j++){
    part[j].x += __shfl_xor(part[j].x,1); part[j].x += __shfl_xor(part[j].x,2);
    part[j].y += __shfl_xor(part[j].y,1); part[j].y += __shfl_xor(part[j].y,2);
    part[j].z += __shfl_xor(part[j].z,1); part[j].z += __shfl_xor(part[j].z,2);
    part[j].w += __shfl_xor(part[j].w,1); part[j].w += __shfl_xor(part[j].w,2);
  }
  float sck = kind ? pmaxb[b] : 1.0f;
  size_t obase = ((size_t)b*Sm + qi)*1536 + kind*Dm + h*DHm;
  #pragma unroll
  for(int jj=0;jj<4;jj++){
    int j = quarter*4 + jj;
    float4 v = part[j];
    v.x *= sck; v.y *= sck; v.z *= sck; v.w *= sck;
    short4 hh, ll;
    unsigned short t0;
    t0=f2bf(v.x); hh.x=(short)t0; ll.x=(short)f2bf(v.x-bf2f(t0));
    t0=f2bf(v.y); hh.y=(short)t0; ll.y=(short)f2bf(v.y-bf2f(t0));
    t0=f2bf(v.z); hh.z=(short)t0; ll.z=(short)f2bf(v.z-bf2f(t0));
    t0=f2bf(v.w); hh.w=(short)t0; ll.w=(short)f2bf(v.w-bf2f(t0));
    *(short4*)(ctx_hi + obase + j*4) = hh;
    *(short4*)(ctx_lo + obase + j*4) = ll;
  }
}

// ================= token-level Switch routing =================
__global__ __launch_bounds__(256) void k_tok_route(const float* __restrict__ att,
    const float* __restrict__ ur_w, const float* __restrict__ ur_b,
    const int* __restrict__ route_b, float* __restrict__ tok_pmax,
    int* __restrict__ tok_e, int* __restrict__ grp_count)
{
  int n = blockIdx.x, tid = threadIdx.x;
  int i = route_b[n>>7];
  const float* w = ur_w + (size_t)i*Dm*4;
  const float* ap = att + (size_t)n*Dm;
  float a0=0,a1=0,a2=0,a3=0;
  for(int d=tid; d<Dm; d+=256){
    float a = ap[d];
    a0 += a*w[d*4+0]; a1 += a*w[d*4+1];
    a2 += a*w[d*4+2]; a3 += a*w[d*4+3];
  }
  __shared__ float red[4][256];
  red[0][tid]=a0; red[1][tid]=a1; red[2][tid]=a2; red[3][tid]=a3;
  for(int off=128; off>0; off>>=1){
    __syncthreads();
    if(tid<off){ for(int u=0;u<4;u++) red[u][tid]+=red[u][tid+off]; }
  }
  __syncthreads();
  if(tid==0){
    float l[4]; for(int u=0;u<4;u++) l[u]=red[u][0]+ur_b[i*4+u];
    float m=l[0]; int arg=0;
    for(int u=1;u<4;u++) if(l[u]>m){ m=l[u]; arg=u; }
    float s=0; for(int u=0;u<4;u++) s+=expf(l[u]-m);
    tok_pmax[n] = 1.0f/s;
    tok_e[n] = arg;
    atomicAdd(&grp_count[i*4+arg], 1);
  }
}

// ================= prefix + tile worklist (BM2-row tiles) =================
__global__ void k_prefix(const int* __restrict__ cnt, int* __restrict__ base,
                         int* __restrict__ cur, int* __restrict__ tlist, int* __restrict__ ntl){
  if(threadIdx.x==0 && blockIdx.x==0){
    int s=0, nt=0;
    for(int g=0; g<16; g++){
      base[g]=s; cur[g]=s;
      int tg = (cnt[g] + BM2 - 1)/BM2;
      for(int t=0; t<tg; t++){ if(nt<32) tlist[nt++] = (g<<8)|t; }
      s += cnt[g];
    }
    ntl[0] = nt;
  }
}

__global__ void k_scatter(const int* __restrict__ route_b, const int* __restrict__ tok_e,
                          int* __restrict__ cur, int* __restrict__ idxl){
  int n = blockIdx.x*256 + threadIdx.x;
  if(n < NT){
    int g = route_b[n>>7]*4 + tok_e[n];
    int pos = atomicAdd(&cur[g], 1);
    idxl[pos] = n;
  }
}

// ======= final residual add + LayerNorm (sums 4+4 bf16 split-K partials) =======
__global__ __launch_bounds__(256) void k_final_ln(const float* __restrict__ att,
    const short* __restrict__ ycf4, const short* __restrict__ yuo4,
    const float* __restrict__ ln_g, const float* __restrict__ ln_b, float* __restrict__ out)
{
  int n = blockIdx.x, tid = threadIdx.x;
  __shared__ float yb[Dm];
  __shared__ float red[256];
  size_t base = (size_t)n*Dm;
  const size_t P = (size_t)NT*Dm;
  float ps = 0.f;
  for(int d=tid; d<Dm; d+=256){
    float v = att[base+d];
    #pragma unroll
    for(int c=0; c<4; c++){
      v += bf2f((unsigned short)ycf4[c*P + base + d]);
      v += bf2f((unsigned short)yuo4[c*P + base + d]);
    }
    yb[d]=v; ps+=v;
  }
  red[tid]=ps;
  for(int off=128; off>0; off>>=1){ __syncthreads(); if(tid<off) red[tid]+=red[tid+off]; }
  __syncthreads();
  float mu = red[0]*(1.0f/Dm);
  __syncthreads();
  float pv = 0.f;
  for(int d=tid; d<Dm; d+=256){ float t = yb[d]-mu; pv += t*t; }
  red[tid]=pv;
  for(int off=128; off>0; off>>=1){ __syncthreads(); if(tid<off) red[tid]+=red[tid+off]; }
  __syncthreads();
  float var = red[0]*(1.0f/Dm);
  float rstd = rsqrtf(var + 1e-12f);
  for(int d=tid; d<Dm; d+=256){
    out[base+d] = (yb[d]-mu)*rstd*ln_g[d] + ln_b[d];
  }
}

extern "C" void kernel_launch(void* const* d_in, const int* in_sizes, int n_in,
                              void* d_out, int out_size, void* d_ws, size_t ws_size,
                              hipStream_t stream)
{
  const float* x     =(const float*)d_in[0];
  const float* mask  =(const float*)d_in[1];
  const float* sw_w  =(const float*)d_in[2];
  const float* sw_b  =(const float*)d_in[3];
  const float* ca_wq =(const float*)d_in[4];
  const float* ca_bq =(const float*)d_in[5];
  const float* ca_wk =(const float*)d_in[6];
  const float* ca_bk =(const float*)d_in[7];
  const float* ca_wv =(const float*)d_in[8];
  const float* ca_bv =(const float*)d_in[9];
  const float* ca_wo =(const float*)d_in[10];
  const float* ca_bo =(const float*)d_in[11];
  const float* ua_wq =(const float*)d_in[12];
  const float* ua_bq =(const float*)d_in[13];
  const float* ua_wk =(const float*)d_in[14];
  const float* ua_bk =(const float*)d_in[15];
  const float* ua_wv =(const float*)d_in[16];
  const float* ua_bv =(const float*)d_in[17];
  const float* ua_wo =(const float*)d_in[18];
  const float* ua_bo =(const float*)d_in[19];
  const float* cf_w1 =(const float*)d_in[20];
  const float* cf_b1 =(const float*)d_in[21];
  const float* cf_w2 =(const float*)d_in[22];
  const float* cf_b2 =(const float*)d_in[23];
  const float* ur_w  =(const float*)d_in[24];
  const float* ur_b  =(const float*)d_in[25];
  const float* uf_w1 =(const float*)d_in[26];
  const float* uf_b1 =(const float*)d_in[27];
  const float* uf_w2 =(const float*)d_in[28];
  const float* uf_b2 =(const float*)d_in[29];
  const float* ln_g  =(const float*)d_in[30];
  const float* ln_b  =(const float*)d_in[31];

  // ---- workspace: region of 8 units (1 unit = NT*Dm f32 = 6.29MB), phase-aliased ----
  float* region = (float*)d_ws;
  float* qkv    = region;
  short* ctx_hi = (short*)(region + (size_t)6*NT*Dm);
  short* ctx_lo = (short*)(region + (size_t)7*NT*Dm);
  float* att2   = region;
  short* h_bf   = (short*)region;
  short* hg_bf  = (short*)region + (size_t)NT*Fm;
  short* ycf4   = (short*)(region + (size_t)4*NT*Dm);
  short* yuo4   = (short*)(region + (size_t)6*NT*Dm);
  float* fp     = region + (size_t)8*NT*Dm;
  short* x_hi   = (short*)fp;                 // alive only during mm3_qkv
  short* x_lo   = x_hi + (size_t)NT*Dm;
  float* att    = fp; fp += (size_t)NT*Dm;    // written by k_att_sum (x_hi/lo dead)
  float* tokp   = fp; fp += NT;
  float* pmaxb  = fp; fp += 16;
  short* att_bf = (short*)fp;
  int*   ip     = (int*)(att_bf + (size_t)NT*Dm);
  int* routeb = ip; ip += 16;
  int* toke   = ip; ip += NT;
  int* gcnt   = ip; ip += 16;
  int* gbase  = ip; ip += 16;
  int* gcur   = ip; ip += 16;
  int* idxl   = ip; ip += NT;
  int* tlist  = ip; ip += 64;
  int* ntl    = ip; ip += 1;
  size_t need = (size_t)((char*)ip - (char*)d_ws);
  if(need > ws_size) return;   // bail visibly (output stays 0)

  (void)hipMemsetAsync(gcnt, 0, 16*sizeof(int), stream);

  k_route_batch<<<16, 256, 0, stream>>>(x, sw_w, sw_b, pmaxb, routeb);
  k_split_x<<<(NT*Dm/4 + 255)/256, 256, 0, stream>>>(x, x_hi, x_lo, NT*Dm/4);

  PtrArr6 pa;
  pa.w[0]=ca_wq; pa.w[1]=ca_wk; pa.w[2]=ca_wv; pa.w[3]=ua_wq; pa.w[4]=ua_wk; pa.w[5]=ua_wv;
  pa.b[0]=ca_bq; pa.b[1]=ca_bk; pa.b[2]=ca_bv; pa.b[3]=ua_bq; pa.b[4]=ua_bk; pa.b[5]=ua_bv;
  mm3_qkv<<<dim3(Dm/BN, NT/BM, 6), 256, 0, stream>>>(x_hi, x_lo, pa, routeb, qkv);

  // attention v2 (f32 -> ctx hi/lo bf16): z = qh + 2*kind
  k_attn_f<<<dim3(Hm, Bm, 4), 256, 0, stream>>>(qkv, mask, pmaxb, ctx_hi, ctx_lo);

  // output projection, split-K=2 (z): partials into dead qkv units
  mm3_outproj<<<dim3(Dm/BN, NT/BM, 2), 256, 0, stream>>>(ctx_hi, ctx_lo, ca_wo, ua_wo,
                                                         ca_bo, ua_bo, routeb, pmaxb, att2);
  k_att_sum<<<(NT*Dm/4 + 255)/256, 256, 0, stream>>>(att2, att, att_bf, NT*Dm/4);

  // token routing + grouping (from f32 att -> flip-safe)
  k_tok_route<<<NT, 256, 0, stream>>>(att, ur_w, ur_b, routeb, tokp, toke, gcnt);
  k_prefix<<<1, 64, 0, stream>>>(gcnt, gbase, gcur, tlist, ntl);
  k_scatter<<<NT/256, 256, 0, stream>>>(routeb, toke, gcur, idxl);

  // F-stage: common FFN1 (16 tiles of 128) + grouped Switch-FFN1 (<=32 tiles)
  mm_fstage<<<dim3(Fm/BN, 16+32), 256, 0, stream>>>(att_bf, cf_w1, cf_b1, uf_w1, uf_b1,
                                                    idxl, gbase, gcnt, tlist, ntl, h_bf, hg_bf);

  // D-stage: split-K=4, bf16 partial buffers
  mm_dstage<<<dim3(Dm/BN, 16+32, 4), 256, 0, stream>>>(h_bf, hg_bf, cf_w2, cf_b2, uf_w2, uf_b2,
                                                       idxl, gbase, gcnt, tlist, ntl, tokp,
                                                       ycf4, yuo4);

  k_final_ln<<<NT, 256, 0, stream>>>(att, ycf4, yuo4, ln_g, ln_b, (float*)d_out);
}